// Round 2
// baseline (7155.651 us; speedup 1.0000x reference)
//
#include <hip/hip_runtime.h>
#include <hip/hip_bf16.h>

typedef __hip_bfloat16 bf16;

#define MEAN0 0.4488f
#define MEAN1 0.4371f
#define MEAN2 0.4040f

static __device__ __forceinline__ float cvt_in(float v){ return v; }
static __device__ __forceinline__ float cvt_in(bf16 v){ return __bfloat162float(v); }

// ---------------- IICM: 3->12 conv3x3 per 32x32 patch, relu ----------------
// grid NP*4, block 256. out: [NP,12,32,32]. x is segment-local (SEG images).
__global__ void k_iicm(const float* __restrict__ x, const float* __restrict__ w,
                       const float* __restrict__ bias, float* __restrict__ out){
  __shared__ __align__(16) float ws_[324];   // [tap27][oc12]
  __shared__ float bs[12];
  for(int k=threadIdx.x;k<324;k+=256){ int t0=k/12, kk=k%12; ws_[k]=w[kk*27+t0]; }
  if(threadIdx.x<12) bs[threadIdx.x]=bias[threadIdx.x];
  __syncthreads();
  int idx = blockIdx.x*256+threadIdx.x;
  int pix = idx & 1023, n = idx >> 10;
  int i = pix>>5, j = pix&31;
  int pw = n%5, ph=(n/5)%5, bb=n/25;   // bb is segment-local image
  float acc[12];
  #pragma unroll
  for(int k=0;k<12;k++) acc[k]=bs[k];
  #pragma unroll
  for(int c=0;c<3;c++){
    const float* xb = x + ((bb*3+c)*160 + ph*32)*160 + pw*32;
    float mc = (c==0)?MEAN0:((c==1)?MEAN1:MEAN2);
    #pragma unroll
    for(int dy=-1;dy<=1;dy++){
      int ii=i+dy; if((unsigned)ii>=32u) continue;
      #pragma unroll
      for(int dx=-1;dx<=1;dx++){
        int jj=j+dx; if((unsigned)jj>=32u) continue;
        float v = xb[ii*160+jj]-mc;
        int t0 = c*9+(dy+1)*3+(dx+1);
        const float4* wv = (const float4*)&ws_[t0*12];
        float4 w0=wv[0], w1=wv[1], w2=wv[2];
        acc[0]+=v*w0.x; acc[1]+=v*w0.y; acc[2]+=v*w0.z; acc[3]+=v*w0.w;
        acc[4]+=v*w1.x; acc[5]+=v*w1.y; acc[6]+=v*w1.z; acc[7]+=v*w1.w;
        acc[8]+=v*w2.x; acc[9]+=v*w2.y; acc[10]+=v*w2.z; acc[11]+=v*w2.w;
      }
    }
  }
  float* ob = out + n*12288 + pix;
  #pragma unroll
  for(int k=0;k<12;k++) ob[k*1024] = fmaxf(acc[k],0.f);
}

// ---------------- ssza + channel-0 std per patch ----------------
// grid NP, block 256. scalp[n]=ssza, scalp[128+n]=std (scalp = scal + p0)
__global__ void k_red(const float* __restrict__ f12, const float* __restrict__ x,
                      float* __restrict__ scalp){
  int n = blockIdx.x, t = threadIdx.x;
  __shared__ float sh[256];
  float s=0.f;
  const float* fb = f12 + n*12288;
  for(int k=t;k<12288;k+=256) s += fabsf(fb[k]);
  sh[t]=s; __syncthreads();
  for(int o=128;o>0;o>>=1){ if(t<o) sh[t]+=sh[t+o]; __syncthreads(); }
  if(t==0) scalp[n]=sh[0]*(1.f/12288.f);
  __syncthreads();
  int pw=n%5, ph=(n/5)%5, bb=n/25;
  const float* xb = x + ((bb*3+0)*160 + ph*32)*160 + pw*32;
  float sm=0.f, sq=0.f;
  for(int k=t;k<1024;k+=256){ int i=k>>5,j=k&31; float v=xb[i*160+j]-MEAN0; sm+=v; sq+=v*v; }
  sh[t]=sm; __syncthreads();
  for(int o=128;o>0;o>>=1){ if(t<o) sh[t]+=sh[t+o]; __syncthreads(); }
  float smean = sh[0]*(1.f/1024.f);
  __syncthreads();
  sh[t]=sq; __syncthreads();
  for(int o=128;o>0;o>>=1){ if(t<o) sh[t]+=sh[t+o]; __syncthreads(); }
  if(t==0){ float var = sh[0]*(1.f/1024.f) - smean*smean; scalp[128+n]=sqrtf(fmaxf(var,0.f)); }
}

// ---------------- conv4: 12->64 conv3x3 per patch, NO relu ----------------
// grid NP*32 ((n*8+chunk)*4+tile), block 256
__global__ void k_conv4(const float* __restrict__ fin, const float* __restrict__ w,
                        const float* __restrict__ bias, float* __restrict__ out){
  int bid=blockIdx.x;
  int tile=bid&3, chunk=(bid>>2)&7, n=bid>>5;
  __shared__ __align__(16) float ws_[864];   // [tap108][oc8]
  __shared__ float bs[8];
  int ocb=chunk*8;
  for(int k=threadIdx.x;k<864;k+=256){ int t0=k>>3, kk=k&7; ws_[k]=w[(ocb+kk)*108+t0]; }
  if(threadIdx.x<8) bs[threadIdx.x]=bias[ocb+threadIdx.x];
  __syncthreads();
  int pix=tile*256+threadIdx.x, i=pix>>5, j=pix&31;
  float acc[8];
  #pragma unroll
  for(int k=0;k<8;k++) acc[k]=bs[k];
  const float* fb = fin + n*12288;
  for(int c=0;c<12;c++){
    const float* fc = fb + c*1024;
    #pragma unroll
    for(int dy=-1;dy<=1;dy++){
      int ii=i+dy; if((unsigned)ii>=32u) continue;
      #pragma unroll
      for(int dx=-1;dx<=1;dx++){
        int jj=j+dx; if((unsigned)jj>=32u) continue;
        float v=fc[(ii<<5)+jj];
        int t0=c*9+(dy+1)*3+(dx+1);
        const float4* wv=(const float4*)&ws_[t0*8];
        float4 wa=wv[0], wb=wv[1];
        acc[0]+=v*wa.x; acc[1]+=v*wa.y; acc[2]+=v*wa.z; acc[3]+=v*wa.w;
        acc[4]+=v*wb.x; acc[5]+=v*wb.y; acc[6]+=v*wb.z; acc[7]+=v*wb.w;
      }}}
  float* ob = out + (n*64+ocb)*1024 + pix;
  #pragma unroll
  for(int k=0;k<8;k++) ob[k*1024]=acc[k];
}

// ---------------- grouped conv 64->64 (4 groups of 16), optional relu/residual ----------------
// grid NP*32, block 256
__global__ void k_gconv(const float* __restrict__ fin, const float* __restrict__ w,
                        const float* __restrict__ bias, const float* __restrict__ resid,
                        float* __restrict__ out, int do_relu){
  int bid=blockIdx.x;
  int tile=bid&3, chunk=(bid>>2)&7, n=bid>>5;
  __shared__ __align__(16) float ws_[1152];  // [tap144][oc8]
  __shared__ float bs[8];
  int ocb=chunk*8;
  for(int k=threadIdx.x;k<1152;k+=256){ int t0=k>>3, kk=k&7; ws_[k]=w[(ocb+kk)*144+t0]; }
  if(threadIdx.x<8) bs[threadIdx.x]=bias[ocb+threadIdx.x];
  __syncthreads();
  int pix=tile*256+threadIdx.x, i=pix>>5, j=pix&31;
  float acc[8];
  #pragma unroll
  for(int k=0;k<8;k++) acc[k]=bs[k];
  int g = ocb>>4;
  const float* fb = fin + (n*64 + g*16)*1024;
  for(int c=0;c<16;c++){
    const float* fc = fb + c*1024;
    #pragma unroll
    for(int dy=-1;dy<=1;dy++){
      int ii=i+dy; if((unsigned)ii>=32u) continue;
      #pragma unroll
      for(int dx=-1;dx<=1;dx++){
        int jj=j+dx; if((unsigned)jj>=32u) continue;
        float v=fc[(ii<<5)+jj];
        int t0=c*9+(dy+1)*3+(dx+1);
        const float4* wv=(const float4*)&ws_[t0*8];
        float4 wa=wv[0], wb=wv[1];
        acc[0]+=v*wa.x; acc[1]+=v*wa.y; acc[2]+=v*wa.z; acc[3]+=v*wa.w;
        acc[4]+=v*wb.x; acc[5]+=v*wb.y; acc[6]+=v*wb.z; acc[7]+=v*wb.w;
      }}}
  float* ob = out + (n*64+ocb)*1024+pix;
  const float* rb = resid ? resid + (n*64+ocb)*1024+pix : (const float*)0;
  #pragma unroll
  for(int k=0;k<8;k++){
    float vv=acc[k];
    if(do_relu) vv=fmaxf(vv,0.f);
    if(rb) vv+=rb[k*1024];
    ob[k*1024]=vv;
  }
}

// ---------------- 1x1 conv over up to 4 concatenated 64ch sources, relu ----------------
// grid NP*32, block 256
__global__ void k_1x1(const float* __restrict__ s0, const float* __restrict__ s1,
                      const float* __restrict__ s2, const float* __restrict__ s3,
                      int ns, const float* __restrict__ w, const float* __restrict__ bias,
                      float* __restrict__ out){
  int bid=blockIdx.x;
  int tile=bid&3, chunk=(bid>>2)&7, n=bid>>5;
  int Cin=ns*64, ocb=chunk*8;
  __shared__ __align__(16) float ws_[8*256];  // [cin][oc8]
  __shared__ float bs[8];
  for(int k=threadIdx.x;k<8*Cin;k+=256){ int kk=k>>3, oo=k&7; ws_[k]=w[(ocb+oo)*Cin+kk]; }
  if(threadIdx.x<8) bs[threadIdx.x]=bias[ocb+threadIdx.x];
  __syncthreads();
  int pix=tile*256+threadIdx.x;
  float acc[8];
  #pragma unroll
  for(int k=0;k<8;k++) acc[k]=bs[k];
  const float* srcs[4]={s0,s1,s2,s3};
  for(int s=0;s<ns;s++){
    const float* sp=srcs[s]+n*65536+pix;
    for(int c=0;c<64;c++){
      float v=sp[c*1024];
      int kk=s*64+c;
      const float4* wv=(const float4*)&ws_[kk*8];
      float4 wa=wv[0], wb=wv[1];
      acc[0]+=v*wa.x; acc[1]+=v*wa.y; acc[2]+=v*wa.z; acc[3]+=v*wa.w;
      acc[4]+=v*wb.x; acc[5]+=v*wb.y; acc[6]+=v*wb.z; acc[7]+=v*wb.w;
    }
  }
  float* ob=out+(n*64+ocb)*1024+pix;
  #pragma unroll
  for(int k=0;k<8;k++) ob[k*1024]=fmaxf(acc[k],0.f);
}

// ---------------- routing select + stitch patches -> feat (SEG,64,160,160) ----------------
// grid SEG*6400, block 256
__global__ void k_route(const float* __restrict__ xs, const float* __restrict__ xm,
                        const float* __restrict__ xh, const float* __restrict__ scalp,
                        const float* __restrict__ tl, const float* __restrict__ tr,
                        float* __restrict__ feat){
  int idx = blockIdx.x*256+threadIdx.x;   // ((b*64+c)*160+y)*160+x, b segment-local
  int x_=idx%160, y=(idx/160)%160, c=(idx/25600)&63, b=idx/1638400;
  int n = b*25 + (y>>5)*5 + (x_>>5);
  float sz = scalp[n];
  float tl0=tl[0], tr0=tr[0], thr=tl0+tr0;
  const float* src = (sz>thr) ? xs : ((sz>=tl0 && sz<=thr) ? xm : xh);
  feat[idx] = src[((n*64+c)<<10) + ((y&31)<<5) + (x_&31)];
}

// ---------------- timep ----------------
// grid SEG, block 64. dtp = out + 4915200 + b0
__global__ void k_timep(const float* __restrict__ scalp, const float* __restrict__ tl,
                        const float* __restrict__ tr, float* __restrict__ dtp){
  __shared__ float sh[64];
  int b=blockIdx.x, t=threadIdx.x;
  float tl0=tl[0], tr0=tr[0], thr=tl0+tr0;
  float v=0.f;
  if(t<25){
    float sz=scalp[b*25+t];
    v = (sz>thr) ? 1e-4f*(sz-thr) : ((sz>=tl0 && sz<=thr) ? 2e-4f*tr0 : 3e-4f*(tl0-sz));
  }
  sh[t]=v; __syncthreads();
  for(int o=32;o>0;o>>=1){ if(t<o) sh[t]+=sh[t+o]; __syncthreads(); }
  if(t==0) dtp[b]=sh[0]*(1.f/25.f);
}

// ---------------- MARM: 67->64 conv3x3 full image, relu ----------------
// grid SEG*800 ((b*8+chunk)*100+tile), block 256
__global__ void k_marm(const float* __restrict__ x, const float* __restrict__ feat,
                       const float* __restrict__ w, const float* __restrict__ bias,
                       float* __restrict__ out){
  int bid=blockIdx.x;
  int tile=bid%100, chunk=(bid/100)&7, b=bid/800;
  __shared__ __align__(16) float ws_[4824];  // [tap603][oc8]
  __shared__ float bs[8];
  int ocb=chunk*8;
  for(int k=threadIdx.x;k<4824;k+=256){ int t0=k>>3, kk=k&7; ws_[k]=w[(ocb+kk)*603+t0]; }
  if(threadIdx.x<8) bs[threadIdx.x]=bias[ocb+threadIdx.x];
  __syncthreads();
  int pix=tile*256+threadIdx.x;
  int y=pix/160, xx0=pix%160;
  float acc[8];
  #pragma unroll
  for(int k=0;k<8;k++) acc[k]=bs[k];
  #pragma unroll
  for(int c=0;c<3;c++){
    const float* xb = x + (b*3+c)*25600;
    float mc = (c==0)?MEAN0:((c==1)?MEAN1:MEAN2);
    #pragma unroll
    for(int dy=-1;dy<=1;dy++){
      int yy=y+dy; if((unsigned)yy>=160u) continue;
      #pragma unroll
      for(int dx=-1;dx<=1;dx++){
        int xc=xx0+dx; if((unsigned)xc>=160u) continue;
        float v=xb[yy*160+xc]-mc;
        int t0=c*9+(dy+1)*3+(dx+1);
        const float4* wv=(const float4*)&ws_[t0*8];
        float4 wa=wv[0], wb=wv[1];
        acc[0]+=v*wa.x; acc[1]+=v*wa.y; acc[2]+=v*wa.z; acc[3]+=v*wa.w;
        acc[4]+=v*wb.x; acc[5]+=v*wb.y; acc[6]+=v*wb.z; acc[7]+=v*wb.w;
      }}}
  for(int c=0;c<64;c++){
    const float* fb = feat + ((size_t)b*64+c)*25600;
    #pragma unroll
    for(int dy=-1;dy<=1;dy++){
      int yy=y+dy; if((unsigned)yy>=160u) continue;
      #pragma unroll
      for(int dx=-1;dx<=1;dx++){
        int xc=xx0+dx; if((unsigned)xc>=160u) continue;
        float v=fb[yy*160+xc];
        int t0=(3+c)*9+(dy+1)*3+(dx+1);
        const float4* wv=(const float4*)&ws_[t0*8];
        float4 wa=wv[0], wb=wv[1];
        acc[0]+=v*wa.x; acc[1]+=v*wa.y; acc[2]+=v*wa.z; acc[3]+=v*wa.w;
        acc[4]+=v*wb.x; acc[5]+=v*wb.y; acc[6]+=v*wb.z; acc[7]+=v*wb.w;
      }}}
  float* ob = out + ((size_t)b*64+ocb)*25600 + pix;
  #pragma unroll
  for(int k=0;k<8;k++) ob[(size_t)k*25600]=fmaxf(acc[k],0.f);
}

// ---------------- upsample conv: 64->256 conv3x3 + pixel-shuffle(2) + relu -> bf16 ----------------
// grid nb*32*TILES, block 256
template<typename Tin, int HIN, int WIN>
__global__ void k_up(const Tin* __restrict__ in, const float* __restrict__ w,
                     const float* __restrict__ bias, bf16* __restrict__ out){
  const int TILES = (HIN*WIN)/256;
  int bid=blockIdx.x;
  int tile=bid%TILES, chunk=(bid/TILES)&31, b=bid/(TILES*32);
  __shared__ __align__(16) float ws_[4608];  // [tap576][oc8]
  __shared__ float bs[8];
  int ocb=chunk*8;
  for(int k=threadIdx.x;k<4608;k+=256){ int t0=k>>3, kk=k&7; ws_[k]=w[(size_t)(ocb+kk)*576+t0]; }
  if(threadIdx.x<8) bs[threadIdx.x]=bias[ocb+threadIdx.x];
  __syncthreads();
  int pix=tile*256+threadIdx.x;
  int y=pix/WIN, xx0=pix%WIN;
  float acc[8];
  #pragma unroll
  for(int k=0;k<8;k++) acc[k]=bs[k];
  const Tin* ib = in + (size_t)b*64*HIN*WIN;
  for(int c=0;c<64;c++){
    const Tin* icp = ib + (size_t)c*HIN*WIN;
    #pragma unroll
    for(int dy=-1;dy<=1;dy++){
      int yy=y+dy; if((unsigned)yy>=(unsigned)HIN) continue;
      #pragma unroll
      for(int dx=-1;dx<=1;dx++){
        int xc=xx0+dx; if((unsigned)xc>=(unsigned)WIN) continue;
        float v=cvt_in(icp[yy*WIN+xc]);
        int t0=c*9+(dy+1)*3+(dx+1);
        const float4* wv=(const float4*)&ws_[t0*8];
        float4 wa=wv[0], wb=wv[1];
        acc[0]+=v*wa.x; acc[1]+=v*wa.y; acc[2]+=v*wa.z; acc[3]+=v*wa.w;
        acc[4]+=v*wb.x; acc[5]+=v*wb.y; acc[6]+=v*wb.z; acc[7]+=v*wb.w;
      }}}
  const int HO=2*HIN, WO=2*WIN;
  #pragma unroll
  for(int k=0;k<8;k++){
    int oc=ocb+k, co=oc>>2, r1=(oc>>1)&1, r2=oc&1;
    float vv=fmaxf(acc[k],0.f);
    out[(((size_t)b*64+co)*HO + 2*y+r1)*WO + 2*xx0+r2] = __float2bfloat16(vv);
  }
}

// ---------------- final conv 64->3 @640x640 + MEAN; writes y, xcropia, xoutputa ----------------
// grid 1600 (single image, b passed), block 256
__global__ void k_upc(const bf16* __restrict__ in, const float* __restrict__ w,
                      const float* __restrict__ bias, const float* __restrict__ scal,
                      float* __restrict__ dout, int b){
  __shared__ __align__(16) float ws_[2304];   // [tap576][4] (4th lane zero)
  for(int k=threadIdx.x;k<2304;k+=256){ int t0=k>>2, kk=k&3; ws_[k]=(kk<3)?w[kk*576+t0]:0.f; }
  __syncthreads();
  int tile=blockIdx.x;
  int pix=tile*256+threadIdx.x;
  int y=pix/640, xx0=pix%640;
  float a0=bias[0], a1=bias[1], a2=bias[2];
  const bf16* ib = in;   // single image
  for(int c=0;c<64;c++){
    const bf16* icp = ib + (size_t)c*409600;
    #pragma unroll
    for(int dy=-1;dy<=1;dy++){
      int yy=y+dy; if((unsigned)yy>=640u) continue;
      #pragma unroll
      for(int dx=-1;dx<=1;dx++){
        int xc=xx0+dx; if((unsigned)xc>=640u) continue;
        float v=__bfloat162float(icp[yy*640+xc]);
        int t0=c*9+(dy+1)*3+(dx+1);
        const float4* wv=(const float4*)&ws_[t0*4];
        float4 wa=wv[0];
        a0+=v*wa.x; a1+=v*wa.y; a2+=v*wa.z;
      }}}
  a0+=MEAN0; a1+=MEAN1; a2+=MEAN2;
  int n=b*25+(y>>7)*5+(xx0>>7);
  float sv=scal[128+n];
  size_t pidx=(size_t)y*640+xx0;
  size_t yb=(size_t)b*3*409600;
  dout[yb+pidx]=a0; dout[yb+409600+pidx]=a1; dout[yb+819200+pidx]=a2;
  dout[4915204 + (size_t)b*409600 + pidx]=sv;
  size_t xa=6553604+yb;
  dout[xa+pidx]=a0*sv; dout[xa+409600+pidx]=a1*sv; dout[xa+819200+pidx]=a2*sv;
}

extern "C" void kernel_launch(void* const* d_in, const int* in_sizes, int n_in,
                              void* d_out, int out_size, void* d_ws, size_t ws_size,
                              hipStream_t stream){
  const float* x     =(const float*)d_in[0];
  const float* tl    =(const float*)d_in[1];
  const float* tr    =(const float*)d_in[2];
  const float* iicm_w=(const float*)d_in[3];
  const float* iicm_b=(const float*)d_in[4];
  const float* conv4_w=(const float*)d_in[5];
  const float* conv4_b=(const float*)d_in[6];
  const float* b1_w1 =(const float*)d_in[7];  const float* b1_b1=(const float*)d_in[8];
  const float* b1_w2 =(const float*)d_in[9];  const float* b1_b2=(const float*)d_in[10];
  const float* c1_w  =(const float*)d_in[11]; const float* c1_b =(const float*)d_in[12];
  const float* b2_w1 =(const float*)d_in[13]; const float* b2_b1=(const float*)d_in[14];
  const float* b2_w2 =(const float*)d_in[15]; const float* b2_b2=(const float*)d_in[16];
  const float* c2_w  =(const float*)d_in[17]; const float* c2_b =(const float*)d_in[18];
  const float* b3_w1 =(const float*)d_in[19]; const float* b3_b1=(const float*)d_in[20];
  const float* b3_w2 =(const float*)d_in[21]; const float* b3_b2=(const float*)d_in[22];
  const float* c3_w  =(const float*)d_in[23]; const float* c3_b =(const float*)d_in[24];
  const float* marm_w=(const float*)d_in[25]; const float* marm_b=(const float*)d_in[26];
  const float* up1_w =(const float*)d_in[27]; const float* up1_b=(const float*)d_in[28];
  const float* up2_w =(const float*)d_in[29]; const float* up2_b=(const float*)d_in[30];
  const float* upc_w =(const float*)d_in[31]; const float* upc_b=(const float*)d_in[32];

  float* ws  =(float*)d_ws;
  float* out =(float*)d_out;
  float* scal=ws;                                   // 256 floats

  // Mode A (SEG=4): everything in 188,417,024 B via aliasing, ps2 per-image.
  // Mode B (SEG=1): per-image pipeline, ~99.5 MB, ps2 dedicated.
  const int SEG = (ws_size >= 188417024ull) ? 4 : 1;
  const int NP  = SEG*25;
  const size_t SZp = (size_t)NP*65536;

  float* f12 = ws + 256;                            // NP*12288
  float* f   = f12 + (size_t)NP*12288;
  float* xm  = f   + SZp;
  float* xh  = xm  + SZp;
  float* b1o = xh  + SZp;
  float* b2o = b1o + SZp;
  float* b3o = b2o + SZp;
  float* xs  = b3o + SZp;
  float* feat = b2o;                                // dead after c3
  float* marm = b3o;                                // dead after c3
  bf16*  ps1  = (bf16*)xh;                          // spans xh+b1o (exact)
  bf16*  ps2  = (SEG==4) ? (bf16*)f                 // spans f+xm (exact, dead)
                         : (bf16*)(xs + SZp);       // dedicated 52.4 MB

  for(int b0=0;b0<4;b0+=SEG){
    int p0 = b0*25;
    const float* xseg = x + (size_t)b0*3*25600;
    float* scalp = scal + p0;

    k_iicm <<<NP*4,  256,0,stream>>>(xseg, iicm_w, iicm_b, f12);
    k_red  <<<NP,    256,0,stream>>>(f12, xseg, scalp);
    k_conv4<<<NP*32, 256,0,stream>>>(f12, conv4_w, conv4_b, f);
    // block 1 (xh as temp)
    k_gconv<<<NP*32, 256,0,stream>>>(f,  b1_w1, b1_b1, (const float*)0, xh, 1);
    k_gconv<<<NP*32, 256,0,stream>>>(xh, b1_w2, b1_b2, f,               b1o, 0);
    k_1x1  <<<NP*32, 256,0,stream>>>(f, b1o, (const float*)0, (const float*)0, 2, c1_w, c1_b, xs);
    // block 2
    k_gconv<<<NP*32, 256,0,stream>>>(xs, b2_w1, b2_b1, (const float*)0, xh, 1);
    k_gconv<<<NP*32, 256,0,stream>>>(xh, b2_w2, b2_b2, xs,              b2o, 0);
    k_1x1  <<<NP*32, 256,0,stream>>>(f, b1o, b2o, (const float*)0, 3, c2_w, c2_b, xm);
    // block 3
    k_gconv<<<NP*32, 256,0,stream>>>(xm, b3_w1, b3_b1, (const float*)0, xh, 1);
    k_gconv<<<NP*32, 256,0,stream>>>(xh, b3_w2, b3_b2, xm,              b3o, 0);
    k_1x1  <<<NP*32, 256,0,stream>>>(f, b1o, b2o, b3o, 4, c3_w, c3_b, xh);
    // routing + stitch + timep
    k_route<<<SEG*6400,256,0,stream>>>(xs, xm, xh, scalp, tl, tr, feat);
    k_timep<<<SEG,   64, 0,stream>>>(scalp, tl, tr, out + 4915200 + b0);
    // fuse + upsample chain
    k_marm <<<SEG*800, 256,0,stream>>>(xseg, feat, marm_w, marm_b, marm);
    k_up<float,160,160><<<SEG*3200,256,0,stream>>>(marm, up1_w, up1_b, ps1);
    for(int i=0;i<SEG;i++){
      k_up<bf16,320,320><<<12800,256,0,stream>>>(ps1 + (size_t)i*6553600, up2_w, up2_b, ps2);
      k_upc<<<1600,256,0,stream>>>(ps2, upc_w, upc_b, scal, out, b0+i);
    }
  }
}

// Round 3
// 2655.730 us; speedup vs baseline: 2.6944x; 2.6944x over previous
//
#include <hip/hip_runtime.h>
#include <hip/hip_bf16.h>

typedef __hip_bfloat16 bf16;
typedef __bf16 bf16x8 __attribute__((ext_vector_type(8)));
typedef float f32x4 __attribute__((ext_vector_type(4)));

#define MEAN0 0.4488f
#define MEAN1 0.4371f
#define MEAN2 0.4040f

// ---------------- IICM: 3->12 conv3x3 per 32x32 patch, relu ----------------
__global__ void k_iicm(const float* __restrict__ x, const float* __restrict__ w,
                       const float* __restrict__ bias, float* __restrict__ out){
  __shared__ __align__(16) float ws_[324];   // [tap27][oc12]
  __shared__ float bs[12];
  for(int k=threadIdx.x;k<324;k+=256){ int t0=k/12, kk=k%12; ws_[k]=w[kk*27+t0]; }
  if(threadIdx.x<12) bs[threadIdx.x]=bias[threadIdx.x];
  __syncthreads();
  int idx = blockIdx.x*256+threadIdx.x;
  int pix = idx & 1023, n = idx >> 10;
  int i = pix>>5, j = pix&31;
  int pw = n%5, ph=(n/5)%5, bb=n/25;
  float acc[12];
  #pragma unroll
  for(int k=0;k<12;k++) acc[k]=bs[k];
  #pragma unroll
  for(int c=0;c<3;c++){
    const float* xb = x + ((bb*3+c)*160 + ph*32)*160 + pw*32;
    float mc = (c==0)?MEAN0:((c==1)?MEAN1:MEAN2);
    #pragma unroll
    for(int dy=-1;dy<=1;dy++){
      int ii=i+dy; if((unsigned)ii>=32u) continue;
      #pragma unroll
      for(int dx=-1;dx<=1;dx++){
        int jj=j+dx; if((unsigned)jj>=32u) continue;
        float v = xb[ii*160+jj]-mc;
        int t0 = c*9+(dy+1)*3+(dx+1);
        const float4* wv = (const float4*)&ws_[t0*12];
        float4 w0=wv[0], w1=wv[1], w2=wv[2];
        acc[0]+=v*w0.x; acc[1]+=v*w0.y; acc[2]+=v*w0.z; acc[3]+=v*w0.w;
        acc[4]+=v*w1.x; acc[5]+=v*w1.y; acc[6]+=v*w1.z; acc[7]+=v*w1.w;
        acc[8]+=v*w2.x; acc[9]+=v*w2.y; acc[10]+=v*w2.z; acc[11]+=v*w2.w;
      }
    }
  }
  float* ob = out + n*12288 + pix;
  #pragma unroll
  for(int k=0;k<12;k++) ob[k*1024] = fmaxf(acc[k],0.f);
}

// ---------------- ssza + channel-0 std per patch ----------------
__global__ void k_red(const float* __restrict__ f12, const float* __restrict__ x,
                      float* __restrict__ scalp){
  int n = blockIdx.x, t = threadIdx.x;
  __shared__ float sh[256];
  float s=0.f;
  const float* fb = f12 + n*12288;
  for(int k=t;k<12288;k+=256) s += fabsf(fb[k]);
  sh[t]=s; __syncthreads();
  for(int o=128;o>0;o>>=1){ if(t<o) sh[t]+=sh[t+o]; __syncthreads(); }
  if(t==0) scalp[n]=sh[0]*(1.f/12288.f);
  __syncthreads();
  int pw=n%5, ph=(n/5)%5, bb=n/25;
  const float* xb = x + ((bb*3+0)*160 + ph*32)*160 + pw*32;
  float sm=0.f, sq=0.f;
  for(int k=t;k<1024;k+=256){ int i=k>>5,j=k&31; float v=xb[i*160+j]-MEAN0; sm+=v; sq+=v*v; }
  sh[t]=sm; __syncthreads();
  for(int o=128;o>0;o>>=1){ if(t<o) sh[t]+=sh[t+o]; __syncthreads(); }
  float smean = sh[0]*(1.f/1024.f);
  __syncthreads();
  sh[t]=sq; __syncthreads();
  for(int o=128;o>0;o>>=1){ if(t<o) sh[t]+=sh[t+o]; __syncthreads(); }
  if(t==0){ float var = sh[0]*(1.f/1024.f) - smean*smean; scalp[128+n]=sqrtf(fmaxf(var,0.f)); }
}

// ---------------- conv4: 12->64 conv3x3 per patch, NO relu ----------------
__global__ void k_conv4(const float* __restrict__ fin, const float* __restrict__ w,
                        const float* __restrict__ bias, float* __restrict__ out){
  int bid=blockIdx.x;
  int tile=bid&3, chunk=(bid>>2)&7, n=bid>>5;
  __shared__ __align__(16) float ws_[864];   // [tap108][oc8]
  __shared__ float bs[8];
  int ocb=chunk*8;
  for(int k=threadIdx.x;k<864;k+=256){ int t0=k>>3, kk=k&7; ws_[k]=w[(ocb+kk)*108+t0]; }
  if(threadIdx.x<8) bs[threadIdx.x]=bias[ocb+threadIdx.x];
  __syncthreads();
  int pix=tile*256+threadIdx.x, i=pix>>5, j=pix&31;
  float acc[8];
  #pragma unroll
  for(int k=0;k<8;k++) acc[k]=bs[k];
  const float* fb = fin + n*12288;
  for(int c=0;c<12;c++){
    const float* fc = fb + c*1024;
    #pragma unroll
    for(int dy=-1;dy<=1;dy++){
      int ii=i+dy; if((unsigned)ii>=32u) continue;
      #pragma unroll
      for(int dx=-1;dx<=1;dx++){
        int jj=j+dx; if((unsigned)jj>=32u) continue;
        float v=fc[(ii<<5)+jj];
        int t0=c*9+(dy+1)*3+(dx+1);
        const float4* wv=(const float4*)&ws_[t0*8];
        float4 wa=wv[0], wb=wv[1];
        acc[0]+=v*wa.x; acc[1]+=v*wa.y; acc[2]+=v*wa.z; acc[3]+=v*wa.w;
        acc[4]+=v*wb.x; acc[5]+=v*wb.y; acc[6]+=v*wb.z; acc[7]+=v*wb.w;
      }}}
  float* ob = out + (n*64+ocb)*1024 + pix;
  #pragma unroll
  for(int k=0;k<8;k++) ob[k*1024]=acc[k];
}

// ---------------- grouped conv 64->64 (4 groups of 16), optional relu/residual ----------------
__global__ void k_gconv(const float* __restrict__ fin, const float* __restrict__ w,
                        const float* __restrict__ bias, const float* __restrict__ resid,
                        float* __restrict__ out, int do_relu){
  int bid=blockIdx.x;
  int tile=bid&3, chunk=(bid>>2)&7, n=bid>>5;
  __shared__ __align__(16) float ws_[1152];  // [tap144][oc8]
  __shared__ float bs[8];
  int ocb=chunk*8;
  for(int k=threadIdx.x;k<1152;k+=256){ int t0=k>>3, kk=k&7; ws_[k]=w[(ocb+kk)*144+t0]; }
  if(threadIdx.x<8) bs[threadIdx.x]=bias[ocb+threadIdx.x];
  __syncthreads();
  int pix=tile*256+threadIdx.x, i=pix>>5, j=pix&31;
  float acc[8];
  #pragma unroll
  for(int k=0;k<8;k++) acc[k]=bs[k];
  int g = ocb>>4;
  const float* fb = fin + (n*64 + g*16)*1024;
  for(int c=0;c<16;c++){
    const float* fc = fb + c*1024;
    #pragma unroll
    for(int dy=-1;dy<=1;dy++){
      int ii=i+dy; if((unsigned)ii>=32u) continue;
      #pragma unroll
      for(int dx=-1;dx<=1;dx++){
        int jj=j+dx; if((unsigned)jj>=32u) continue;
        float v=fc[(ii<<5)+jj];
        int t0=c*9+(dy+1)*3+(dx+1);
        const float4* wv=(const float4*)&ws_[t0*8];
        float4 wa=wv[0], wb=wv[1];
        acc[0]+=v*wa.x; acc[1]+=v*wa.y; acc[2]+=v*wa.z; acc[3]+=v*wa.w;
        acc[4]+=v*wb.x; acc[5]+=v*wb.y; acc[6]+=v*wb.z; acc[7]+=v*wb.w;
      }}}
  float* ob = out + (n*64+ocb)*1024+pix;
  const float* rb = resid ? resid + (n*64+ocb)*1024+pix : (const float*)0;
  #pragma unroll
  for(int k=0;k<8;k++){
    float vv=acc[k];
    if(do_relu) vv=fmaxf(vv,0.f);
    if(rb) vv+=rb[k*1024];
    ob[k*1024]=vv;
  }
}

// ---------------- 1x1 conv over up to 4 concatenated 64ch sources, relu ----------------
__global__ void k_1x1(const float* __restrict__ s0, const float* __restrict__ s1,
                      const float* __restrict__ s2, const float* __restrict__ s3,
                      int ns, const float* __restrict__ w, const float* __restrict__ bias,
                      float* __restrict__ out){
  int bid=blockIdx.x;
  int tile=bid&3, chunk=(bid>>2)&7, n=bid>>5;
  int Cin=ns*64, ocb=chunk*8;
  __shared__ __align__(16) float ws_[8*256];  // [cin][oc8]
  __shared__ float bs[8];
  for(int k=threadIdx.x;k<8*Cin;k+=256){ int kk=k>>3, oo=k&7; ws_[k]=w[(ocb+oo)*Cin+kk]; }
  if(threadIdx.x<8) bs[threadIdx.x]=bias[ocb+threadIdx.x];
  __syncthreads();
  int pix=tile*256+threadIdx.x;
  float acc[8];
  #pragma unroll
  for(int k=0;k<8;k++) acc[k]=bs[k];
  const float* srcs[4]={s0,s1,s2,s3};
  for(int s=0;s<ns;s++){
    const float* sp=srcs[s]+n*65536+pix;
    for(int c=0;c<64;c++){
      float v=sp[c*1024];
      int kk=s*64+c;
      const float4* wv=(const float4*)&ws_[kk*8];
      float4 wa=wv[0], wb=wv[1];
      acc[0]+=v*wa.x; acc[1]+=v*wa.y; acc[2]+=v*wa.z; acc[3]+=v*wa.w;
      acc[4]+=v*wb.x; acc[5]+=v*wb.y; acc[6]+=v*wb.z; acc[7]+=v*wb.w;
    }
  }
  float* ob=out+(n*64+ocb)*1024+pix;
  #pragma unroll
  for(int k=0;k<8;k++) ob[k*1024]=fmaxf(acc[k],0.f);
}

// ---------------- routing select + stitch patches -> feat (SEG,64,160,160) planar f32 ----------------
__global__ void k_route(const float* __restrict__ xs, const float* __restrict__ xm,
                        const float* __restrict__ xh, const float* __restrict__ scalp,
                        const float* __restrict__ tl, const float* __restrict__ tr,
                        float* __restrict__ feat){
  int idx = blockIdx.x*256+threadIdx.x;
  int x_=idx%160, y=(idx/160)%160, c=(idx/25600)&63, b=idx/1638400;
  int n = b*25 + (y>>5)*5 + (x_>>5);
  float sz = scalp[n];
  float tl0=tl[0], tr0=tr[0], thr=tl0+tr0;
  const float* src = (sz>thr) ? xs : ((sz>=tl0 && sz<=thr) ? xm : xh);
  feat[idx] = src[((n*64+c)<<10) + ((y&31)<<5) + (x_&31)];
}

// ---------------- timep ----------------
__global__ void k_timep(const float* __restrict__ scalp, const float* __restrict__ tl,
                        const float* __restrict__ tr, float* __restrict__ dtp){
  __shared__ float sh[64];
  int b=blockIdx.x, t=threadIdx.x;
  float tl0=tl[0], tr0=tr[0], thr=tl0+tr0;
  float v=0.f;
  if(t<25){
    float sz=scalp[b*25+t];
    v = (sz>thr) ? 1e-4f*(sz-thr) : ((sz>=tl0 && sz<=thr) ? 2e-4f*tr0 : 3e-4f*(tl0-sz));
  }
  sh[t]=v; __syncthreads();
  for(int o=32;o>0;o>>=1){ if(t<o) sh[t]+=sh[t+o]; __syncthreads(); }
  if(t==0) dtp[b]=sh[0]*(1.f/25.f);
}

// ---------------- weight pack for MFMA up-convs: [tap][mb][icchunk][oc128][ic8] bf16 ----------------
__global__ void k_wprep(const float* __restrict__ w1, const float* __restrict__ w2,
                        bf16* __restrict__ wp){
  int idx = blockIdx.x*256+threadIdx.x;   // < 294912
  int conv = idx/147456; int r = idx - conv*147456;
  int tap = r>>14; int r2 = r&16383;
  int mb  = r2>>13; int r3 = r2&8191;
  int s   = r3>>10; int r4 = r3&1023;
  int ocl = r4>>3;  int j  = r4&7;
  int oc = mb*128+ocl, ic = s*8+j;
  const float* w = conv? w2 : w1;
  wp[idx] = __float2bfloat16(w[oc*576 + ic*9 + tap]);
}

// ---------------- MARM: 67->64 conv3x3 full image, relu -> NHWC bf16 ----------------
__global__ void k_marm(const float* __restrict__ x, const float* __restrict__ feat,
                       const float* __restrict__ w, const float* __restrict__ bias,
                       bf16* __restrict__ outN){
  int bid=blockIdx.x;
  int tile=bid%100, chunk=(bid/100)&7, b=bid/800;
  __shared__ __align__(16) float ws_[4824];  // [tap603][oc8]
  __shared__ float bs[8];
  int ocb=chunk*8;
  for(int k=threadIdx.x;k<4824;k+=256){ int t0=k>>3, kk=k&7; ws_[k]=w[(ocb+kk)*603+t0]; }
  if(threadIdx.x<8) bs[threadIdx.x]=bias[ocb+threadIdx.x];
  __syncthreads();
  int pix=tile*256+threadIdx.x;
  int y=pix/160, xx0=pix%160;
  float acc[8];
  #pragma unroll
  for(int k=0;k<8;k++) acc[k]=bs[k];
  #pragma unroll
  for(int c=0;c<3;c++){
    const float* xb = x + (b*3+c)*25600;
    float mc = (c==0)?MEAN0:((c==1)?MEAN1:MEAN2);
    #pragma unroll
    for(int dy=-1;dy<=1;dy++){
      int yy=y+dy; if((unsigned)yy>=160u) continue;
      #pragma unroll
      for(int dx=-1;dx<=1;dx++){
        int xc=xx0+dx; if((unsigned)xc>=160u) continue;
        float v=xb[yy*160+xc]-mc;
        int t0=c*9+(dy+1)*3+(dx+1);
        const float4* wv=(const float4*)&ws_[t0*8];
        float4 wa=wv[0], wb=wv[1];
        acc[0]+=v*wa.x; acc[1]+=v*wa.y; acc[2]+=v*wa.z; acc[3]+=v*wa.w;
        acc[4]+=v*wb.x; acc[5]+=v*wb.y; acc[6]+=v*wb.z; acc[7]+=v*wb.w;
      }}}
  for(int c=0;c<64;c++){
    const float* fb = feat + ((size_t)b*64+c)*25600;
    #pragma unroll
    for(int dy=-1;dy<=1;dy++){
      int yy=y+dy; if((unsigned)yy>=160u) continue;
      #pragma unroll
      for(int dx=-1;dx<=1;dx++){
        int xc=xx0+dx; if((unsigned)xc>=160u) continue;
        float v=fb[yy*160+xc];
        int t0=(3+c)*9+(dy+1)*3+(dx+1);
        const float4* wv=(const float4*)&ws_[t0*8];
        float4 wa=wv[0], wb=wv[1];
        acc[0]+=v*wa.x; acc[1]+=v*wa.y; acc[2]+=v*wa.z; acc[3]+=v*wa.w;
        acc[4]+=v*wb.x; acc[5]+=v*wb.y; acc[6]+=v*wb.z; acc[7]+=v*wb.w;
      }}}
  union { float4 v; bf16 h[8]; } pk;
  #pragma unroll
  for(int k=0;k<8;k++) pk.h[k]=__float2bfloat16(fmaxf(acc[k],0.f));
  *(float4*)(outN + ((size_t)b*25600 + pix)*64 + ocb) = pk.v;
}

// ---------------- MFMA up-conv: NHWC bf16 64->256 conv3x3 + bias + pixel-shuffle(2) + relu -> NHWC bf16 ----------------
// block 256 (4 waves), tile 128oc x (4 rows x 32 cols)
template<int H, int W>
__global__ __launch_bounds__(256,2) void k_convup(const bf16* __restrict__ in,
                        const bf16* __restrict__ wp, const float* __restrict__ bias,
                        bf16* __restrict__ out){
  constexpr int TX = W/32, TY = H/4, TPI = TX*TY;
  __shared__ __align__(16) __bf16 sB[8*204*8];   // [icchunk][pixel204][8] 26112 B
  __shared__ __align__(16) __bf16 sA[8*128*8];   // [icchunk][oc128][8]   16384 B
  int bid = blockIdx.x;
  int img = bid/(2*TPI); int rem = bid - img*2*TPI;
  int mb = rem/TPI; int t_ = rem - mb*TPI;
  int y0 = (t_/TX)*4, x0 = (t_ - (t_/TX)*TX)*32;
  int tid = threadIdx.x;
  const bf16* ib = in + (size_t)img*H*W*64;
  // stage B (input tile with halo): rows y0-1..y0+4, cols x0-1..x0+32
  for(int cid=tid; cid<1632; cid+=256){
    int tt = cid/204, p = cid - tt*204;
    int r = p/34, cc = p - r*34;
    int gy = y0-1+r, gx = x0-1+cc;
    float4 v = {0.f,0.f,0.f,0.f};
    if((unsigned)gy<(unsigned)H && (unsigned)gx<(unsigned)W)
      v = *(const float4*)(ib + ((size_t)(gy*W+gx)*64 + tt*8));
    *(float4*)(&sB[(size_t)(tt*204+p)*8]) = v;
  }
  // stage A tap0
  {
    const bf16* wpt = wp + ((size_t)0*2 + mb)*8192;
    #pragma unroll
    for(int k=0;k<4;k++)
      *(float4*)(&sA[(size_t)(k*256+tid)*8]) = *(const float4*)(wpt + (size_t)(k*256+tid)*8);
  }
  __syncthreads();
  int w_ = tid>>6, l = tid&63;
  int wm = w_>>1, wn = w_&1;
  int ks = l>>4, l15 = l&15;
  f32x4 acc[4][4];
  #pragma unroll
  for(int i=0;i<4;i++)
    #pragma unroll
    for(int j=0;j<4;j++) acc[i][j]=(f32x4){0.f,0.f,0.f,0.f};
  int ryc[4], cxc[4], ocl[4];
  #pragma unroll
  for(int fn=0;fn<4;fn++){ int nl = wn*64+fn*16+l15; ryc[fn]=nl>>5; cxc[fn]=nl&31; }
  #pragma unroll
  for(int fm=0;fm<4;fm++) ocl[fm] = wm*64+fm*16+l15;

  float4 pre[4];
  for(int tap=0;tap<9;tap++){
    if(tap<8){   // prefetch next tap's weights into regs (latency hidden under MFMAs)
      const bf16* wpt = wp + ((size_t)(tap+1)*2 + mb)*8192;
      #pragma unroll
      for(int k=0;k<4;k++) pre[k] = *(const float4*)(wpt + (size_t)(k*256+tid)*8);
    }
    int ty=tap/3, tx=tap-ty*3;
    #pragma unroll
    for(int kk=0;kk<2;kk++){
      int tc = kk*4+ks;
      bf16x8 a[4], b[4];
      #pragma unroll
      for(int fm=0;fm<4;fm++) a[fm] = *(const bf16x8*)(&sA[(size_t)(tc*128+ocl[fm])*8]);
      #pragma unroll
      for(int fn=0;fn<4;fn++){
        int p = (ryc[fn]+ty)*34 + cxc[fn]+tx;
        b[fn] = *(const bf16x8*)(&sB[(size_t)(tc*204+p)*8]);
      }
      #pragma unroll
      for(int fm=0;fm<4;fm++)
        #pragma unroll
        for(int fn=0;fn<4;fn++)
          acc[fm][fn] = __builtin_amdgcn_mfma_f32_16x16x32_bf16(a[fm], b[fn], acc[fm][fn], 0,0,0);
    }
    if(tap<8){
      __syncthreads();
      #pragma unroll
      for(int k=0;k<4;k++)
        *(float4*)(&sA[(size_t)(k*256+tid)*8]) = pre[k];
      __syncthreads();
    }
  }
  // epilogue: bias + relu + pixel-shuffle -> NHWC bf16 [2H][2W][64]
  bf16* ob = out + (size_t)img*4*H*W*64;
  #pragma unroll
  for(int fm=0;fm<4;fm++){
    int ocb = mb*128 + wm*64 + fm*16 + ks*4;
    int co = ocb>>2;
    #pragma unroll
    for(int j=0;j<4;j++){
      float bsv = bias[ocb+j];
      int r1 = (j>>1)&1, r2 = j&1;
      #pragma unroll
      for(int fn=0;fn<4;fn++){
        int y = y0 + ryc[fn], x = x0 + cxc[fn];
        float v = fmaxf(acc[fm][fn][j] + bsv, 0.f);
        ob[((size_t)((2*y+r1)*2*W + 2*x+r2))*64 + co] = __float2bfloat16(v);
      }
    }
  }
}

// ---------------- final conv 64->3 @640x640 NHWC bf16 in; + MEAN; writes y, xcropia, xoutputa ----------------
// 4 pixels per thread; grid 400 per image
__global__ void k_upc(const bf16* __restrict__ in, const float* __restrict__ w,
                      const float* __restrict__ bias, const float* __restrict__ scal,
                      float* __restrict__ dout, int b){
  __shared__ __align__(16) float wsm[9*64*4];   // [tap][ic][oc(3)+pad]
  for(int k=threadIdx.x;k<2304;k+=256){
    int tap=k>>8, ic=(k>>2)&63, o4=k&3;
    wsm[k] = (o4<3) ? w[(o4*64+ic)*9 + tap] : 0.f;
  }
  __syncthreads();
  int pix0 = (blockIdx.x*256 + threadIdx.x)*4;
  int y = pix0/640, x0 = pix0 - y*640;
  float a[4][3];
  float b0=bias[0], b1=bias[1], b2=bias[2];
  #pragma unroll
  for(int p=0;p<4;p++){ a[p][0]=b0; a[p][1]=b1; a[p][2]=b2; }
  for(int ty=0;ty<3;ty++){
    int gy = y+ty-1;
    if((unsigned)gy>=640u) continue;
    const bf16* row = in + (size_t)gy*640*64;
    for(int s=0;s<8;s++){
      uint4 ch[6];
      #pragma unroll
      for(int q=0;q<6;q++){
        int gx = x0-1+q;
        if((unsigned)gx<640u) ch[q] = *(const uint4*)(row + (size_t)gx*64 + s*8);
        else ch[q] = make_uint4(0,0,0,0);
      }
      float f[6][8];
      #pragma unroll
      for(int q=0;q<6;q++){
        unsigned d0=ch[q].x, d1=ch[q].y, d2=ch[q].z, d3=ch[q].w;
        f[q][0]=__uint_as_float(d0<<16); f[q][1]=__uint_as_float(d0&0xffff0000u);
        f[q][2]=__uint_as_float(d1<<16); f[q][3]=__uint_as_float(d1&0xffff0000u);
        f[q][4]=__uint_as_float(d2<<16); f[q][5]=__uint_as_float(d2&0xffff0000u);
        f[q][6]=__uint_as_float(d3<<16); f[q][7]=__uint_as_float(d3&0xffff0000u);
      }
      #pragma unroll
      for(int tx=0;tx<3;tx++){
        int tap = ty*3+tx;
        const float4* wv = (const float4*)&wsm[(tap*64 + s*8)*4];
        #pragma unroll
        for(int j=0;j<8;j++){
          float4 wj = wv[j];
          #pragma unroll
          for(int p=0;p<4;p++){
            float v = f[p+tx][j];
            a[p][0] = fmaf(v, wj.x, a[p][0]);
            a[p][1] = fmaf(v, wj.y, a[p][1]);
            a[p][2] = fmaf(v, wj.z, a[p][2]);
          }
        }
      }
    }
  }
  size_t yb=(size_t)b*3*409600;
  #pragma unroll
  for(int p=0;p<4;p++){
    int x = x0+p;
    float a0=a[p][0]+MEAN0, a1=a[p][1]+MEAN1, a2=a[p][2]+MEAN2;
    int n=b*25+(y>>7)*5+(x>>7);
    float sv=scal[128+n];
    size_t pidx=(size_t)y*640+x;
    dout[yb+pidx]=a0; dout[yb+409600+pidx]=a1; dout[yb+819200+pidx]=a2;
    dout[4915204 + (size_t)b*409600 + pidx]=sv;
    size_t xa=6553604+yb;
    dout[xa+pidx]=a0*sv; dout[xa+409600+pidx]=a1*sv; dout[xa+819200+pidx]=a2*sv;
  }
}

extern "C" void kernel_launch(void* const* d_in, const int* in_sizes, int n_in,
                              void* d_out, int out_size, void* d_ws, size_t ws_size,
                              hipStream_t stream){
  const float* x     =(const float*)d_in[0];
  const float* tl    =(const float*)d_in[1];
  const float* tr    =(const float*)d_in[2];
  const float* iicm_w=(const float*)d_in[3];
  const float* iicm_b=(const float*)d_in[4];
  const float* conv4_w=(const float*)d_in[5];
  const float* conv4_b=(const float*)d_in[6];
  const float* b1_w1 =(const float*)d_in[7];  const float* b1_b1=(const float*)d_in[8];
  const float* b1_w2 =(const float*)d_in[9];  const float* b1_b2=(const float*)d_in[10];
  const float* c1_w  =(const float*)d_in[11]; const float* c1_b =(const float*)d_in[12];
  const float* b2_w1 =(const float*)d_in[13]; const float* b2_b1=(const float*)d_in[14];
  const float* b2_w2 =(const float*)d_in[15]; const float* b2_b2=(const float*)d_in[16];
  const float* c2_w  =(const float*)d_in[17]; const float* c2_b =(const float*)d_in[18];
  const float* b3_w1 =(const float*)d_in[19]; const float* b3_b1=(const float*)d_in[20];
  const float* b3_w2 =(const float*)d_in[21]; const float* b3_b2=(const float*)d_in[22];
  const float* c3_w  =(const float*)d_in[23]; const float* c3_b =(const float*)d_in[24];
  const float* marm_w=(const float*)d_in[25]; const float* marm_b=(const float*)d_in[26];
  const float* up1_w =(const float*)d_in[27]; const float* up1_b=(const float*)d_in[28];
  const float* up2_w =(const float*)d_in[29]; const float* up2_b=(const float*)d_in[30];
  const float* upc_w =(const float*)d_in[31]; const float* upc_b=(const float*)d_in[32];

  float* ws  =(float*)d_ws;
  float* out =(float*)d_out;
  float* scal=ws;                                   // 256 floats

  const int SEG = (ws_size >= 188417024ull) ? 4 : 1;
  const int NP  = SEG*25;
  const size_t SZp = (size_t)NP*65536;

  float* f12 = ws + 256;                            // NP*12288
  float* f   = f12 + (size_t)NP*12288;
  float* xm  = f   + SZp;
  float* xh  = xm  + SZp;
  float* b1o = xh  + SZp;
  float* b2o = b1o + SZp;
  float* b3o = b2o + SZp;
  float* xs  = b3o + SZp;
  float* feat  = b2o;                               // dead after c3
  bf16*  marmN = (bf16*)b3o;                        // NHWC bf16, dead region
  bf16*  ps1   = (bf16*)xh;                         // spans xh+b1o (exact fit)
  bf16*  ps2   = (SEG==4) ? (bf16*)f                // spans f+xm (exact, dead)
                          : (bf16*)(xs + SZp);      // dedicated 52.4 MB
  bf16*  wp1   = (SEG==4) ? (bf16*)(xs + SZp - 147456)   // tail of xs (dead after route)
                          : (bf16*)((float*)ps2 + 13107200);
  bf16*  wp2   = wp1 + 147456;

  for(int b0=0;b0<4;b0+=SEG){
    int p0 = b0*25;
    const float* xseg = x + (size_t)b0*3*25600;
    float* scalp = scal + p0;

    k_iicm <<<NP*4,  256,0,stream>>>(xseg, iicm_w, iicm_b, f12);
    k_red  <<<NP,    256,0,stream>>>(f12, xseg, scalp);
    k_conv4<<<NP*32, 256,0,stream>>>(f12, conv4_w, conv4_b, f);
    // block 1 (xh as temp)
    k_gconv<<<NP*32, 256,0,stream>>>(f,  b1_w1, b1_b1, (const float*)0, xh, 1);
    k_gconv<<<NP*32, 256,0,stream>>>(xh, b1_w2, b1_b2, f,               b1o, 0);
    k_1x1  <<<NP*32, 256,0,stream>>>(f, b1o, (const float*)0, (const float*)0, 2, c1_w, c1_b, xs);
    // block 2
    k_gconv<<<NP*32, 256,0,stream>>>(xs, b2_w1, b2_b1, (const float*)0, xh, 1);
    k_gconv<<<NP*32, 256,0,stream>>>(xh, b2_w2, b2_b2, xs,              b2o, 0);
    k_1x1  <<<NP*32, 256,0,stream>>>(f, b1o, b2o, (const float*)0, 3, c2_w, c2_b, xm);
    // block 3
    k_gconv<<<NP*32, 256,0,stream>>>(xm, b3_w1, b3_b1, (const float*)0, xh, 1);
    k_gconv<<<NP*32, 256,0,stream>>>(xh, b3_w2, b3_b2, xm,              b3o, 0);
    k_1x1  <<<NP*32, 256,0,stream>>>(f, b1o, b2o, b3o, 4, c3_w, c3_b, xh);
    // routing + stitch + timep
    k_route<<<SEG*6400,256,0,stream>>>(xs, xm, xh, scalp, tl, tr, feat);
    k_timep<<<SEG,   64, 0,stream>>>(scalp, tl, tr, out + 4915200 + b0);
    // weight pack (xs dead now in mode A)
    k_wprep<<<1152,  256,0,stream>>>(up1_w, up2_w, wp1);
    // fuse + upsample chain (MFMA)
    k_marm <<<SEG*800, 256,0,stream>>>(xseg, feat, marm_w, marm_b, marmN);
    k_convup<160,160><<<SEG*2*200, 256,0,stream>>>(marmN, wp1, up1_b, ps1);
    for(int i=0;i<SEG;i++){
      k_convup<320,320><<<2*800, 256,0,stream>>>(ps1 + (size_t)i*6553600, wp2, up2_b, ps2);
      k_upc<<<400,256,0,stream>>>(ps2, upc_w, upc_b, scal, out, b0+i);
    }
  }
}

// Round 4
// 2253.995 us; speedup vs baseline: 3.1747x; 1.1782x over previous
//
#include <hip/hip_runtime.h>
#include <hip/hip_bf16.h>

typedef __hip_bfloat16 bf16;
typedef __bf16 bf16x8 __attribute__((ext_vector_type(8)));
typedef float f32x4 __attribute__((ext_vector_type(4)));

#define MEAN0 0.4488f
#define MEAN1 0.4371f
#define MEAN2 0.4040f

static __device__ __forceinline__ float cvt_in(float v){ return v; }
static __device__ __forceinline__ float cvt_in(bf16 v){ return __bfloat162float(v); }

// ---------------- IICM: 3->12 conv3x3 per 32x32 patch, relu ----------------
__global__ void k_iicm(const float* __restrict__ x, const float* __restrict__ w,
                       const float* __restrict__ bias, float* __restrict__ out){
  __shared__ __align__(16) float ws_[324];   // [tap27][oc12]
  __shared__ float bs[12];
  for(int k=threadIdx.x;k<324;k+=256){ int t0=k/12, kk=k%12; ws_[k]=w[kk*27+t0]; }
  if(threadIdx.x<12) bs[threadIdx.x]=bias[threadIdx.x];
  __syncthreads();
  int idx = blockIdx.x*256+threadIdx.x;
  int pix = idx & 1023, n = idx >> 10;
  int i = pix>>5, j = pix&31;
  int pw = n%5, ph=(n/5)%5, bb=n/25;
  float acc[12];
  #pragma unroll
  for(int k=0;k<12;k++) acc[k]=bs[k];
  #pragma unroll
  for(int c=0;c<3;c++){
    const float* xb = x + ((bb*3+c)*160 + ph*32)*160 + pw*32;
    float mc = (c==0)?MEAN0:((c==1)?MEAN1:MEAN2);
    #pragma unroll
    for(int dy=-1;dy<=1;dy++){
      int ii=i+dy; if((unsigned)ii>=32u) continue;
      #pragma unroll
      for(int dx=-1;dx<=1;dx++){
        int jj=j+dx; if((unsigned)jj>=32u) continue;
        float v = xb[ii*160+jj]-mc;
        int t0 = c*9+(dy+1)*3+(dx+1);
        const float4* wv = (const float4*)&ws_[t0*12];
        float4 w0=wv[0], w1=wv[1], w2=wv[2];
        acc[0]+=v*w0.x; acc[1]+=v*w0.y; acc[2]+=v*w0.z; acc[3]+=v*w0.w;
        acc[4]+=v*w1.x; acc[5]+=v*w1.y; acc[6]+=v*w1.z; acc[7]+=v*w1.w;
        acc[8]+=v*w2.x; acc[9]+=v*w2.y; acc[10]+=v*w2.z; acc[11]+=v*w2.w;
      }
    }
  }
  float* ob = out + n*12288 + pix;
  #pragma unroll
  for(int k=0;k<12;k++) ob[k*1024] = fmaxf(acc[k],0.f);
}

// ---------------- ssza + channel-0 std per patch ----------------
__global__ void k_red(const float* __restrict__ f12, const float* __restrict__ x,
                      float* __restrict__ scalp){
  int n = blockIdx.x, t = threadIdx.x;
  __shared__ float sh[256];
  float s=0.f;
  const float* fb = f12 + n*12288;
  for(int k=t;k<12288;k+=256) s += fabsf(fb[k]);
  sh[t]=s; __syncthreads();
  for(int o=128;o>0;o>>=1){ if(t<o) sh[t]+=sh[t+o]; __syncthreads(); }
  if(t==0) scalp[n]=sh[0]*(1.f/12288.f);
  __syncthreads();
  int pw=n%5, ph=(n/5)%5, bb=n/25;
  const float* xb = x + ((bb*3+0)*160 + ph*32)*160 + pw*32;
  float sm=0.f, sq=0.f;
  for(int k=t;k<1024;k+=256){ int i=k>>5,j=k&31; float v=xb[i*160+j]-MEAN0; sm+=v; sq+=v*v; }
  sh[t]=sm; __syncthreads();
  for(int o=128;o>0;o>>=1){ if(t<o) sh[t]+=sh[t+o]; __syncthreads(); }
  float smean = sh[0]*(1.f/1024.f);
  __syncthreads();
  sh[t]=sq; __syncthreads();
  for(int o=128;o>0;o>>=1){ if(t<o) sh[t]+=sh[t+o]; __syncthreads(); }
  if(t==0){ float var = sh[0]*(1.f/1024.f) - smean*smean; scalp[128+n]=sqrtf(fmaxf(var,0.f)); }
}

// ---------------- conv4: 12->64 conv3x3 per patch, NO relu; planar f32 + NHWC bf16 ----------------
__global__ void k_conv4(const float* __restrict__ fin, const float* __restrict__ w,
                        const float* __restrict__ bias, float* __restrict__ out,
                        bf16* __restrict__ outN){
  int bid=blockIdx.x;
  int tile=bid&3, chunk=(bid>>2)&7, n=bid>>5;
  __shared__ __align__(16) float ws_[864];   // [tap108][oc8]
  __shared__ float bs[8];
  int ocb=chunk*8;
  for(int k=threadIdx.x;k<864;k+=256){ int t0=k>>3, kk=k&7; ws_[k]=w[(ocb+kk)*108+t0]; }
  if(threadIdx.x<8) bs[threadIdx.x]=bias[ocb+threadIdx.x];
  __syncthreads();
  int pix=tile*256+threadIdx.x, i=pix>>5, j=pix&31;
  float acc[8];
  #pragma unroll
  for(int k=0;k<8;k++) acc[k]=bs[k];
  const float* fb = fin + n*12288;
  for(int c=0;c<12;c++){
    const float* fc = fb + c*1024;
    #pragma unroll
    for(int dy=-1;dy<=1;dy++){
      int ii=i+dy; if((unsigned)ii>=32u) continue;
      #pragma unroll
      for(int dx=-1;dx<=1;dx++){
        int jj=j+dx; if((unsigned)jj>=32u) continue;
        float v=fc[(ii<<5)+jj];
        int t0=c*9+(dy+1)*3+(dx+1);
        const float4* wv=(const float4*)&ws_[t0*8];
        float4 wa=wv[0], wb=wv[1];
        acc[0]+=v*wa.x; acc[1]+=v*wa.y; acc[2]+=v*wa.z; acc[3]+=v*wa.w;
        acc[4]+=v*wb.x; acc[5]+=v*wb.y; acc[6]+=v*wb.z; acc[7]+=v*wb.w;
      }}}
  float* ob = out + (n*64+ocb)*1024 + pix;
  #pragma unroll
  for(int k=0;k<8;k++) ob[k*1024]=acc[k];
  union { float4 v; bf16 h[8]; } pk;
  #pragma unroll
  for(int k=0;k<8;k++) pk.h[k]=__float2bfloat16(acc[k]);
  *(float4*)(outN + ((size_t)(n*1024+pix))*64 + ocb) = pk.v;
}

// ---------------- grouped conv 64->64 (4 groups of 16), optional relu/residual ----------------
// out (planar f32) and outN (NHWC bf16) each optional (nullable)
__global__ void k_gconv(const float* __restrict__ fin, const float* __restrict__ w,
                        const float* __restrict__ bias, const float* __restrict__ resid,
                        float* __restrict__ out, bf16* __restrict__ outN, int do_relu){
  int bid=blockIdx.x;
  int tile=bid&3, chunk=(bid>>2)&7, n=bid>>5;
  __shared__ __align__(16) float ws_[1152];  // [tap144][oc8]
  __shared__ float bs[8];
  int ocb=chunk*8;
  for(int k=threadIdx.x;k<1152;k+=256){ int t0=k>>3, kk=k&7; ws_[k]=w[(ocb+kk)*144+t0]; }
  if(threadIdx.x<8) bs[threadIdx.x]=bias[ocb+threadIdx.x];
  __syncthreads();
  int pix=tile*256+threadIdx.x, i=pix>>5, j=pix&31;
  float acc[8];
  #pragma unroll
  for(int k=0;k<8;k++) acc[k]=bs[k];
  int g = ocb>>4;
  const float* fb = fin + (n*64 + g*16)*1024;
  for(int c=0;c<16;c++){
    const float* fc = fb + c*1024;
    #pragma unroll
    for(int dy=-1;dy<=1;dy++){
      int ii=i+dy; if((unsigned)ii>=32u) continue;
      #pragma unroll
      for(int dx=-1;dx<=1;dx++){
        int jj=j+dx; if((unsigned)jj>=32u) continue;
        float v=fc[(ii<<5)+jj];
        int t0=c*9+(dy+1)*3+(dx+1);
        const float4* wv=(const float4*)&ws_[t0*8];
        float4 wa=wv[0], wb=wv[1];
        acc[0]+=v*wa.x; acc[1]+=v*wa.y; acc[2]+=v*wa.z; acc[3]+=v*wa.w;
        acc[4]+=v*wb.x; acc[5]+=v*wb.y; acc[6]+=v*wb.z; acc[7]+=v*wb.w;
      }}}
  const float* rb = resid ? resid + (n*64+ocb)*1024+pix : (const float*)0;
  float vv[8];
  #pragma unroll
  for(int k=0;k<8;k++){
    float t=acc[k];
    if(do_relu) t=fmaxf(t,0.f);
    if(rb) t+=rb[k*1024];
    vv[k]=t;
  }
  if(out){
    float* ob = out + (n*64+ocb)*1024+pix;
    #pragma unroll
    for(int k=0;k<8;k++) ob[k*1024]=vv[k];
  }
  if(outN){
    union { float4 v; bf16 h[8]; } pk;
    #pragma unroll
    for(int k=0;k<8;k++) pk.h[k]=__float2bfloat16(vv[k]);
    *(float4*)(outN + ((size_t)(n*1024+pix))*64 + ocb) = pk.v;
  }
}

// ---------------- weight pack for 1x1 GEMMs: [g][oc64][ic8] bf16, convs concatenated ----------------
__global__ void k_wcprep(const float* __restrict__ w1, const float* __restrict__ w2,
                         const float* __restrict__ w3, bf16* __restrict__ wpc){
  int idx = blockIdx.x*256+threadIdx.x;   // < 36864
  const float* w; int Cin, base;
  if(idx<8192){ w=w1; Cin=128; base=0; }
  else if(idx<20480){ w=w2; Cin=192; base=8192; }
  else { w=w3; Cin=256; base=20480; }
  int r = idx-base;
  int g = r>>9, oc = (r>>3)&63, j = r&7;
  wpc[idx] = __float2bfloat16(w[oc*Cin + g*8 + j]);
}

// ---------------- MFMA 1x1 conv (pure GEMM): NHWC bf16 sources -> planar f32 out, relu ----------------
// block 256 (4 waves), tile 64oc x 256px
__global__ __launch_bounds__(256,2) void k_1x1M(const bf16* __restrict__ s0,
                        const bf16* __restrict__ s1, const bf16* __restrict__ s2,
                        const bf16* __restrict__ s3, int ns,
                        const bf16* __restrict__ wpk, const float* __restrict__ bias,
                        float* __restrict__ out){
  __shared__ __align__(16) __bf16 sA[32*64*8];   // [g<=32][oc64][8] 32768 B
  __shared__ __align__(16) __bf16 sB[8*256*8];   // [g8][px256][8]   32768 B
  int tid = threadIdx.x;
  int px0 = blockIdx.x*256;
  for(int cid=tid; cid<ns*512; cid+=256)
    *(float4*)(&sA[(size_t)cid*8]) = ((const float4*)wpk)[cid];
  int w_ = tid>>6, l = tid&63;
  int ks = l>>4, l15 = l&63&15;
  f32x4 acc[4][4];
  #pragma unroll
  for(int i=0;i<4;i++)
    #pragma unroll
    for(int j=0;j<4;j++) acc[i][j]=(f32x4){0.f,0.f,0.f,0.f};
  const bf16* srcs[4]={s0,s1,s2,s3};
  for(int s=0;s<ns;s++){
    __syncthreads();
    const bf16* sp = srcs[s];
    #pragma unroll
    for(int it=0;it<8;it++){   // g=it, p=tid
      *(float4*)(&sB[(size_t)(it*256+tid)*8]) = *(const float4*)(sp + (size_t)(px0+tid)*64 + it*8);
    }
    __syncthreads();
    #pragma unroll
    for(int kk=0;kk<2;kk++){
      int tc = kk*4+ks;
      bf16x8 a[4], b[4];
      #pragma unroll
      for(int fm=0;fm<4;fm++) a[fm] = *(const bf16x8*)(&sA[(size_t)((s*8+tc)*64 + fm*16+l15)*8]);
      #pragma unroll
      for(int fn=0;fn<4;fn++) b[fn] = *(const bf16x8*)(&sB[(size_t)(tc*256 + w_*64+fn*16+l15)*8]);
      #pragma unroll
      for(int fm=0;fm<4;fm++)
        #pragma unroll
        for(int fn=0;fn<4;fn++)
          acc[fm][fn] = __builtin_amdgcn_mfma_f32_16x16x32_bf16(a[fm], b[fn], acc[fm][fn], 0,0,0);
    }
  }
  #pragma unroll
  for(int fm=0;fm<4;fm++){
    int oc0 = fm*16 + ks*4;
    #pragma unroll
    for(int j=0;j<4;j++){
      float bsv = bias[oc0+j];
      #pragma unroll
      for(int fn=0;fn<4;fn++){
        int pxt = px0 + w_*64 + fn*16 + l15;
        int n = pxt>>10, pix = pxt&1023;
        out[((size_t)(n*64 + oc0+j))<<10 | pix] = fmaxf(acc[fm][fn][j]+bsv, 0.f);
      }
    }
  }
}

// ---------------- routing select -> NHWC bf16 featN (96ch: 64 feat + 3 x-mean + 29 zero) ----------------
__global__ void k_routeN(const float* __restrict__ xs, const float* __restrict__ xm,
                         const float* __restrict__ xh, const float* __restrict__ xseg,
                         const float* __restrict__ scalp, const float* __restrict__ tl,
                         const float* __restrict__ tr, bf16* __restrict__ featN, int npix){
  int idx = blockIdx.x*256+threadIdx.x;
  int c8 = idx%9; int pxb = idx/9;
  int p0 = pxb*8;
  if(p0 >= npix) return;
  int b = p0/25600; int rem = p0 - b*25600;
  int y = rem/160, xx = rem - y*160;
  int n = b*25 + (y>>5)*5 + (xx>>5);
  int pp0 = ((y&31)<<5) + (xx&31);
  float sz = scalp[n];
  float tl0 = tl[0], tr0 = tr[0], thr = tl0+tr0;
  const float* src = (sz>thr) ? xs : ((sz>=tl0 && sz<=thr) ? xm : xh);
  if(c8 < 8){
    const float* sp = src + (((size_t)(n*64 + c8*8)) << 10) + pp0;
    float v[8][8];
    #pragma unroll
    for(int cc=0;cc<8;cc++){
      float4 lo = *(const float4*)(sp + cc*1024);
      float4 hi = *(const float4*)(sp + cc*1024 + 4);
      v[cc][0]=lo.x; v[cc][1]=lo.y; v[cc][2]=lo.z; v[cc][3]=lo.w;
      v[cc][4]=hi.x; v[cc][5]=hi.y; v[cc][6]=hi.z; v[cc][7]=hi.w;
    }
    #pragma unroll
    for(int k=0;k<8;k++){
      union{float4 q; bf16 h[8];} pk;
      #pragma unroll
      for(int cc=0;cc<8;cc++) pk.h[cc]=__float2bfloat16(v[cc][k]);
      *(float4*)(featN + (size_t)(p0+k)*96 + c8*8) = pk.q;
    }
  } else {
    const float* x0p = xseg + (b*3+0)*25600 + rem;
    const float* x1p = xseg + (b*3+1)*25600 + rem;
    const float* x2p = xseg + (b*3+2)*25600 + rem;
    float4 z = {0.f,0.f,0.f,0.f};
    #pragma unroll
    for(int k=0;k<8;k++){
      union{float4 q; bf16 h[8];} pk;
      pk.h[0]=__float2bfloat16(x0p[k]-MEAN0);
      pk.h[1]=__float2bfloat16(x1p[k]-MEAN1);
      pk.h[2]=__float2bfloat16(x2p[k]-MEAN2);
      #pragma unroll
      for(int cc=3;cc<8;cc++) pk.h[cc]=__float2bfloat16(0.f);
      bf16* dst = featN + (size_t)(p0+k)*96 + 64;
      *(float4*)dst = pk.q;
      *(float4*)(dst+8) = z;
      *(float4*)(dst+16) = z;
      *(float4*)(dst+24) = z;
    }
  }
}

// ---------------- timep ----------------
__global__ void k_timep(const float* __restrict__ scalp, const float* __restrict__ tl,
                        const float* __restrict__ tr, float* __restrict__ dtp){
  __shared__ float sh[64];
  int b=blockIdx.x, t=threadIdx.x;
  float tl0=tl[0], tr0=tr[0], thr=tl0+tr0;
  float v=0.f;
  if(t<25){
    float sz=scalp[b*25+t];
    v = (sz>thr) ? 1e-4f*(sz-thr) : ((sz>=tl0 && sz<=thr) ? 2e-4f*tr0 : 3e-4f*(tl0-sz));
  }
  sh[t]=v; __syncthreads();
  for(int o=32;o>0;o>>=1){ if(t<o) sh[t]+=sh[t+o]; __syncthreads(); }
  if(t==0) dtp[b]=sh[0]*(1.f/25.f);
}

// ---------------- weight pack for MFMA up-convs: [tap][mb][icchunk][oc128][ic8] bf16 ----------------
__global__ void k_wprep(const float* __restrict__ w1, const float* __restrict__ w2,
                        bf16* __restrict__ wp){
  int idx = blockIdx.x*256+threadIdx.x;   // < 294912
  int conv = idx/147456; int r = idx - conv*147456;
  int tap = r>>14; int r2 = r&16383;
  int mb  = r2>>13; int r3 = r2&8191;
  int s   = r3>>10; int r4 = r3&1023;
  int ocl = r4>>3;  int j  = r4&7;
  int oc = mb*128+ocl, ic = s*8+j;
  const float* w = conv? w2 : w1;
  wp[idx] = __float2bfloat16(w[oc*576 + ic*9 + tap]);
}

// ---------------- weight pack for MARM MFMA: [tap][icg12][oc64][ic8] bf16 (96-ch order) ----------------
__global__ void k_wmprep(const float* __restrict__ w, bf16* __restrict__ wpm){
  int idx = blockIdx.x*256+threadIdx.x;   // < 55296
  if(idx>=55296) return;
  int tap = idx/6144; int r = idx - tap*6144;
  int icg = r>>9; int oc = (r>>3)&63; int j = r&7;
  int ic = icg*8+j;
  float v = 0.f;
  if(ic<64)      v = w[oc*603 + (3+ic)*9 + tap];
  else if(ic<67) v = w[oc*603 + (ic-64)*9 + tap];
  wpm[idx] = __float2bfloat16(v);
}

// ---------------- MARM MFMA: 96ch NHWC bf16 conv3x3 -> 64ch NHWC bf16, relu ----------------
// block 256 (4 waves), tile 64oc x (8 rows x 32 cols) per image
__global__ __launch_bounds__(256,2) void k_marmM(const bf16* __restrict__ featN,
                        const bf16* __restrict__ wpm, const float* __restrict__ bias,
                        bf16* __restrict__ outN){
  __shared__ __align__(16) __bf16 sB[12*340*8];  // [icg][px340][8] 65280 B
  __shared__ __align__(16) __bf16 sA[12*64*8];   // [icg][oc64][8]  12288 B
  int bid = blockIdx.x;
  int img = bid/100; int t_ = bid - img*100;
  int y0 = (t_/5)*8, x0 = (t_%5)*32;
  int tid = threadIdx.x;
  const bf16* ib = featN + (size_t)img*25600*96;
  for(int cid=tid; cid<4080; cid+=256){
    int icg = cid/340, p = cid - icg*340;
    int r = p/34, cc = p - r*34;
    int gy = y0-1+r, gx = x0-1+cc;
    float4 v = {0.f,0.f,0.f,0.f};
    if((unsigned)gy<160u && (unsigned)gx<160u)
      v = *(const float4*)(ib + (size_t)(gy*160+gx)*96 + icg*8);
    *(float4*)(&sB[(size_t)(icg*340+p)*8]) = v;
  }
  for(int cid=tid; cid<768; cid+=256)
    *(float4*)(&sA[(size_t)cid*8]) = ((const float4*)wpm)[cid];
  __syncthreads();
  int w_ = tid>>6, l = tid&63;
  int ks = l>>4, l15 = l&15;
  f32x4 acc[4][4];
  #pragma unroll
  for(int i=0;i<4;i++)
    #pragma unroll
    for(int j=0;j<4;j++) acc[i][j]=(f32x4){0.f,0.f,0.f,0.f};
  int pr[4], pc[4];
  #pragma unroll
  for(int fn=0;fn<4;fn++){ int npx = w_*64+fn*16+l15; pr[fn]=npx>>5; pc[fn]=npx&31; }
  float4 pre[3];
  for(int tap=0;tap<9;tap++){
    if(tap<8){
      #pragma unroll
      for(int k=0;k<3;k++) pre[k] = ((const float4*)wpm)[(tap+1)*768 + k*256 + tid];
    }
    int ty=tap/3, tx=tap-ty*3;
    #pragma unroll
    for(int kk=0;kk<3;kk++){
      int tc = kk*4+ks;
      bf16x8 a[4], b[4];
      #pragma unroll
      for(int fm=0;fm<4;fm++) a[fm] = *(const bf16x8*)(&sA[(size_t)(tc*64 + fm*16+l15)*8]);
      #pragma unroll
      for(int fn=0;fn<4;fn++)
        b[fn] = *(const bf16x8*)(&sB[(size_t)(tc*340 + (pr[fn]+ty)*34 + pc[fn]+tx)*8]);
      #pragma unroll
      for(int fm=0;fm<4;fm++)
        #pragma unroll
        for(int fn=0;fn<4;fn++)
          acc[fm][fn] = __builtin_amdgcn_mfma_f32_16x16x32_bf16(a[fm], b[fn], acc[fm][fn], 0,0,0);
    }
    if(tap<8){
      __syncthreads();
      #pragma unroll
      for(int k=0;k<3;k++) ((float4*)sA)[k*256+tid] = pre[k];
      __syncthreads();
    }
  }
  bf16* ob = outN + (size_t)img*25600*64;
  #pragma unroll
  for(int fm=0;fm<4;fm++){
    int oc0 = fm*16 + ks*4;
    #pragma unroll
    for(int fn=0;fn<4;fn++){
      int px = (y0+pr[fn])*160 + x0+pc[fn];
      union{ uint2 u; bf16 h[4]; } pk;
      #pragma unroll
      for(int j=0;j<4;j++) pk.h[j]=__float2bfloat16(fmaxf(acc[fm][fn][j]+bias[oc0+j],0.f));
      *(uint2*)(ob + (size_t)px*64 + oc0) = pk.u;
    }
  }
}

// ---------------- MFMA up-conv: NHWC bf16 64->256 conv3x3 + bias + pixel-shuffle(2) + relu -> NHWC bf16 ----------------
template<int H, int W>
__global__ __launch_bounds__(256,2) void k_convup(const bf16* __restrict__ in,
                        const bf16* __restrict__ wp, const float* __restrict__ bias,
                        bf16* __restrict__ out){
  constexpr int TX = W/32, TY = H/4, TPI = TX*TY;
  __shared__ __align__(16) __bf16 sB[8*204*8];   // [icchunk][pixel204][8] 26112 B
  __shared__ __align__(16) __bf16 sA[8*128*8];   // [icchunk][oc128][8]   16384 B
  int bid = blockIdx.x;
  int img = bid/(2*TPI); int rem = bid - img*2*TPI;
  int mb = rem/TPI; int t_ = rem - mb*TPI;
  int y0 = (t_/TX)*4, x0 = (t_ - (t_/TX)*TX)*32;
  int tid = threadIdx.x;
  const bf16* ib = in + (size_t)img*H*W*64;
  for(int cid=tid; cid<1632; cid+=256){
    int tt = cid/204, p = cid - tt*204;
    int r = p/34, cc = p - r*34;
    int gy = y0-1+r, gx = x0-1+cc;
    float4 v = {0.f,0.f,0.f,0.f};
    if((unsigned)gy<(unsigned)H && (unsigned)gx<(unsigned)W)
      v = *(const float4*)(ib + ((size_t)(gy*W+gx)*64 + tt*8));
    *(float4*)(&sB[(size_t)(tt*204+p)*8]) = v;
  }
  {
    const bf16* wpt = wp + ((size_t)0*2 + mb)*8192;
    #pragma unroll
    for(int k=0;k<4;k++)
      *(float4*)(&sA[(size_t)(k*256+tid)*8]) = *(const float4*)(wpt + (size_t)(k*256+tid)*8);
  }
  __syncthreads();
  int w_ = tid>>6, l = tid&63;
  int wm = w_>>1, wn = w_&1;
  int ks = l>>4, l15 = l&15;
  f32x4 acc[4][4];
  #pragma unroll
  for(int i=0;i<4;i++)
    #pragma unroll
    for(int j=0;j<4;j++) acc[i][j]=(f32x4){0.f,0.f,0.f,0.f};
  int ryc[4], cxc[4], ocl[4];
  #pragma unroll
  for(int fn=0;fn<4;fn++){ int nl = wn*64+fn*16+l15; ryc[fn]=nl>>5; cxc[fn]=nl&31; }
  #pragma unroll
  for(int fm=0;fm<4;fm++) ocl[fm] = wm*64+fm*16+l15;

  float4 pre[4];
  for(int tap=0;tap<9;tap++){
    if(tap<8){
      const bf16* wpt = wp + ((size_t)(tap+1)*2 + mb)*8192;
      #pragma unroll
      for(int k=0;k<4;k++) pre[k] = *(const float4*)(wpt + (size_t)(k*256+tid)*8);
    }
    int ty=tap/3, tx=tap-ty*3;
    #pragma unroll
    for(int kk=0;kk<2;kk++){
      int tc = kk*4+ks;
      bf16x8 a[4], b[4];
      #pragma unroll
      for(int fm=0;fm<4;fm++) a[fm] = *(const bf16x8*)(&sA[(size_t)(tc*128+ocl[fm])*8]);
      #pragma unroll
      for(int fn=0;fn<4;fn++){
        int p = (ryc[fn]+ty)*34 + cxc[fn]+tx;
        b[fn] = *(const bf16x8*)(&sB[(size_t)(tc*204+p)*8]);
      }
      #pragma unroll
      for(int fm=0;fm<4;fm++)
        #pragma unroll
        for(int fn=0;fn<4;fn++)
          acc[fm][fn] = __builtin_amdgcn_mfma_f32_16x16x32_bf16(a[fm], b[fn], acc[fm][fn], 0,0,0);
    }
    if(tap<8){
      __syncthreads();
      #pragma unroll
      for(int k=0;k<4;k++)
        *(float4*)(&sA[(size_t)(k*256+tid)*8]) = pre[k];
      __syncthreads();
    }
  }
  bf16* ob = out + (size_t)img*4*H*W*64;
  #pragma unroll
  for(int fm=0;fm<4;fm++){
    int ocb = mb*128 + wm*64 + fm*16 + ks*4;
    int co = ocb>>2;
    #pragma unroll
    for(int j=0;j<4;j++){
      float bsv = bias[ocb+j];
      int r1 = (j>>1)&1, r2 = j&1;
      #pragma unroll
      for(int fn=0;fn<4;fn++){
        int y = y0 + ryc[fn], x = x0 + cxc[fn];
        float v = fmaxf(acc[fm][fn][j] + bsv, 0.f);
        ob[((size_t)((2*y+r1)*2*W + 2*x+r2))*64 + co] = __float2bfloat16(v);
      }
    }
  }
}

// ---------------- final conv 64->3 @640x640 NHWC bf16 in; + MEAN; writes y, xcropia, xoutputa ----------------
__global__ void k_upc(const bf16* __restrict__ in, const float* __restrict__ w,
                      const float* __restrict__ bias, const float* __restrict__ scal,
                      float* __restrict__ dout, int b){
  __shared__ __align__(16) float wsm[9*64*4];   // [tap][ic][oc(3)+pad]
  for(int k=threadIdx.x;k<2304;k+=256){
    int tap=k>>8, ic=(k>>2)&63, o4=k&3;
    wsm[k] = (o4<3) ? w[(o4*64+ic)*9 + tap] : 0.f;
  }
  __syncthreads();
  int pix0 = (blockIdx.x*256 + threadIdx.x)*4;
  int y = pix0/640, x0 = pix0 - y*640;
  float a[4][3];
  float b0=bias[0], b1=bias[1], b2=bias[2];
  #pragma unroll
  for(int p=0;p<4;p++){ a[p][0]=b0; a[p][1]=b1; a[p][2]=b2; }
  for(int ty=0;ty<3;ty++){
    int gy = y+ty-1;
    if((unsigned)gy>=640u) continue;
    const bf16* row = in + (size_t)gy*640*64;
    for(int s=0;s<8;s++){
      uint4 ch[6];
      #pragma unroll
      for(int q=0;q<6;q++){
        int gx = x0-1+q;
        if((unsigned)gx<640u) ch[q] = *(const uint4*)(row + (size_t)gx*64 + s*8);
        else ch[q] = make_uint4(0,0,0,0);
      }
      float f[6][8];
      #pragma unroll
      for(int q=0;q<6;q++){
        unsigned d0=ch[q].x, d1=ch[q].y, d2=ch[q].z, d3=ch[q].w;
        f[q][0]=__uint_as_float(d0<<16); f[q][1]=__uint_as_float(d0&0xffff0000u);
        f[q][2]=__uint_as_float(d1<<16); f[q][3]=__uint_as_float(d1&0xffff0000u);
        f[q][4]=__uint_as_float(d2<<16); f[q][5]=__uint_as_float(d2&0xffff0000u);
        f[q][6]=__uint_as_float(d3<<16); f[q][7]=__uint_as_float(d3&0xffff0000u);
      }
      #pragma unroll
      for(int tx=0;tx<3;tx++){
        int tap = ty*3+tx;
        const float4* wv = (const float4*)&wsm[(tap*64 + s*8)*4];
        #pragma unroll
        for(int j=0;j<8;j++){
          float4 wj = wv[j];
          #pragma unroll
          for(int p=0;p<4;p++){
            float v = f[p+tx][j];
            a[p][0] = fmaf(v, wj.x, a[p][0]);
            a[p][1] = fmaf(v, wj.y, a[p][1]);
            a[p][2] = fmaf(v, wj.z, a[p][2]);
          }
        }
      }
    }
  }
  size_t yb=(size_t)b*3*409600;
  #pragma unroll
  for(int p=0;p<4;p++){
    int x = x0+p;
    float a0=a[p][0]+MEAN0, a1=a[p][1]+MEAN1, a2=a[p][2]+MEAN2;
    int n=b*25+(y>>7)*5+(x>>7);
    float sv=scal[128+n];
    size_t pidx=(size_t)y*640+x;
    dout[yb+pidx]=a0; dout[yb+409600+pidx]=a1; dout[yb+819200+pidx]=a2;
    dout[4915204 + (size_t)b*409600 + pidx]=sv;
    size_t xa=6553604+yb;
    dout[xa+pidx]=a0*sv; dout[xa+409600+pidx]=a1*sv; dout[xa+819200+pidx]=a2*sv;
  }
}

extern "C" void kernel_launch(void* const* d_in, const int* in_sizes, int n_in,
                              void* d_out, int out_size, void* d_ws, size_t ws_size,
                              hipStream_t stream){
  const float* x     =(const float*)d_in[0];
  const float* tl    =(const float*)d_in[1];
  const float* tr    =(const float*)d_in[2];
  const float* iicm_w=(const float*)d_in[3];
  const float* iicm_b=(const float*)d_in[4];
  const float* conv4_w=(const float*)d_in[5];
  const float* conv4_b=(const float*)d_in[6];
  const float* b1_w1 =(const float*)d_in[7];  const float* b1_b1=(const float*)d_in[8];
  const float* b1_w2 =(const float*)d_in[9];  const float* b1_b2=(const float*)d_in[10];
  const float* c1_w  =(const float*)d_in[11]; const float* c1_b =(const float*)d_in[12];
  const float* b2_w1 =(const float*)d_in[13]; const float* b2_b1=(const float*)d_in[14];
  const float* b2_w2 =(const float*)d_in[15]; const float* b2_b2=(const float*)d_in[16];
  const float* c2_w  =(const float*)d_in[17]; const float* c2_b =(const float*)d_in[18];
  const float* b3_w1 =(const float*)d_in[19]; const float* b3_b1=(const float*)d_in[20];
  const float* b3_w2 =(const float*)d_in[21]; const float* b3_b2=(const float*)d_in[22];
  const float* c3_w  =(const float*)d_in[23]; const float* c3_b =(const float*)d_in[24];
  const float* marm_w=(const float*)d_in[25]; const float* marm_b=(const float*)d_in[26];
  const float* up1_w =(const float*)d_in[27]; const float* up1_b=(const float*)d_in[28];
  const float* up2_w =(const float*)d_in[29]; const float* up2_b=(const float*)d_in[30];
  const float* upc_w =(const float*)d_in[31]; const float* upc_b=(const float*)d_in[32];

  float* ws  =(float*)d_ws;
  float* out =(float*)d_out;
  float* scal=ws;                                   // 256 floats

  const int SEG = (ws_size >= 188417024ull) ? 4 : 1;
  const int NP  = SEG*25;
  const int NPix= NP*1024;
  const size_t SZp = (size_t)NP*65536;

  float* f12 = ws + 256;                            // NP*12288
  float* f   = f12 + (size_t)NP*12288;
  float* xm  = f   + SZp;
  float* xh  = xm  + SZp;
  float* rb1 = xh  + SZp;
  float* rb2 = rb1 + SZp;
  float* rb3 = rb2 + SZp;
  float* xs  = rb3 + SZp;
  bf16* b1oN = (bf16*)rb1;
  bf16* fN   = (bf16*)(rb1 + SZp/2);
  bf16* b2oN = (bf16*)rb2;
  bf16* b3oN = (bf16*)rb3;
  bf16* featN= (bf16*)rb2;                          // after c3 (overwrites b2oN)
  bf16* marmN= (bf16*)rb3;                          // after c3
  bf16* ps1  = (bf16*)xh;                           // spans xh+rb1
  bf16* ps2  = (SEG==4) ? (bf16*)f : (bf16*)(xs + SZp);
  bf16* wpc  = (bf16*)(f12 + (size_t)NP*12288 - 18432);  // 36864 bf16, f12 tail
  bf16 *wpm, *wp1, *wp2;
  if(SEG==4){
    wp1 = (bf16*)(xs + SZp - 147456);
    wpm = (bf16*)(xs + SZp - 147456 - 27648);
  } else {
    wpm = (bf16*)((float*)(xs + SZp) + 13107200);
    wp1 = wpm + 55296;
  }
  wp2 = wp1 + 147456;

  for(int b0=0;b0<4;b0+=SEG){
    int p0 = b0*25;
    const float* xseg = x + (size_t)b0*3*25600;
    float* scalp = scal + p0;

    k_iicm <<<NP*4,  256,0,stream>>>(xseg, iicm_w, iicm_b, f12);
    k_red  <<<NP,    256,0,stream>>>(f12, xseg, scalp);
    k_conv4<<<NP*32, 256,0,stream>>>(f12, conv4_w, conv4_b, f, fN);
    k_wcprep<<<144,  256,0,stream>>>(c1_w, c2_w, c3_w, wpc);
    // block 1 (xh as temp)
    k_gconv<<<NP*32, 256,0,stream>>>(f,  b1_w1, b1_b1, (const float*)0, xh, (bf16*)0, 1);
    k_gconv<<<NP*32, 256,0,stream>>>(xh, b1_w2, b1_b2, f, (float*)0, b1oN, 0);
    k_1x1M <<<NP*4,  256,0,stream>>>(fN, b1oN, (const bf16*)0, (const bf16*)0, 2, wpc, c1_b, xs);
    // block 2
    k_gconv<<<NP*32, 256,0,stream>>>(xs, b2_w1, b2_b1, (const float*)0, xh, (bf16*)0, 1);
    k_gconv<<<NP*32, 256,0,stream>>>(xh, b2_w2, b2_b2, xs, (float*)0, b2oN, 0);
    k_1x1M <<<NP*4,  256,0,stream>>>(fN, b1oN, b2oN, (const bf16*)0, 3, wpc+8192, c2_b, xm);
    // block 3
    k_gconv<<<NP*32, 256,0,stream>>>(xm, b3_w1, b3_b1, (const float*)0, xh, (bf16*)0, 1);
    k_gconv<<<NP*32, 256,0,stream>>>(xh, b3_w2, b3_b2, xm, (float*)0, b3oN, 0);
    k_1x1M <<<NP*4,  256,0,stream>>>(fN, b1oN, b2oN, b3oN, 4, wpc+20480, c3_b, xh);
    // routing -> NHWC featN (96ch) + timep
    k_routeN<<<(NPix/8*9+255)/256,256,0,stream>>>(xs, xm, xh, xseg, scalp, tl, tr, featN, NPix);
    k_timep<<<SEG,   64, 0,stream>>>(scalp, tl, tr, out + 4915200 + b0);
    // weight packs (xs region dead after route)
    k_wprep <<<1152, 256,0,stream>>>(up1_w, up2_w, wp1);
    k_wmprep<<<216,  256,0,stream>>>(marm_w, wpm);
    // MARM MFMA + upsample chain
    k_marmM<<<SEG*100, 256,0,stream>>>(featN, wpm, marm_b, marmN);
    k_convup<160,160><<<SEG*2*200, 256,0,stream>>>(marmN, wp1, up1_b, ps1);
    for(int i=0;i<SEG;i++){
      k_convup<320,320><<<2*800, 256,0,stream>>>(ps1 + (size_t)i*6553600, wp2, up2_b, ps2);
      k_upc<<<400,256,0,stream>>>(ps2, upc_w, upc_b, scal, out, b0+i);
    }
  }
}

// Round 5
// 1419.061 us; speedup vs baseline: 5.0425x; 1.5884x over previous
//
#include <hip/hip_runtime.h>
#include <hip/hip_bf16.h>

typedef __hip_bfloat16 bf16;
typedef __bf16 bf16x8 __attribute__((ext_vector_type(8)));
typedef float f32x4 __attribute__((ext_vector_type(4)));

#define MEAN0 0.4488f
#define MEAN1 0.4371f
#define MEAN2 0.4040f

// ---------------- IICM: 3->12 conv3x3 per 32x32 patch, relu ----------------
__global__ void k_iicm(const float* __restrict__ x, const float* __restrict__ w,
                       const float* __restrict__ bias, float* __restrict__ out){
  __shared__ __align__(16) float ws_[324];   // [tap27][oc12]
  __shared__ float bs[12];
  for(int k=threadIdx.x;k<324;k+=256){ int t0=k/12, kk=k%12; ws_[k]=w[kk*27+t0]; }
  if(threadIdx.x<12) bs[threadIdx.x]=bias[threadIdx.x];
  __syncthreads();
  int idx = blockIdx.x*256+threadIdx.x;
  int pix = idx & 1023, n = idx >> 10;
  int i = pix>>5, j = pix&31;
  int pw = n%5, ph=(n/5)%5, bb=n/25;
  float acc[12];
  #pragma unroll
  for(int k=0;k<12;k++) acc[k]=bs[k];
  #pragma unroll
  for(int c=0;c<3;c++){
    const float* xb = x + ((bb*3+c)*160 + ph*32)*160 + pw*32;
    float mc = (c==0)?MEAN0:((c==1)?MEAN1:MEAN2);
    #pragma unroll
    for(int dy=-1;dy<=1;dy++){
      int ii=i+dy; if((unsigned)ii>=32u) continue;
      #pragma unroll
      for(int dx=-1;dx<=1;dx++){
        int jj=j+dx; if((unsigned)jj>=32u) continue;
        float v = xb[ii*160+jj]-mc;
        int t0 = c*9+(dy+1)*3+(dx+1);
        const float4* wv = (const float4*)&ws_[t0*12];
        float4 w0=wv[0], w1=wv[1], w2=wv[2];
        acc[0]+=v*w0.x; acc[1]+=v*w0.y; acc[2]+=v*w0.z; acc[3]+=v*w0.w;
        acc[4]+=v*w1.x; acc[5]+=v*w1.y; acc[6]+=v*w1.z; acc[7]+=v*w1.w;
        acc[8]+=v*w2.x; acc[9]+=v*w2.y; acc[10]+=v*w2.z; acc[11]+=v*w2.w;
      }
    }
  }
  float* ob = out + n*12288 + pix;
  #pragma unroll
  for(int k=0;k<12;k++) ob[k*1024] = fmaxf(acc[k],0.f);
}

// ---------------- ssza + channel-0 std per patch ----------------
__global__ void k_red(const float* __restrict__ f12, const float* __restrict__ x,
                      float* __restrict__ scalp){
  int n = blockIdx.x, t = threadIdx.x;
  __shared__ float sh[256];
  float s=0.f;
  const float* fb = f12 + n*12288;
  for(int k=t;k<12288;k+=256) s += fabsf(fb[k]);
  sh[t]=s; __syncthreads();
  for(int o=128;o>0;o>>=1){ if(t<o) sh[t]+=sh[t+o]; __syncthreads(); }
  if(t==0) scalp[n]=sh[0]*(1.f/12288.f);
  __syncthreads();
  int pw=n%5, ph=(n/5)%5, bb=n/25;
  const float* xb = x + ((bb*3+0)*160 + ph*32)*160 + pw*32;
  float sm=0.f, sq=0.f;
  for(int k=t;k<1024;k+=256){ int i=k>>5,j=k&31; float v=xb[i*160+j]-MEAN0; sm+=v; sq+=v*v; }
  sh[t]=sm; __syncthreads();
  for(int o=128;o>0;o>>=1){ if(t<o) sh[t]+=sh[t+o]; __syncthreads(); }
  float smean = sh[0]*(1.f/1024.f);
  __syncthreads();
  sh[t]=sq; __syncthreads();
  for(int o=128;o>0;o>>=1){ if(t<o) sh[t]+=sh[t+o]; __syncthreads(); }
  if(t==0){ float var = sh[0]*(1.f/1024.f) - smean*smean; scalp[128+n]=sqrtf(fmaxf(var,0.f)); }
}

// ---------------- conv4: 12->64 conv3x3 per patch, NO relu; planar f32 + NHWC bf16 ----------------
__global__ void k_conv4(const float* __restrict__ fin, const float* __restrict__ w,
                        const float* __restrict__ bias, float* __restrict__ out,
                        bf16* __restrict__ outN){
  int bid=blockIdx.x;
  int tile=bid&3, chunk=(bid>>2)&7, n=bid>>5;
  __shared__ __align__(16) float ws_[864];   // [tap108][oc8]
  __shared__ float bs[8];
  int ocb=chunk*8;
  for(int k=threadIdx.x;k<864;k+=256){ int t0=k>>3, kk=k&7; ws_[k]=w[(ocb+kk)*108+t0]; }
  if(threadIdx.x<8) bs[threadIdx.x]=bias[ocb+threadIdx.x];
  __syncthreads();
  int pix=tile*256+threadIdx.x, i=pix>>5, j=pix&31;
  float acc[8];
  #pragma unroll
  for(int k=0;k<8;k++) acc[k]=bs[k];
  const float* fb = fin + n*12288;
  for(int c=0;c<12;c++){
    const float* fc = fb + c*1024;
    #pragma unroll
    for(int dy=-1;dy<=1;dy++){
      int ii=i+dy; if((unsigned)ii>=32u) continue;
      #pragma unroll
      for(int dx=-1;dx<=1;dx++){
        int jj=j+dx; if((unsigned)jj>=32u) continue;
        float v=fc[(ii<<5)+jj];
        int t0=c*9+(dy+1)*3+(dx+1);
        const float4* wv=(const float4*)&ws_[t0*8];
        float4 wa=wv[0], wb=wv[1];
        acc[0]+=v*wa.x; acc[1]+=v*wa.y; acc[2]+=v*wa.z; acc[3]+=v*wa.w;
        acc[4]+=v*wb.x; acc[5]+=v*wb.y; acc[6]+=v*wb.z; acc[7]+=v*wb.w;
      }}}
  float* ob = out + (n*64+ocb)*1024 + pix;
  #pragma unroll
  for(int k=0;k<8;k++) ob[k*1024]=acc[k];
  union { float4 v; bf16 h[8]; } pk;
  #pragma unroll
  for(int k=0;k<8;k++) pk.h[k]=__float2bfloat16(acc[k]);
  *(float4*)(outN + ((size_t)(n*1024+pix))*64 + ocb) = pk.v;
}

// ---------------- grouped conv 64->64 (4 groups of 16), optional relu/residual ----------------
__global__ void k_gconv(const float* __restrict__ fin, const float* __restrict__ w,
                        const float* __restrict__ bias, const float* __restrict__ resid,
                        float* __restrict__ out, bf16* __restrict__ outN, int do_relu){
  int bid=blockIdx.x;
  int tile=bid&3, chunk=(bid>>2)&7, n=bid>>5;
  __shared__ __align__(16) float ws_[1152];  // [tap144][oc8]
  __shared__ float bs[8];
  int ocb=chunk*8;
  for(int k=threadIdx.x;k<1152;k+=256){ int t0=k>>3, kk=k&7; ws_[k]=w[(ocb+kk)*144+t0]; }
  if(threadIdx.x<8) bs[threadIdx.x]=bias[ocb+threadIdx.x];
  __syncthreads();
  int pix=tile*256+threadIdx.x, i=pix>>5, j=pix&31;
  float acc[8];
  #pragma unroll
  for(int k=0;k<8;k++) acc[k]=bs[k];
  int g = ocb>>4;
  const float* fb = fin + (n*64 + g*16)*1024;
  for(int c=0;c<16;c++){
    const float* fc = fb + c*1024;
    #pragma unroll
    for(int dy=-1;dy<=1;dy++){
      int ii=i+dy; if((unsigned)ii>=32u) continue;
      #pragma unroll
      for(int dx=-1;dx<=1;dx++){
        int jj=j+dx; if((unsigned)jj>=32u) continue;
        float v=fc[(ii<<5)+jj];
        int t0=c*9+(dy+1)*3+(dx+1);
        const float4* wv=(const float4*)&ws_[t0*8];
        float4 wa=wv[0], wb=wv[1];
        acc[0]+=v*wa.x; acc[1]+=v*wa.y; acc[2]+=v*wa.z; acc[3]+=v*wa.w;
        acc[4]+=v*wb.x; acc[5]+=v*wb.y; acc[6]+=v*wb.z; acc[7]+=v*wb.w;
      }}}
  const float* rb = resid ? resid + (n*64+ocb)*1024+pix : (const float*)0;
  float vv[8];
  #pragma unroll
  for(int k=0;k<8;k++){
    float t=acc[k];
    if(do_relu) t=fmaxf(t,0.f);
    if(rb) t+=rb[k*1024];
    vv[k]=t;
  }
  if(out){
    float* ob = out + (n*64+ocb)*1024+pix;
    #pragma unroll
    for(int k=0;k<8;k++) ob[k*1024]=vv[k];
  }
  if(outN){
    union { float4 v; bf16 h[8]; } pk;
    #pragma unroll
    for(int k=0;k<8;k++) pk.h[k]=__float2bfloat16(vv[k]);
    *(float4*)(outN + ((size_t)(n*1024+pix))*64 + ocb) = pk.v;
  }
}

// ---------------- weight pack for 1x1 GEMMs: [g][oc64][ic8] bf16, convs concatenated ----------------
__global__ void k_wcprep(const float* __restrict__ w1, const float* __restrict__ w2,
                         const float* __restrict__ w3, bf16* __restrict__ wpc){
  int idx = blockIdx.x*256+threadIdx.x;   // < 36864
  const float* w; int Cin, base;
  if(idx<8192){ w=w1; Cin=128; base=0; }
  else if(idx<20480){ w=w2; Cin=192; base=8192; }
  else { w=w3; Cin=256; base=20480; }
  int r = idx-base;
  int g = r>>9, oc = (r>>3)&63, j = r&7;
  wpc[idx] = __float2bfloat16(w[oc*Cin + g*8 + j]);
}

// ---------------- MFMA 1x1 conv (pure GEMM): NHWC bf16 sources -> planar f32 out, relu ----------------
__global__ __launch_bounds__(256,2) void k_1x1M(const bf16* __restrict__ s0,
                        const bf16* __restrict__ s1, const bf16* __restrict__ s2,
                        const bf16* __restrict__ s3, int ns,
                        const bf16* __restrict__ wpk, const float* __restrict__ bias,
                        float* __restrict__ out){
  __shared__ __align__(16) __bf16 sA[32*64*8];   // [g<=32][oc64][8] 32768 B
  __shared__ __align__(16) __bf16 sB[8*256*8];   // [g8][px256][8]   32768 B
  int tid = threadIdx.x;
  int px0 = blockIdx.x*256;
  for(int cid=tid; cid<ns*512; cid+=256)
    *(float4*)(&sA[(size_t)cid*8]) = ((const float4*)wpk)[cid];
  int w_ = tid>>6, l = tid&63;
  int ks = l>>4, l15 = l&63&15;
  f32x4 acc[4][4];
  #pragma unroll
  for(int i=0;i<4;i++)
    #pragma unroll
    for(int j=0;j<4;j++) acc[i][j]=(f32x4){0.f,0.f,0.f,0.f};
  const bf16* srcs[4]={s0,s1,s2,s3};
  for(int s=0;s<ns;s++){
    __syncthreads();
    const bf16* sp = srcs[s];
    #pragma unroll
    for(int it=0;it<8;it++){
      *(float4*)(&sB[(size_t)(it*256+tid)*8]) = *(const float4*)(sp + (size_t)(px0+tid)*64 + it*8);
    }
    __syncthreads();
    #pragma unroll
    for(int kk=0;kk<2;kk++){
      int tc = kk*4+ks;
      bf16x8 a[4], b[4];
      #pragma unroll
      for(int fm=0;fm<4;fm++) a[fm] = *(const bf16x8*)(&sA[(size_t)((s*8+tc)*64 + fm*16+l15)*8]);
      #pragma unroll
      for(int fn=0;fn<4;fn++) b[fn] = *(const bf16x8*)(&sB[(size_t)(tc*256 + w_*64+fn*16+l15)*8]);
      #pragma unroll
      for(int fm=0;fm<4;fm++)
        #pragma unroll
        for(int fn=0;fn<4;fn++)
          acc[fm][fn] = __builtin_amdgcn_mfma_f32_16x16x32_bf16(a[fm], b[fn], acc[fm][fn], 0,0,0);
    }
  }
  #pragma unroll
  for(int fm=0;fm<4;fm++){
    int oc0 = fm*16 + ks*4;
    #pragma unroll
    for(int j=0;j<4;j++){
      float bsv = bias[oc0+j];
      #pragma unroll
      for(int fn=0;fn<4;fn++){
        int pxt = px0 + w_*64 + fn*16 + l15;
        int n = pxt>>10, pix = pxt&1023;
        out[((size_t)(n*64 + oc0+j))<<10 | pix] = fmaxf(acc[fm][fn][j]+bsv, 0.f);
      }
    }
  }
}

// ---------------- routing select -> NHWC bf16 featN (96ch: 64 feat + 3 x-mean + 29 zero) ----------------
__global__ void k_routeN(const float* __restrict__ xs, const float* __restrict__ xm,
                         const float* __restrict__ xh, const float* __restrict__ xseg,
                         const float* __restrict__ scalp, const float* __restrict__ tl,
                         const float* __restrict__ tr, bf16* __restrict__ featN, int npix){
  int idx = blockIdx.x*256+threadIdx.x;
  int c8 = idx%9; int pxb = idx/9;
  int p0 = pxb*8;
  if(p0 >= npix) return;
  int b = p0/25600; int rem = p0 - b*25600;
  int y = rem/160, xx = rem - y*160;
  int n = b*25 + (y>>5)*5 + (xx>>5);
  int pp0 = ((y&31)<<5) + (xx&31);
  float sz = scalp[n];
  float tl0 = tl[0], tr0 = tr[0], thr = tl0+tr0;
  const float* src = (sz>thr) ? xs : ((sz>=tl0 && sz<=thr) ? xm : xh);
  if(c8 < 8){
    const float* sp = src + (((size_t)(n*64 + c8*8)) << 10) + pp0;
    float v[8][8];
    #pragma unroll
    for(int cc=0;cc<8;cc++){
      float4 lo = *(const float4*)(sp + cc*1024);
      float4 hi = *(const float4*)(sp + cc*1024 + 4);
      v[cc][0]=lo.x; v[cc][1]=lo.y; v[cc][2]=lo.z; v[cc][3]=lo.w;
      v[cc][4]=hi.x; v[cc][5]=hi.y; v[cc][6]=hi.z; v[cc][7]=hi.w;
    }
    #pragma unroll
    for(int k=0;k<8;k++){
      union{float4 q; bf16 h[8];} pk;
      #pragma unroll
      for(int cc=0;cc<8;cc++) pk.h[cc]=__float2bfloat16(v[cc][k]);
      *(float4*)(featN + (size_t)(p0+k)*96 + c8*8) = pk.q;
    }
  } else {
    const float* x0p = xseg + (b*3+0)*25600 + rem;
    const float* x1p = xseg + (b*3+1)*25600 + rem;
    const float* x2p = xseg + (b*3+2)*25600 + rem;
    float4 z = {0.f,0.f,0.f,0.f};
    #pragma unroll
    for(int k=0;k<8;k++){
      union{float4 q; bf16 h[8];} pk;
      pk.h[0]=__float2bfloat16(x0p[k]-MEAN0);
      pk.h[1]=__float2bfloat16(x1p[k]-MEAN1);
      pk.h[2]=__float2bfloat16(x2p[k]-MEAN2);
      #pragma unroll
      for(int cc=3;cc<8;cc++) pk.h[cc]=__float2bfloat16(0.f);
      bf16* dst = featN + (size_t)(p0+k)*96 + 64;
      *(float4*)dst = pk.q;
      *(float4*)(dst+8) = z;
      *(float4*)(dst+16) = z;
      *(float4*)(dst+24) = z;
    }
  }
}

// ---------------- timep ----------------
__global__ void k_timep(const float* __restrict__ scalp, const float* __restrict__ tl,
                        const float* __restrict__ tr, float* __restrict__ dtp){
  __shared__ float sh[64];
  int b=blockIdx.x, t=threadIdx.x;
  float tl0=tl[0], tr0=tr[0], thr=tl0+tr0;
  float v=0.f;
  if(t<25){
    float sz=scalp[b*25+t];
    v = (sz>thr) ? 1e-4f*(sz-thr) : ((sz>=tl0 && sz<=thr) ? 2e-4f*tr0 : 3e-4f*(tl0-sz));
  }
  sh[t]=v; __syncthreads();
  for(int o=32;o>0;o>>=1){ if(t<o) sh[t]+=sh[t+o]; __syncthreads(); }
  if(t==0) dtp[b]=sh[0]*(1.f/25.f);
}

// ---------------- weight pack for MFMA up-convs: [tap][mb][icchunk][oc128][ic8] bf16 ----------------
__global__ void k_wprep(const float* __restrict__ w1, const float* __restrict__ w2,
                        bf16* __restrict__ wp){
  int idx = blockIdx.x*256+threadIdx.x;   // < 294912
  int conv = idx/147456; int r = idx - conv*147456;
  int tap = r>>14; int r2 = r&16383;
  int mb  = r2>>13; int r3 = r2&8191;
  int s   = r3>>10; int r4 = r3&1023;
  int ocl = r4>>3;  int j  = r4&7;
  int oc = mb*128+ocl, ic = s*8+j;
  const float* w = conv? w2 : w1;
  wp[idx] = __float2bfloat16(w[oc*576 + ic*9 + tap]);
}

// ---------------- weight pack for MARM MFMA: [tap][icg12][oc64][ic8] bf16 (96-ch order) ----------------
__global__ void k_wmprep(const float* __restrict__ w, bf16* __restrict__ wpm){
  int idx = blockIdx.x*256+threadIdx.x;   // < 55296
  if(idx>=55296) return;
  int tap = idx/6144; int r = idx - tap*6144;
  int icg = r>>9; int oc = (r>>3)&63; int j = r&7;
  int ic = icg*8+j;
  float v = 0.f;
  if(ic<64)      v = w[oc*603 + (3+ic)*9 + tap];
  else if(ic<67) v = w[oc*603 + (ic-64)*9 + tap];
  wpm[idx] = __float2bfloat16(v);
}

// ---------------- weight pack for final conv MFMA: [tap][tc8][oc16][ic8] bf16 (oc>=3 zero) ----------------
__global__ void k_wuprep(const float* __restrict__ w, bf16* __restrict__ wpu){
  int idx = blockIdx.x*256+threadIdx.x;   // < 9216
  if(idx>=9216) return;
  int tap = idx>>10; int r = idx&1023;
  int tc = r>>7; int oc = (r>>3)&15; int j = r&7;
  int ic = tc*8+j;
  float v = (oc<3) ? w[oc*576 + ic*9 + tap] : 0.f;
  wpu[idx] = __float2bfloat16(v);
}

// ---------------- MARM MFMA: 96ch NHWC bf16 conv3x3 -> 64ch NHWC bf16, relu ----------------
__global__ __launch_bounds__(256,2) void k_marmM(const bf16* __restrict__ featN,
                        const bf16* __restrict__ wpm, const float* __restrict__ bias,
                        bf16* __restrict__ outN){
  __shared__ __align__(16) __bf16 sB[12*340*8];  // [icg][px340][8] 65280 B
  __shared__ __align__(16) __bf16 sA[12*64*8];   // [icg][oc64][8]  12288 B
  int bid = blockIdx.x;
  int img = bid/100; int t_ = bid - img*100;
  int y0 = (t_/5)*8, x0 = (t_%5)*32;
  int tid = threadIdx.x;
  const bf16* ib = featN + (size_t)img*25600*96;
  for(int cid=tid; cid<4080; cid+=256){
    int icg = cid/340, p = cid - icg*340;
    int r = p/34, cc = p - r*34;
    int gy = y0-1+r, gx = x0-1+cc;
    float4 v = {0.f,0.f,0.f,0.f};
    if((unsigned)gy<160u && (unsigned)gx<160u)
      v = *(const float4*)(ib + (size_t)(gy*160+gx)*96 + icg*8);
    *(float4*)(&sB[(size_t)(icg*340+p)*8]) = v;
  }
  for(int cid=tid; cid<768; cid+=256)
    *(float4*)(&sA[(size_t)cid*8]) = ((const float4*)wpm)[cid];
  __syncthreads();
  int w_ = tid>>6, l = tid&63;
  int ks = l>>4, l15 = l&15;
  f32x4 acc[4][4];
  #pragma unroll
  for(int i=0;i<4;i++)
    #pragma unroll
    for(int j=0;j<4;j++) acc[i][j]=(f32x4){0.f,0.f,0.f,0.f};
  int pr[4], pc[4];
  #pragma unroll
  for(int fn=0;fn<4;fn++){ int npx = w_*64+fn*16+l15; pr[fn]=npx>>5; pc[fn]=npx&31; }
  float4 pre[3];
  for(int tap=0;tap<9;tap++){
    if(tap<8){
      #pragma unroll
      for(int k=0;k<3;k++) pre[k] = ((const float4*)wpm)[(tap+1)*768 + k*256 + tid];
    }
    int ty=tap/3, tx=tap-ty*3;
    #pragma unroll
    for(int kk=0;kk<3;kk++){
      int tc = kk*4+ks;
      bf16x8 a[4], b[4];
      #pragma unroll
      for(int fm=0;fm<4;fm++) a[fm] = *(const bf16x8*)(&sA[(size_t)(tc*64 + fm*16+l15)*8]);
      #pragma unroll
      for(int fn=0;fn<4;fn++)
        b[fn] = *(const bf16x8*)(&sB[(size_t)(tc*340 + (pr[fn]+ty)*34 + pc[fn]+tx)*8]);
      #pragma unroll
      for(int fm=0;fm<4;fm++)
        #pragma unroll
        for(int fn=0;fn<4;fn++)
          acc[fm][fn] = __builtin_amdgcn_mfma_f32_16x16x32_bf16(a[fm], b[fn], acc[fm][fn], 0,0,0);
    }
    if(tap<8){
      __syncthreads();
      #pragma unroll
      for(int k=0;k<3;k++) ((float4*)sA)[k*256+tid] = pre[k];
      __syncthreads();
    }
  }
  bf16* ob = outN + (size_t)img*25600*64;
  #pragma unroll
  for(int fm=0;fm<4;fm++){
    int oc0 = fm*16 + ks*4;
    #pragma unroll
    for(int fn=0;fn<4;fn++){
      int px = (y0+pr[fn])*160 + x0+pc[fn];
      union{ uint2 u; bf16 h[4]; } pk;
      #pragma unroll
      for(int j=0;j<4;j++) pk.h[j]=__float2bfloat16(fmaxf(acc[fm][fn][j]+bias[oc0+j],0.f));
      *(uint2*)(ob + (size_t)px*64 + oc0) = pk.u;
    }
  }
}

// ---------------- MFMA up-conv: NHWC bf16 64->256 conv3x3 + bias + pixel-shuffle(2) + relu -> NHWC bf16 ----------------
template<int H, int W>
__global__ __launch_bounds__(256,2) void k_convup(const bf16* __restrict__ in,
                        const bf16* __restrict__ wp, const float* __restrict__ bias,
                        bf16* __restrict__ out){
  constexpr int TX = W/32, TY = H/4, TPI = TX*TY;
  __shared__ __align__(16) __bf16 sB[8*204*8];   // [icchunk][pixel204][8] 26112 B
  __shared__ __align__(16) __bf16 sA[8*128*8];   // [icchunk][oc128][8]   16384 B
  int bid = blockIdx.x;
  int img = bid/(2*TPI); int rem = bid - img*2*TPI;
  int mb = rem/TPI; int t_ = rem - mb*TPI;
  int y0 = (t_/TX)*4, x0 = (t_ - (t_/TX)*TX)*32;
  int tid = threadIdx.x;
  const bf16* ib = in + (size_t)img*H*W*64;
  for(int cid=tid; cid<1632; cid+=256){
    int tt = cid/204, p = cid - tt*204;
    int r = p/34, cc = p - r*34;
    int gy = y0-1+r, gx = x0-1+cc;
    float4 v = {0.f,0.f,0.f,0.f};
    if((unsigned)gy<(unsigned)H && (unsigned)gx<(unsigned)W)
      v = *(const float4*)(ib + ((size_t)(gy*W+gx)*64 + tt*8));
    *(float4*)(&sB[(size_t)(tt*204+p)*8]) = v;
  }
  {
    const bf16* wpt = wp + ((size_t)0*2 + mb)*8192;
    #pragma unroll
    for(int k=0;k<4;k++)
      *(float4*)(&sA[(size_t)(k*256+tid)*8]) = *(const float4*)(wpt + (size_t)(k*256+tid)*8);
  }
  __syncthreads();
  int w_ = tid>>6, l = tid&63;
  int wm = w_>>1, wn = w_&1;
  int ks = l>>4, l15 = l&15;
  f32x4 acc[4][4];
  #pragma unroll
  for(int i=0;i<4;i++)
    #pragma unroll
    for(int j=0;j<4;j++) acc[i][j]=(f32x4){0.f,0.f,0.f,0.f};
  int ryc[4], cxc[4], ocl[4];
  #pragma unroll
  for(int fn=0;fn<4;fn++){ int nl = wn*64+fn*16+l15; ryc[fn]=nl>>5; cxc[fn]=nl&31; }
  #pragma unroll
  for(int fm=0;fm<4;fm++) ocl[fm] = wm*64+fm*16+l15;

  float4 pre[4];
  for(int tap=0;tap<9;tap++){
    if(tap<8){
      const bf16* wpt = wp + ((size_t)(tap+1)*2 + mb)*8192;
      #pragma unroll
      for(int k=0;k<4;k++) pre[k] = *(const float4*)(wpt + (size_t)(k*256+tid)*8);
    }
    int ty=tap/3, tx=tap-ty*3;
    #pragma unroll
    for(int kk=0;kk<2;kk++){
      int tc = kk*4+ks;
      bf16x8 a[4], b[4];
      #pragma unroll
      for(int fm=0;fm<4;fm++) a[fm] = *(const bf16x8*)(&sA[(size_t)(tc*128+ocl[fm])*8]);
      #pragma unroll
      for(int fn=0;fn<4;fn++){
        int p = (ryc[fn]+ty)*34 + cxc[fn]+tx;
        b[fn] = *(const bf16x8*)(&sB[(size_t)(tc*204+p)*8]);
      }
      #pragma unroll
      for(int fm=0;fm<4;fm++)
        #pragma unroll
        for(int fn=0;fn<4;fn++)
          acc[fm][fn] = __builtin_amdgcn_mfma_f32_16x16x32_bf16(a[fm], b[fn], acc[fm][fn], 0,0,0);
    }
    if(tap<8){
      __syncthreads();
      #pragma unroll
      for(int k=0;k<4;k++)
        *(float4*)(&sA[(size_t)(k*256+tid)*8]) = pre[k];
      __syncthreads();
    }
  }
  bf16* ob = out + (size_t)img*4*H*W*64;
  #pragma unroll
  for(int fm=0;fm<4;fm++){
    int ocb = mb*128 + wm*64 + fm*16 + ks*4;
    int co = ocb>>2;
    #pragma unroll
    for(int j=0;j<4;j++){
      float bsv = bias[ocb+j];
      int r1 = (j>>1)&1, r2 = j&1;
      #pragma unroll
      for(int fn=0;fn<4;fn++){
        int y = y0 + ryc[fn], x = x0 + cxc[fn];
        float v = fmaxf(acc[fm][fn][j] + bsv, 0.f);
        ob[((size_t)((2*y+r1)*2*W + 2*x+r2))*64 + co] = __float2bfloat16(v);
      }
    }
  }
}

// ---------------- final conv MFMA: 64->3(pad16) @640x640 NHWC bf16; + MEAN; writes y, xcropia, xoutputa ----------------
// block 256 (4 waves), tile 4 rows x 64 cols; LDS halo 6x66x64ch with chunk-XOR swizzle
__global__ __launch_bounds__(256,2) void k_upcM(const bf16* __restrict__ in,
                        const bf16* __restrict__ wpu, const float* __restrict__ bias,
                        const float* __restrict__ scal, float* __restrict__ dout, int b){
  __shared__ __align__(16) __bf16 sB[396*64];   // 50688 B
  int tid = threadIdx.x;
  int t_ = blockIdx.x;
  int by0 = (t_/10)*4, bx0 = (t_%10)*64;
  for(int cid=tid; cid<3168; cid+=256){
    int px = cid>>3, c = cid&7;
    int hr = px/66, hc = px - hr*66;
    int gy = by0-1+hr, gx = bx0-1+hc;
    float4 v = {0.f,0.f,0.f,0.f};
    if((unsigned)gy<640u && (unsigned)gx<640u)
      v = *(const float4*)(in + ((size_t)(gy*640+gx))*64 + c*8);
    int slot = c ^ (px&7);
    *(float4*)(&sB[(size_t)px*64 + slot*8]) = v;
  }
  int w_ = tid>>6, l = tid&63;
  int ks = l>>4, l15 = l&15;
  // preload all weight fragments into VGPRs (9 taps x 2 K-halves)
  bf16x8 afr[9][2];
  #pragma unroll
  for(int tap=0;tap<9;tap++)
    #pragma unroll
    for(int kk=0;kk<2;kk++)
      afr[tap][kk] = *(const bf16x8*)(wpu + (size_t)((tap*8 + kk*4+ks)*16 + l15)*8);
  __syncthreads();
  f32x4 acc[4];
  #pragma unroll
  for(int fn=0;fn<4;fn++) acc[fn]=(f32x4){0.f,0.f,0.f,0.f};
  int r = w_;
  int cxc[4];
  #pragma unroll
  for(int fn=0;fn<4;fn++) cxc[fn]=fn*16+l15;
  for(int tap=0;tap<9;tap++){
    int ty=tap/3, tx=tap-ty*3;
    #pragma unroll
    for(int kk=0;kk<2;kk++){
      int tc = kk*4+ks;
      #pragma unroll
      for(int fn=0;fn<4;fn++){
        int ph = (r+ty)*66 + cxc[fn]+tx;
        int slot = tc ^ (ph&7);
        bf16x8 bb = *(const bf16x8*)(&sB[(size_t)ph*64 + slot*8]);
        acc[fn] = __builtin_amdgcn_mfma_f32_16x16x32_bf16(afr[tap][kk], bb, acc[fn], 0,0,0);
      }
    }
  }
  if(ks==0){
    float c0=bias[0]+MEAN0, c1=bias[1]+MEAN1, c2=bias[2]+MEAN2;
    int gy = by0 + r;
    size_t yb=(size_t)b*3*409600;
    #pragma unroll
    for(int fn=0;fn<4;fn++){
      int gx = bx0 + cxc[fn];
      float a0=acc[fn][0]+c0, a1=acc[fn][1]+c1, a2=acc[fn][2]+c2;
      int n=b*25+(gy>>7)*5+(gx>>7);
      float sv=scal[128+n];
      size_t pidx=(size_t)gy*640+gx;
      dout[yb+pidx]=a0; dout[yb+409600+pidx]=a1; dout[yb+819200+pidx]=a2;
      dout[4915204 + (size_t)b*409600 + pidx]=sv;
      size_t xa=6553604+yb;
      dout[xa+pidx]=a0*sv; dout[xa+409600+pidx]=a1*sv; dout[xa+819200+pidx]=a2*sv;
    }
  }
}

extern "C" void kernel_launch(void* const* d_in, const int* in_sizes, int n_in,
                              void* d_out, int out_size, void* d_ws, size_t ws_size,
                              hipStream_t stream){
  const float* x     =(const float*)d_in[0];
  const float* tl    =(const float*)d_in[1];
  const float* tr    =(const float*)d_in[2];
  const float* iicm_w=(const float*)d_in[3];
  const float* iicm_b=(const float*)d_in[4];
  const float* conv4_w=(const float*)d_in[5];
  const float* conv4_b=(const float*)d_in[6];
  const float* b1_w1 =(const float*)d_in[7];  const float* b1_b1=(const float*)d_in[8];
  const float* b1_w2 =(const float*)d_in[9];  const float* b1_b2=(const float*)d_in[10];
  const float* c1_w  =(const float*)d_in[11]; const float* c1_b =(const float*)d_in[12];
  const float* b2_w1 =(const float*)d_in[13]; const float* b2_b1=(const float*)d_in[14];
  const float* b2_w2 =(const float*)d_in[15]; const float* b2_b2=(const float*)d_in[16];
  const float* c2_w  =(const float*)d_in[17]; const float* c2_b =(const float*)d_in[18];
  const float* b3_w1 =(const float*)d_in[19]; const float* b3_b1=(const float*)d_in[20];
  const float* b3_w2 =(const float*)d_in[21]; const float* b3_b2=(const float*)d_in[22];
  const float* c3_w  =(const float*)d_in[23]; const float* c3_b =(const float*)d_in[24];
  const float* marm_w=(const float*)d_in[25]; const float* marm_b=(const float*)d_in[26];
  const float* up1_w =(const float*)d_in[27]; const float* up1_b=(const float*)d_in[28];
  const float* up2_w =(const float*)d_in[29]; const float* up2_b=(const float*)d_in[30];
  const float* upc_w =(const float*)d_in[31]; const float* upc_b=(const float*)d_in[32];

  float* ws  =(float*)d_ws;
  float* out =(float*)d_out;
  float* scal=ws;                                   // 256 floats

  const int SEG = (ws_size >= 188417024ull) ? 4 : 1;
  const int NP  = SEG*25;
  const int NPix= NP*1024;
  const size_t SZp = (size_t)NP*65536;

  float* f12 = ws + 256;                            // NP*12288
  float* f   = f12 + (size_t)NP*12288;
  float* xm  = f   + SZp;
  float* xh  = xm  + SZp;
  float* rb1 = xh  + SZp;
  float* rb2 = rb1 + SZp;
  float* rb3 = rb2 + SZp;
  float* xs  = rb3 + SZp;
  bf16* b1oN = (bf16*)rb1;
  bf16* fN   = (bf16*)(rb1 + SZp/2);
  bf16* b2oN = (bf16*)rb2;
  bf16* b3oN = (bf16*)rb3;
  bf16* featN= (bf16*)rb2;                          // after c3 (overwrites b2oN)
  bf16* marmN= (bf16*)rb3;                          // after c3
  bf16* ps1  = (bf16*)xh;                           // spans xh+rb1
  bf16* ps2  = (SEG==4) ? (bf16*)f : (bf16*)(xs + SZp);
  bf16* wpc  = (bf16*)(f12 + (size_t)NP*12288 - 18432);  // 36864 bf16, f12 tail
  bf16 *wpm, *wp1, *wp2, *wpu;
  if(SEG==4){
    float* tailf = xs + SZp;
    wp1 = (bf16*)(tailf - 147456);
    wpm = (bf16*)(tailf - 147456 - 27648);
    wpu = (bf16*)(tailf - 147456 - 27648 - 4608);
  } else {
    wpm = (bf16*)((float*)(xs + SZp) + 13107200);
    wp1 = wpm + 55296;
    wpu = wp1 + 294912 + 9216;  // placed after wp2 region
  }
  wp2 = wp1 + 147456;

  for(int b0=0;b0<4;b0+=SEG){
    int p0 = b0*25;
    const float* xseg = x + (size_t)b0*3*25600;
    float* scalp = scal + p0;

    k_iicm <<<NP*4,  256,0,stream>>>(xseg, iicm_w, iicm_b, f12);
    k_red  <<<NP,    256,0,stream>>>(f12, xseg, scalp);
    k_conv4<<<NP*32, 256,0,stream>>>(f12, conv4_w, conv4_b, f, fN);
    k_wcprep<<<144,  256,0,stream>>>(c1_w, c2_w, c3_w, wpc);
    // block 1 (xh as temp)
    k_gconv<<<NP*32, 256,0,stream>>>(f,  b1_w1, b1_b1, (const float*)0, xh, (bf16*)0, 1);
    k_gconv<<<NP*32, 256,0,stream>>>(xh, b1_w2, b1_b2, f, (float*)0, b1oN, 0);
    k_1x1M <<<NP*4,  256,0,stream>>>(fN, b1oN, (const bf16*)0, (const bf16*)0, 2, wpc, c1_b, xs);
    // block 2
    k_gconv<<<NP*32, 256,0,stream>>>(xs, b2_w1, b2_b1, (const float*)0, xh, (bf16*)0, 1);
    k_gconv<<<NP*32, 256,0,stream>>>(xh, b2_w2, b2_b2, xs, (float*)0, b2oN, 0);
    k_1x1M <<<NP*4,  256,0,stream>>>(fN, b1oN, b2oN, (const bf16*)0, 3, wpc+8192, c2_b, xm);
    // block 3
    k_gconv<<<NP*32, 256,0,stream>>>(xm, b3_w1, b3_b1, (const float*)0, xh, (bf16*)0, 1);
    k_gconv<<<NP*32, 256,0,stream>>>(xh, b3_w2, b3_b2, xm, (float*)0, b3oN, 0);
    k_1x1M <<<NP*4,  256,0,stream>>>(fN, b1oN, b2oN, b3oN, 4, wpc+20480, c3_b, xh);
    // routing -> NHWC featN (96ch) + timep
    k_routeN<<<(NPix/8*9+255)/256,256,0,stream>>>(xs, xm, xh, xseg, scalp, tl, tr, featN, NPix);
    k_timep<<<SEG,   64, 0,stream>>>(scalp, tl, tr, out + 4915200 + b0);
    // weight packs (xs region dead after route)
    k_wprep <<<1152, 256,0,stream>>>(up1_w, up2_w, wp1);
    k_wmprep<<<216,  256,0,stream>>>(marm_w, wpm);
    k_wuprep<<<36,   256,0,stream>>>(upc_w, wpu);
    // MARM MFMA + upsample chain
    k_marmM<<<SEG*100, 256,0,stream>>>(featN, wpm, marm_b, marmN);
    k_convup<160,160><<<SEG*2*200, 256,0,stream>>>(marmN, wp1, up1_b, ps1);
    for(int i=0;i<SEG;i++){
      k_convup<320,320><<<2*800, 256,0,stream>>>(ps1 + (size_t)i*6553600, wp2, up2_b, ps2);
      k_upcM<<<1600,256,0,stream>>>(ps2, wpu, upc_b, scal, out, b0+i);
    }
  }
}

// Round 6
// 887.541 us; speedup vs baseline: 8.0623x; 1.5989x over previous
//
#include <hip/hip_runtime.h>
#include <hip/hip_bf16.h>

typedef __hip_bfloat16 bf16;
typedef __bf16 bf16x8 __attribute__((ext_vector_type(8)));
typedef float f32x4 __attribute__((ext_vector_type(4)));

#define MEAN0 0.4488f
#define MEAN1 0.4371f
#define MEAN2 0.4040f

// ---------------- IICM: 3->12 conv3x3 per 32x32 patch, relu ----------------
__global__ void k_iicm(const float* __restrict__ x, const float* __restrict__ w,
                       const float* __restrict__ bias, float* __restrict__ out){
  __shared__ __align__(16) float ws_[324];   // [tap27][oc12]
  __shared__ float bs[12];
  for(int k=threadIdx.x;k<324;k+=256){ int t0=k/12, kk=k%12; ws_[k]=w[kk*27+t0]; }
  if(threadIdx.x<12) bs[threadIdx.x]=bias[threadIdx.x];
  __syncthreads();
  int idx = blockIdx.x*256+threadIdx.x;
  int pix = idx & 1023, n = idx >> 10;
  int i = pix>>5, j = pix&31;
  int pw = n%5, ph=(n/5)%5, bb=n/25;
  float acc[12];
  #pragma unroll
  for(int k=0;k<12;k++) acc[k]=bs[k];
  #pragma unroll
  for(int c=0;c<3;c++){
    const float* xb = x + ((bb*3+c)*160 + ph*32)*160 + pw*32;
    float mc = (c==0)?MEAN0:((c==1)?MEAN1:MEAN2);
    #pragma unroll
    for(int dy=-1;dy<=1;dy++){
      int ii=i+dy; if((unsigned)ii>=32u) continue;
      #pragma unroll
      for(int dx=-1;dx<=1;dx++){
        int jj=j+dx; if((unsigned)jj>=32u) continue;
        float v = xb[ii*160+jj]-mc;
        int t0 = c*9+(dy+1)*3+(dx+1);
        const float4* wv = (const float4*)&ws_[t0*12];
        float4 w0=wv[0], w1=wv[1], w2=wv[2];
        acc[0]+=v*w0.x; acc[1]+=v*w0.y; acc[2]+=v*w0.z; acc[3]+=v*w0.w;
        acc[4]+=v*w1.x; acc[5]+=v*w1.y; acc[6]+=v*w1.z; acc[7]+=v*w1.w;
        acc[8]+=v*w2.x; acc[9]+=v*w2.y; acc[10]+=v*w2.z; acc[11]+=v*w2.w;
      }
    }
  }
  float* ob = out + n*12288 + pix;
  #pragma unroll
  for(int k=0;k<12;k++) ob[k*1024] = fmaxf(acc[k],0.f);
}

// ---------------- ssza + channel-0 std per patch ----------------
__global__ void k_red(const float* __restrict__ f12, const float* __restrict__ x,
                      float* __restrict__ scalp){
  int n = blockIdx.x, t = threadIdx.x;
  __shared__ float sh[256];
  float s=0.f;
  const float* fb = f12 + n*12288;
  for(int k=t;k<12288;k+=256) s += fabsf(fb[k]);
  sh[t]=s; __syncthreads();
  for(int o=128;o>0;o>>=1){ if(t<o) sh[t]+=sh[t+o]; __syncthreads(); }
  if(t==0) scalp[n]=sh[0]*(1.f/12288.f);
  __syncthreads();
  int pw=n%5, ph=(n/5)%5, bb=n/25;
  const float* xb = x + ((bb*3+0)*160 + ph*32)*160 + pw*32;
  float sm=0.f, sq=0.f;
  for(int k=t;k<1024;k+=256){ int i=k>>5,j=k&31; float v=xb[i*160+j]-MEAN0; sm+=v; sq+=v*v; }
  sh[t]=sm; __syncthreads();
  for(int o=128;o>0;o>>=1){ if(t<o) sh[t]+=sh[t+o]; __syncthreads(); }
  float smean = sh[0]*(1.f/1024.f);
  __syncthreads();
  sh[t]=sq; __syncthreads();
  for(int o=128;o>0;o>>=1){ if(t<o) sh[t]+=sh[t+o]; __syncthreads(); }
  if(t==0){ float var = sh[0]*(1.f/1024.f) - smean*smean; scalp[128+n]=sqrtf(fmaxf(var,0.f)); }
}

// ---------------- conv4: 12->64 conv3x3 per patch, NO relu -> NHWC bf16 ----------------
__global__ void k_conv4(const float* __restrict__ fin, const float* __restrict__ w,
                        const float* __restrict__ bias, bf16* __restrict__ outN){
  int bid=blockIdx.x;
  int tile=bid&3, chunk=(bid>>2)&7, n=bid>>5;
  __shared__ __align__(16) float ws_[864];   // [tap108][oc8]
  __shared__ float bs[8];
  int ocb=chunk*8;
  for(int k=threadIdx.x;k<864;k+=256){ int t0=k>>3, kk=k&7; ws_[k]=w[(ocb+kk)*108+t0]; }
  if(threadIdx.x<8) bs[threadIdx.x]=bias[ocb+threadIdx.x];
  __syncthreads();
  int pix=tile*256+threadIdx.x, i=pix>>5, j=pix&31;
  float acc[8];
  #pragma unroll
  for(int k=0;k<8;k++) acc[k]=bs[k];
  const float* fb = fin + n*12288;
  for(int c=0;c<12;c++){
    const float* fc = fb + c*1024;
    #pragma unroll
    for(int dy=-1;dy<=1;dy++){
      int ii=i+dy; if((unsigned)ii>=32u) continue;
      #pragma unroll
      for(int dx=-1;dx<=1;dx++){
        int jj=j+dx; if((unsigned)jj>=32u) continue;
        float v=fc[(ii<<5)+jj];
        int t0=c*9+(dy+1)*3+(dx+1);
        const float4* wv=(const float4*)&ws_[t0*8];
        float4 wa=wv[0], wb=wv[1];
        acc[0]+=v*wa.x; acc[1]+=v*wa.y; acc[2]+=v*wa.z; acc[3]+=v*wa.w;
        acc[4]+=v*wb.x; acc[5]+=v*wb.y; acc[6]+=v*wb.z; acc[7]+=v*wb.w;
      }}}
  union { float4 v; bf16 h[8]; } pk;
  #pragma unroll
  for(int k=0;k<8;k++) pk.h[k]=__float2bfloat16(acc[k]);
  *(float4*)(outN + ((size_t)(n*1024+pix))*64 + ocb) = pk.v;
}

// ---------------- weight pack for dense-ified grouped convs: [conv6][tap][icchunk][oc64][ic8] ----------------
__global__ void k_wgprep(const float* __restrict__ w0, const float* __restrict__ w1,
                         const float* __restrict__ w2, const float* __restrict__ w3,
                         const float* __restrict__ w4, const float* __restrict__ w5,
                         bf16* __restrict__ wpg){
  int idx = blockIdx.x*256+threadIdx.x;   // < 221184
  if(idx>=221184) return;
  int conv = idx/36864; int r = idx - conv*36864;
  int tap = r>>12; int r2 = r&4095;
  int s = r2>>9; int oc = (r2>>3)&63; int j = r2&7;
  int ic = s*8+j, g = oc>>4, il = ic - g*16;
  const float* w = (conv==0)?w0:(conv==1)?w1:(conv==2)?w2:(conv==3)?w3:(conv==4)?w4:w5;
  float v = ((unsigned)il<16u) ? w[oc*144 + il*9 + tap] : 0.f;
  wpg[idx] = __float2bfloat16(v);
}

// ---------------- dense MFMA grouped conv: NHWC bf16 64->64 conv3x3 per patch, relu/resid ----------------
// block 128 (2 waves), tile 64oc x (4 rows x 32 cols); grid NP*8
__global__ __launch_bounds__(128,8) void k_gconvM(const bf16* __restrict__ in,
                        const bf16* __restrict__ wg, const float* __restrict__ bias,
                        const bf16* __restrict__ resid, bf16* __restrict__ out, int do_relu){
  __shared__ __align__(16) __bf16 sB[8*204*8];   // 26112 B
  __shared__ __align__(16) __bf16 sA[8*64*8];    // 8192 B
  int tid = threadIdx.x;
  int bid = blockIdx.x;
  int n = bid>>3, tile = bid&7;
  int y0 = tile*4;
  const bf16* ib = in + (size_t)n*65536;
  for(int cid=tid; cid<1632; cid+=128){
    int s = cid/204, p = cid - s*204;
    int r = p/34, c = p - r*34;
    int gy = y0-1+r, gx = c-1;
    float4 v = {0.f,0.f,0.f,0.f};
    if((unsigned)gy<32u && (unsigned)gx<32u)
      v = *(const float4*)(ib + (size_t)((gy<<5)+gx)*64 + s*8);
    *(float4*)(&sB[(size_t)(s*204+p)*8]) = v;
  }
  for(int cid=tid; cid<512; cid+=128)
    *(float4*)(&sA[(size_t)cid*8]) = ((const float4*)wg)[cid];
  __syncthreads();
  int w_ = tid>>6, l = tid&63;
  int ks = l>>4, l15 = l&15;
  f32x4 acc[4][4];
  #pragma unroll
  for(int i=0;i<4;i++)
    #pragma unroll
    for(int j=0;j<4;j++) acc[i][j]=(f32x4){0.f,0.f,0.f,0.f};
  int pr[4], pc[4];
  #pragma unroll
  for(int fn=0;fn<4;fn++){ int npx = w_*64+fn*16+l15; pr[fn]=npx>>5; pc[fn]=npx&31; }
  float4 pre[4];
  for(int tap=0;tap<9;tap++){
    if(tap<8){
      #pragma unroll
      for(int k=0;k<4;k++) pre[k] = ((const float4*)wg)[(tap+1)*512 + k*128 + tid];
    }
    int ty=tap/3, tx=tap-ty*3;
    #pragma unroll
    for(int kk=0;kk<2;kk++){
      int tc = kk*4+ks;
      bf16x8 a[4], b[4];
      #pragma unroll
      for(int fm=0;fm<4;fm++) a[fm] = *(const bf16x8*)(&sA[(size_t)(tc*64 + fm*16+l15)*8]);
      #pragma unroll
      for(int fn=0;fn<4;fn++)
        b[fn] = *(const bf16x8*)(&sB[(size_t)(tc*204 + (pr[fn]+ty)*34 + pc[fn]+tx)*8]);
      #pragma unroll
      for(int fm=0;fm<4;fm++)
        #pragma unroll
        for(int fn=0;fn<4;fn++)
          acc[fm][fn] = __builtin_amdgcn_mfma_f32_16x16x32_bf16(a[fm], b[fn], acc[fm][fn], 0,0,0);
    }
    if(tap<8){
      __syncthreads();
      #pragma unroll
      for(int k=0;k<4;k++) ((float4*)sA)[k*128+tid] = pre[k];
      __syncthreads();
    }
  }
  bf16* ob = out + (size_t)n*65536;
  const bf16* rb = resid ? resid + (size_t)n*65536 : (const bf16*)0;
  #pragma unroll
  for(int fm=0;fm<4;fm++){
    int oc0 = fm*16 + ks*4;
    #pragma unroll
    for(int fn=0;fn<4;fn++){
      int pxl = (y0+pr[fn])*32 + pc[fn];
      float v[4];
      #pragma unroll
      for(int j=0;j<4;j++){
        float t = acc[fm][fn][j] + bias[oc0+j];
        if(do_relu) t = fmaxf(t,0.f);
        v[j]=t;
      }
      if(rb){
        union{ uint2 u; bf16 h[4]; } ru;
        ru.u = *(const uint2*)(rb + (size_t)pxl*64 + oc0);
        #pragma unroll
        for(int j=0;j<4;j++) v[j] += __bfloat162float(ru.h[j]);
      }
      union{ uint2 u; bf16 h[4]; } pk;
      #pragma unroll
      for(int j=0;j<4;j++) pk.h[j]=__float2bfloat16(v[j]);
      *(uint2*)(ob + (size_t)pxl*64 + oc0) = pk.u;
    }
  }
}

// ---------------- weight pack for 1x1 GEMMs ----------------
__global__ void k_wcprep(const float* __restrict__ w1, const float* __restrict__ w2,
                         const float* __restrict__ w3, bf16* __restrict__ wpc){
  int idx = blockIdx.x*256+threadIdx.x;   // < 36864
  const float* w; int Cin, base;
  if(idx<8192){ w=w1; Cin=128; base=0; }
  else if(idx<20480){ w=w2; Cin=192; base=8192; }
  else { w=w3; Cin=256; base=20480; }
  int r = idx-base;
  int g = r>>9, oc = (r>>3)&63, j = r&7;
  wpc[idx] = __float2bfloat16(w[oc*Cin + g*8 + j]);
}

// ---------------- MFMA 1x1 conv (pure GEMM): NHWC bf16 sources -> NHWC bf16 out, relu ----------------
__global__ __launch_bounds__(256,2) void k_1x1M(const bf16* __restrict__ s0,
                        const bf16* __restrict__ s1, const bf16* __restrict__ s2,
                        const bf16* __restrict__ s3, int ns,
                        const bf16* __restrict__ wpk, const float* __restrict__ bias,
                        bf16* __restrict__ outN){
  __shared__ __align__(16) __bf16 sA[32*64*8];   // 32768 B
  __shared__ __align__(16) __bf16 sB[8*256*8];   // 32768 B
  int tid = threadIdx.x;
  int px0 = blockIdx.x*256;
  for(int cid=tid; cid<ns*512; cid+=256)
    *(float4*)(&sA[(size_t)cid*8]) = ((const float4*)wpk)[cid];
  int w_ = tid>>6, l = tid&63;
  int ks = l>>4, l15 = l&15;
  f32x4 acc[4][4];
  #pragma unroll
  for(int i=0;i<4;i++)
    #pragma unroll
    for(int j=0;j<4;j++) acc[i][j]=(f32x4){0.f,0.f,0.f,0.f};
  const bf16* srcs[4]={s0,s1,s2,s3};
  for(int s=0;s<ns;s++){
    __syncthreads();
    const bf16* sp = srcs[s];
    #pragma unroll
    for(int it=0;it<8;it++){
      *(float4*)(&sB[(size_t)(it*256+tid)*8]) = *(const float4*)(sp + (size_t)(px0+tid)*64 + it*8);
    }
    __syncthreads();
    #pragma unroll
    for(int kk=0;kk<2;kk++){
      int tc = kk*4+ks;
      bf16x8 a[4], b[4];
      #pragma unroll
      for(int fm=0;fm<4;fm++) a[fm] = *(const bf16x8*)(&sA[(size_t)((s*8+tc)*64 + fm*16+l15)*8]);
      #pragma unroll
      for(int fn=0;fn<4;fn++) b[fn] = *(const bf16x8*)(&sB[(size_t)(tc*256 + w_*64+fn*16+l15)*8]);
      #pragma unroll
      for(int fm=0;fm<4;fm++)
        #pragma unroll
        for(int fn=0;fn<4;fn++)
          acc[fm][fn] = __builtin_amdgcn_mfma_f32_16x16x32_bf16(a[fm], b[fn], acc[fm][fn], 0,0,0);
    }
  }
  #pragma unroll
  for(int fm=0;fm<4;fm++){
    int oc0 = fm*16 + ks*4;
    #pragma unroll
    for(int fn=0;fn<4;fn++){
      int pxt = px0 + w_*64 + fn*16 + l15;
      union{ uint2 u; bf16 h[4]; } pk;
      #pragma unroll
      for(int j=0;j<4;j++) pk.h[j]=__float2bfloat16(fmaxf(acc[fm][fn][j]+bias[oc0+j],0.f));
      *(uint2*)(outN + (size_t)pxt*64 + oc0) = pk.u;
    }
  }
}

// ---------------- routing select (NHWC bf16 srcs) -> NHWC bf16 featN (96ch) ----------------
__global__ void k_routeN(const bf16* __restrict__ xs, const bf16* __restrict__ xm,
                         const bf16* __restrict__ xh, const float* __restrict__ xseg,
                         const float* __restrict__ scalp, const float* __restrict__ tl,
                         const float* __restrict__ tr, bf16* __restrict__ featN, int npix){
  int idx = blockIdx.x*256+threadIdx.x;
  int c = idx%12; int px = idx/12;
  if(px >= npix) return;
  int b = px/25600; int rem = px - b*25600;
  int y = rem/160, xx = rem - y*160;
  int n = b*25 + (y>>5)*5 + (xx>>5);
  float sz = scalp[n];
  float tl0 = tl[0], tr0 = tr[0], thr = tl0+tr0;
  const bf16* src = (sz>thr) ? xs : ((sz>=tl0 && sz<=thr) ? xm : xh);
  uint4 v = make_uint4(0,0,0,0);
  if(c < 8){
    v = *(const uint4*)(src + ((size_t)n*1024 + ((y&31)<<5) + (xx&31))*64 + c*8);
  } else if(c == 8){
    union{ uint4 q; bf16 h[8]; } pk;
    pk.q = make_uint4(0,0,0,0);
    pk.h[0]=__float2bfloat16(xseg[(b*3+0)*25600 + rem]-MEAN0);
    pk.h[1]=__float2bfloat16(xseg[(b*3+1)*25600 + rem]-MEAN1);
    pk.h[2]=__float2bfloat16(xseg[(b*3+2)*25600 + rem]-MEAN2);
    v = pk.q;
  }
  *(uint4*)(featN + (size_t)px*96 + c*8) = v;
}

// ---------------- timep ----------------
__global__ void k_timep(const float* __restrict__ scalp, const float* __restrict__ tl,
                        const float* __restrict__ tr, float* __restrict__ dtp){
  __shared__ float sh[64];
  int b=blockIdx.x, t=threadIdx.x;
  float tl0=tl[0], tr0=tr[0], thr=tl0+tr0;
  float v=0.f;
  if(t<25){
    float sz=scalp[b*25+t];
    v = (sz>thr) ? 1e-4f*(sz-thr) : ((sz>=tl0 && sz<=thr) ? 2e-4f*tr0 : 3e-4f*(tl0-sz));
  }
  sh[t]=v; __syncthreads();
  for(int o=32;o>0;o>>=1){ if(t<o) sh[t]+=sh[t+o]; __syncthreads(); }
  if(t==0) dtp[b]=sh[0]*(1.f/25.f);
}

// ---------------- weight pack for MFMA up-convs ----------------
__global__ void k_wprep(const float* __restrict__ w1, const float* __restrict__ w2,
                        bf16* __restrict__ wp){
  int idx = blockIdx.x*256+threadIdx.x;   // < 294912
  int conv = idx/147456; int r = idx - conv*147456;
  int tap = r>>14; int r2 = r&16383;
  int mb  = r2>>13; int r3 = r2&8191;
  int s   = r3>>10; int r4 = r3&1023;
  int ocl = r4>>3;  int j  = r4&7;
  int oc = mb*128+ocl, ic = s*8+j;
  const float* w = conv? w2 : w1;
  wp[idx] = __float2bfloat16(w[oc*576 + ic*9 + tap]);
}

// ---------------- weight pack for MARM MFMA ----------------
__global__ void k_wmprep(const float* __restrict__ w, bf16* __restrict__ wpm){
  int idx = blockIdx.x*256+threadIdx.x;   // < 55296
  if(idx>=55296) return;
  int tap = idx/6144; int r = idx - tap*6144;
  int icg = r>>9; int oc = (r>>3)&63; int j = r&7;
  int ic = icg*8+j;
  float v = 0.f;
  if(ic<64)      v = w[oc*603 + (3+ic)*9 + tap];
  else if(ic<67) v = w[oc*603 + (ic-64)*9 + tap];
  wpm[idx] = __float2bfloat16(v);
}

// ---------------- weight pack for final conv MFMA ----------------
__global__ void k_wuprep(const float* __restrict__ w, bf16* __restrict__ wpu){
  int idx = blockIdx.x*256+threadIdx.x;   // < 9216
  if(idx>=9216) return;
  int tap = idx>>10; int r = idx&1023;
  int tc = r>>7; int oc = (r>>3)&15; int j = r&7;
  int ic = tc*8+j;
  float v = (oc<3) ? w[oc*576 + ic*9 + tap] : 0.f;
  wpu[idx] = __float2bfloat16(v);
}

// ---------------- MARM MFMA: 96ch NHWC bf16 conv3x3 -> 64ch NHWC bf16, relu ----------------
__global__ __launch_bounds__(256,2) void k_marmM(const bf16* __restrict__ featN,
                        const bf16* __restrict__ wpm, const float* __restrict__ bias,
                        bf16* __restrict__ outN){
  __shared__ __align__(16) __bf16 sB[12*340*8];  // 65280 B
  __shared__ __align__(16) __bf16 sA[12*64*8];   // 12288 B
  int bid = blockIdx.x;
  int img = bid/100; int t_ = bid - img*100;
  int y0 = (t_/5)*8, x0 = (t_%5)*32;
  int tid = threadIdx.x;
  const bf16* ib = featN + (size_t)img*25600*96;
  for(int cid=tid; cid<4080; cid+=256){
    int icg = cid/340, p = cid - icg*340;
    int r = p/34, cc = p - r*34;
    int gy = y0-1+r, gx = x0-1+cc;
    float4 v = {0.f,0.f,0.f,0.f};
    if((unsigned)gy<160u && (unsigned)gx<160u)
      v = *(const float4*)(ib + (size_t)(gy*160+gx)*96 + icg*8);
    *(float4*)(&sB[(size_t)(icg*340+p)*8]) = v;
  }
  for(int cid=tid; cid<768; cid+=256)
    *(float4*)(&sA[(size_t)cid*8]) = ((const float4*)wpm)[cid];
  __syncthreads();
  int w_ = tid>>6, l = tid&63;
  int ks = l>>4, l15 = l&15;
  f32x4 acc[4][4];
  #pragma unroll
  for(int i=0;i<4;i++)
    #pragma unroll
    for(int j=0;j<4;j++) acc[i][j]=(f32x4){0.f,0.f,0.f,0.f};
  int pr[4], pc[4];
  #pragma unroll
  for(int fn=0;fn<4;fn++){ int npx = w_*64+fn*16+l15; pr[fn]=npx>>5; pc[fn]=npx&31; }
  float4 pre[3];
  for(int tap=0;tap<9;tap++){
    if(tap<8){
      #pragma unroll
      for(int k=0;k<3;k++) pre[k] = ((const float4*)wpm)[(tap+1)*768 + k*256 + tid];
    }
    int ty=tap/3, tx=tap-ty*3;
    #pragma unroll
    for(int kk=0;kk<3;kk++){
      int tc = kk*4+ks;
      bf16x8 a[4], b[4];
      #pragma unroll
      for(int fm=0;fm<4;fm++) a[fm] = *(const bf16x8*)(&sA[(size_t)(tc*64 + fm*16+l15)*8]);
      #pragma unroll
      for(int fn=0;fn<4;fn++)
        b[fn] = *(const bf16x8*)(&sB[(size_t)(tc*340 + (pr[fn]+ty)*34 + pc[fn]+tx)*8]);
      #pragma unroll
      for(int fm=0;fm<4;fm++)
        #pragma unroll
        for(int fn=0;fn<4;fn++)
          acc[fm][fn] = __builtin_amdgcn_mfma_f32_16x16x32_bf16(a[fm], b[fn], acc[fm][fn], 0,0,0);
    }
    if(tap<8){
      __syncthreads();
      #pragma unroll
      for(int k=0;k<3;k++) ((float4*)sA)[k*256+tid] = pre[k];
      __syncthreads();
    }
  }
  bf16* ob = outN + (size_t)img*25600*64;
  #pragma unroll
  for(int fm=0;fm<4;fm++){
    int oc0 = fm*16 + ks*4;
    #pragma unroll
    for(int fn=0;fn<4;fn++){
      int px = (y0+pr[fn])*160 + x0+pc[fn];
      union{ uint2 u; bf16 h[4]; } pk;
      #pragma unroll
      for(int j=0;j<4;j++) pk.h[j]=__float2bfloat16(fmaxf(acc[fm][fn][j]+bias[oc0+j],0.f));
      *(uint2*)(ob + (size_t)px*64 + oc0) = pk.u;
    }
  }
}

// ---------------- MFMA up-conv: 64->256 conv3x3 + bias + pixel-shuffle(2) + relu -> NHWC bf16 ----------------
// epilogue via LDS transpose -> contiguous 16B stores
template<int H, int W>
__global__ __launch_bounds__(256,3) void k_convup(const bf16* __restrict__ in,
                        const bf16* __restrict__ wp, const float* __restrict__ bias,
                        bf16* __restrict__ out){
  constexpr int TX = W/32, TY = H/4, TPI = TX*TY;
  __shared__ __align__(16) char smem[42496];
  __bf16* sB = (__bf16*)smem;              // 8*204*8 = 26112 B
  __bf16* sA = (__bf16*)(smem + 26112);    // 8*128*8 = 16384 B
  int bid = blockIdx.x;
  int img = bid/(2*TPI); int rem = bid - img*2*TPI;
  int mb = rem/TPI; int t_ = rem - mb*TPI;
  int y0 = (t_/TX)*4, x0 = (t_ - (t_/TX)*TX)*32;
  int tid = threadIdx.x;
  const bf16* ib = in + (size_t)img*H*W*64;
  for(int cid=tid; cid<1632; cid+=256){
    int tt = cid/204, p = cid - tt*204;
    int r = p/34, cc = p - r*34;
    int gy = y0-1+r, gx = x0-1+cc;
    float4 v = {0.f,0.f,0.f,0.f};
    if((unsigned)gy<(unsigned)H && (unsigned)gx<(unsigned)W)
      v = *(const float4*)(ib + ((size_t)(gy*W+gx)*64 + tt*8));
    *(float4*)(&sB[(size_t)(tt*204+p)*8]) = v;
  }
  {
    const bf16* wpt = wp + ((size_t)mb)*8192;
    #pragma unroll
    for(int k=0;k<4;k++)
      *(float4*)(&sA[(size_t)(k*256+tid)*8]) = *(const float4*)(wpt + (size_t)(k*256+tid)*8);
  }
  __syncthreads();
  int w_ = tid>>6, l = tid&63;
  int wm = w_>>1, wn = w_&1;
  int ks = l>>4, l15 = l&15;
  f32x4 acc[4][4];
  #pragma unroll
  for(int i=0;i<4;i++)
    #pragma unroll
    for(int j=0;j<4;j++) acc[i][j]=(f32x4){0.f,0.f,0.f,0.f};
  int ryc[4], cxc[4], ocl[4];
  #pragma unroll
  for(int fn=0;fn<4;fn++){ int nl = wn*64+fn*16+l15; ryc[fn]=nl>>5; cxc[fn]=nl&31; }
  #pragma unroll
  for(int fm=0;fm<4;fm++) ocl[fm] = wm*64+fm*16+l15;

  float4 pre[4];
  for(int tap=0;tap<9;tap++){
    if(tap<8){
      const bf16* wpt = wp + ((size_t)(tap+1)*2 + mb)*8192;
      #pragma unroll
      for(int k=0;k<4;k++) pre[k] = *(const float4*)(wpt + (size_t)(k*256+tid)*8);
    }
    int ty=tap/3, tx=tap-ty*3;
    #pragma unroll
    for(int kk=0;kk<2;kk++){
      int tc = kk*4+ks;
      bf16x8 a[4], b[4];
      #pragma unroll
      for(int fm=0;fm<4;fm++) a[fm] = *(const bf16x8*)(&sA[(size_t)(tc*128+ocl[fm])*8]);
      #pragma unroll
      for(int fn=0;fn<4;fn++){
        int p = (ryc[fn]+ty)*34 + cxc[fn]+tx;
        b[fn] = *(const bf16x8*)(&sB[(size_t)(tc*204+p)*8]);
      }
      #pragma unroll
      for(int fm=0;fm<4;fm++)
        #pragma unroll
        for(int fn=0;fn<4;fn++)
          acc[fm][fn] = __builtin_amdgcn_mfma_f32_16x16x32_bf16(a[fm], b[fn], acc[fm][fn], 0,0,0);
    }
    if(tap<8){
      __syncthreads();
      #pragma unroll
      for(int k=0;k<4;k++)
        *(float4*)(&sA[(size_t)(k*256+tid)*8]) = pre[k];
      __syncthreads();
    }
  }
  // ---- epilogue: bias+relu+pixel-shuffle into LDS (rows 80B, chunk-XOR), then wide stores
  __syncthreads();
  char* oT = smem;                          // 512 rows x 80 B = 40960 B
  #pragma unroll
  for(int fm=0;fm<4;fm++){
    int co_loc = wm*16 + fm*4 + ks;         // 0..31
    int q_w = co_loc>>3, wi = co_loc&7;
    #pragma unroll
    for(int j=0;j<4;j++){
      float bsv = bias[mb*128 + wm*64 + fm*16 + ks*4 + j];
      int r1=(j>>1)&1, r2=j&1;
      #pragma unroll
      for(int fn=0;fn<4;fn++){
        int opx = (2*ryc[fn]+r1)*64 + 2*cxc[fn]+r2;
        float v = fmaxf(acc[fm][fn][j]+bsv, 0.f);
        *(bf16*)(oT + opx*80 + ((q_w ^ ((opx>>3)&3))<<4) + wi*2) = __float2bfloat16(v);
      }
    }
  }
  __syncthreads();
  bf16* ob = out + (size_t)img*4*H*W*64;
  const int W2 = 2*W;
  #pragma unroll
  for(int k=0;k<8;k++){
    int cid = k*256 + tid;
    int p = cid>>2, q = cid&3;
    int ly = p>>6, lx = p&63;
    uint4 v = *(const uint4*)(oT + p*80 + ((q ^ ((p>>3)&3))<<4));
    int Y = 2*y0+ly, X = 2*x0+lx;
    *(uint4*)(ob + ((size_t)Y*W2 + X)*64 + mb*32 + q*8) = v;
  }
}

// ---------------- final conv MFMA: 64->3(pad16) @640x640 NHWC bf16; writes y, xcropia, xoutputa ----------------
__global__ __launch_bounds__(256,2) void k_upcM(const bf16* __restrict__ in,
                        const bf16* __restrict__ wpu, const float* __restrict__ bias,
                        const float* __restrict__ scal, float* __restrict__ dout, int b){
  __shared__ __align__(16) __bf16 sB[396*64];   // 50688 B
  int tid = threadIdx.x;
  int t_ = blockIdx.x;
  int by0 = (t_/10)*4, bx0 = (t_%10)*64;
  for(int cid=tid; cid<3168; cid+=256){
    int px = cid>>3, c = cid&7;
    int hr = px/66, hc = px - hr*66;
    int gy = by0-1+hr, gx = bx0-1+hc;
    float4 v = {0.f,0.f,0.f,0.f};
    if((unsigned)gy<640u && (unsigned)gx<640u)
      v = *(const float4*)(in + ((size_t)(gy*640+gx))*64 + c*8);
    int slot = c ^ (px&7);
    *(float4*)(&sB[(size_t)px*64 + slot*8]) = v;
  }
  int w_ = tid>>6, l = tid&63;
  int ks = l>>4, l15 = l&15;
  bf16x8 afr[9][2];
  #pragma unroll
  for(int tap=0;tap<9;tap++)
    #pragma unroll
    for(int kk=0;kk<2;kk++)
      afr[tap][kk] = *(const bf16x8*)(wpu + (size_t)((tap*8 + kk*4+ks)*16 + l15)*8);
  __syncthreads();
  f32x4 acc[4];
  #pragma unroll
  for(int fn=0;fn<4;fn++) acc[fn]=(f32x4){0.f,0.f,0.f,0.f};
  int r = w_;
  int cxc[4];
  #pragma unroll
  for(int fn=0;fn<4;fn++) cxc[fn]=fn*16+l15;
  for(int tap=0;tap<9;tap++){
    int ty=tap/3, tx=tap-ty*3;
    #pragma unroll
    for(int kk=0;kk<2;kk++){
      int tc = kk*4+ks;
      #pragma unroll
      for(int fn=0;fn<4;fn++){
        int ph = (r+ty)*66 + cxc[fn]+tx;
        int slot = tc ^ (ph&7);
        bf16x8 bb = *(const bf16x8*)(&sB[(size_t)ph*64 + slot*8]);
        acc[fn] = __builtin_amdgcn_mfma_f32_16x16x32_bf16(afr[tap][kk], bb, acc[fn], 0,0,0);
      }
    }
  }
  if(ks==0){
    float c0=bias[0]+MEAN0, c1=bias[1]+MEAN1, c2=bias[2]+MEAN2;
    int gy = by0 + r;
    size_t yb=(size_t)b*3*409600;
    #pragma unroll
    for(int fn=0;fn<4;fn++){
      int gx = bx0 + cxc[fn];
      float a0=acc[fn][0]+c0, a1=acc[fn][1]+c1, a2=acc[fn][2]+c2;
      int n=b*25+(gy>>7)*5+(gx>>7);
      float sv=scal[128+n];
      size_t pidx=(size_t)gy*640+gx;
      dout[yb+pidx]=a0; dout[yb+409600+pidx]=a1; dout[yb+819200+pidx]=a2;
      dout[4915204 + (size_t)b*409600 + pidx]=sv;
      size_t xa=6553604+yb;
      dout[xa+pidx]=a0*sv; dout[xa+409600+pidx]=a1*sv; dout[xa+819200+pidx]=a2*sv;
    }
  }
}

extern "C" void kernel_launch(void* const* d_in, const int* in_sizes, int n_in,
                              void* d_out, int out_size, void* d_ws, size_t ws_size,
                              hipStream_t stream){
  const float* x     =(const float*)d_in[0];
  const float* tl    =(const float*)d_in[1];
  const float* tr    =(const float*)d_in[2];
  const float* iicm_w=(const float*)d_in[3];
  const float* iicm_b=(const float*)d_in[4];
  const float* conv4_w=(const float*)d_in[5];
  const float* conv4_b=(const float*)d_in[6];
  const float* b1_w1 =(const float*)d_in[7];  const float* b1_b1=(const float*)d_in[8];
  const float* b1_w2 =(const float*)d_in[9];  const float* b1_b2=(const float*)d_in[10];
  const float* c1_w  =(const float*)d_in[11]; const float* c1_b =(const float*)d_in[12];
  const float* b2_w1 =(const float*)d_in[13]; const float* b2_b1=(const float*)d_in[14];
  const float* b2_w2 =(const float*)d_in[15]; const float* b2_b2=(const float*)d_in[16];
  const float* c2_w  =(const float*)d_in[17]; const float* c2_b =(const float*)d_in[18];
  const float* b3_w1 =(const float*)d_in[19]; const float* b3_b1=(const float*)d_in[20];
  const float* b3_w2 =(const float*)d_in[21]; const float* b3_b2=(const float*)d_in[22];
  const float* c3_w  =(const float*)d_in[23]; const float* c3_b =(const float*)d_in[24];
  const float* marm_w=(const float*)d_in[25]; const float* marm_b=(const float*)d_in[26];
  const float* up1_w =(const float*)d_in[27]; const float* up1_b=(const float*)d_in[28];
  const float* up2_w =(const float*)d_in[29]; const float* up2_b=(const float*)d_in[30];
  const float* upc_w =(const float*)d_in[31]; const float* upc_b=(const float*)d_in[32];

  char* base = (char*)d_ws;
  float* out =(float*)d_out;
  float* scal=(float*)base;                         // 1024 B

  const int SEG = (ws_size >= 188417024ull) ? 4 : 1;
  const int NP  = SEG*25;
  const int NPix= NP*1024;

  const size_t F12 = (size_t)NP*49152;              // f12 bytes
  const size_t SZB = (size_t)NP*131072;             // one NHWC-64 bf16 buffer
  float* f12 = (float*)(base + 1024);
  char* bufs = base + 1024 + F12;
  bf16* fN   = (bf16*)(bufs + 0*SZB);
  bf16* tmpN = (bf16*)(bufs + 1*SZB);
  bf16* xsN  = (bf16*)(bufs + 2*SZB);
  bf16* b1oN = (bf16*)(bufs + 3*SZB);
  bf16* b2oN = (bf16*)(bufs + 4*SZB);
  bf16* xmN  = (bf16*)(bufs + 5*SZB);
  bf16* b3oN = (bf16*)(bufs + 6*SZB);
  bf16* xhN  = (bf16*)(bufs + 7*SZB);
  bf16* featN= (bf16*)(bufs + 0*SZB);               // 1.5*SZB, over fN+tmpN (dead)
  bf16* marmN= (bf16*)(bufs + 2*SZB);               // over xsN (dead after route)
  bf16* ps1  = (bf16*)(bufs + 4*SZB);               // 4*SZB, over b2oN..xhN (dead)
  bf16* ps2  = (bf16*)(bufs + 8*SZB);               // 52,428,800 B (one image)
  char* packs = bufs + 8*SZB + 52428800;
  bf16* wpc = (bf16*)packs;                         // 36864
  bf16* wp1 = wpc + 36864;                          // 147456
  bf16* wp2 = wp1 + 147456;                         // 147456
  bf16* wpm = wp2 + 147456;                         // 55296
  bf16* wpu = wpm + 55296;                          // 9216
  bf16* wpg = wpu + 9216;                           // 221184

  // weight packs once
  k_wcprep<<<144, 256,0,stream>>>(c1_w, c2_w, c3_w, wpc);
  k_wprep <<<1152,256,0,stream>>>(up1_w, up2_w, wp1);
  k_wmprep<<<216, 256,0,stream>>>(marm_w, wpm);
  k_wuprep<<<36,  256,0,stream>>>(upc_w, wpu);
  k_wgprep<<<864, 256,0,stream>>>(b1_w1,b1_w2,b2_w1,b2_w2,b3_w1,b3_w2, wpg);

  for(int b0=0;b0<4;b0+=SEG){
    int p0 = b0*25;
    const float* xseg = x + (size_t)b0*3*25600;
    float* scalp = scal + p0;

    k_iicm <<<NP*4,  256,0,stream>>>(xseg, iicm_w, iicm_b, f12);
    k_red  <<<NP,    256,0,stream>>>(f12, xseg, scalp);
    k_conv4<<<NP*32, 256,0,stream>>>(f12, conv4_w, conv4_b, fN);
    // block 1
    k_gconvM<<<NP*8, 128,0,stream>>>(fN,   wpg,          b1_b1, (const bf16*)0, tmpN, 1);
    k_gconvM<<<NP*8, 128,0,stream>>>(tmpN, wpg+36864,    b1_b2, fN,             b1oN, 0);
    k_1x1M <<<NP*4,  256,0,stream>>>(fN, b1oN, (const bf16*)0, (const bf16*)0, 2, wpc, c1_b, xsN);
    // block 2
    k_gconvM<<<NP*8, 128,0,stream>>>(xsN,  wpg+2*36864,  b2_b1, (const bf16*)0, tmpN, 1);
    k_gconvM<<<NP*8, 128,0,stream>>>(tmpN, wpg+3*36864,  b2_b2, xsN,            b2oN, 0);
    k_1x1M <<<NP*4,  256,0,stream>>>(fN, b1oN, b2oN, (const bf16*)0, 3, wpc+8192, c2_b, xmN);
    // block 3
    k_gconvM<<<NP*8, 128,0,stream>>>(xmN,  wpg+4*36864,  b3_b1, (const bf16*)0, tmpN, 1);
    k_gconvM<<<NP*8, 128,0,stream>>>(tmpN, wpg+5*36864,  b3_b2, xmN,            b3oN, 0);
    k_1x1M <<<NP*4,  256,0,stream>>>(fN, b1oN, b2oN, b3oN, 4, wpc+20480, c3_b, xhN);
    // routing -> featN (96ch NHWC) + timep
    k_routeN<<<(NPix*12+255)/256,256,0,stream>>>(xsN, xmN, xhN, xseg, scalp, tl, tr, featN, NPix);
    k_timep<<<SEG,   64, 0,stream>>>(scalp, tl, tr, out + 4915200 + b0);
    // MARM + upsample chain
    k_marmM<<<SEG*100, 256,0,stream>>>(featN, wpm, marm_b, marmN);
    k_convup<160,160><<<SEG*2*200, 256,0,stream>>>(marmN, wp1, up1_b, ps1);
    for(int i=0;i<SEG;i++){
      k_convup<320,320><<<2*800, 256,0,stream>>>(ps1 + (size_t)i*6553600, wp2, up2_b, ps2);
      k_upcM<<<1600,256,0,stream>>>(ps2, wpu, upc_b, scal, out, b0+i);
    }
  }
}

// Round 7
// 779.796 us; speedup vs baseline: 9.1763x; 1.1382x over previous
//
#include <hip/hip_runtime.h>
#include <hip/hip_bf16.h>

typedef __hip_bfloat16 bf16;
typedef __bf16 bf16x8 __attribute__((ext_vector_type(8)));
typedef float f32x4 __attribute__((ext_vector_type(4)));

#define MEAN0 0.4488f
#define MEAN1 0.4371f
#define MEAN2 0.4040f

// ---------------- IICM: 3->12 conv3x3 per 32x32 patch, relu ----------------
__global__ void k_iicm(const float* __restrict__ x, const float* __restrict__ w,
                       const float* __restrict__ bias, float* __restrict__ out){
  __shared__ __align__(16) float ws_[324];   // [tap27][oc12]
  __shared__ float bs[12];
  for(int k=threadIdx.x;k<324;k+=256){ int t0=k/12, kk=k%12; ws_[k]=w[kk*27+t0]; }
  if(threadIdx.x<12) bs[threadIdx.x]=bias[threadIdx.x];
  __syncthreads();
  int idx = blockIdx.x*256+threadIdx.x;
  int pix = idx & 1023, n = idx >> 10;
  int i = pix>>5, j = pix&31;
  int pw = n%5, ph=(n/5)%5, bb=n/25;
  float acc[12];
  #pragma unroll
  for(int k=0;k<12;k++) acc[k]=bs[k];
  #pragma unroll
  for(int c=0;c<3;c++){
    const float* xb = x + ((bb*3+c)*160 + ph*32)*160 + pw*32;
    float mc = (c==0)?MEAN0:((c==1)?MEAN1:MEAN2);
    #pragma unroll
    for(int dy=-1;dy<=1;dy++){
      int ii=i+dy; if((unsigned)ii>=32u) continue;
      #pragma unroll
      for(int dx=-1;dx<=1;dx++){
        int jj=j+dx; if((unsigned)jj>=32u) continue;
        float v = xb[ii*160+jj]-mc;
        int t0 = c*9+(dy+1)*3+(dx+1);
        const float4* wv = (const float4*)&ws_[t0*12];
        float4 w0=wv[0], w1=wv[1], w2=wv[2];
        acc[0]+=v*w0.x; acc[1]+=v*w0.y; acc[2]+=v*w0.z; acc[3]+=v*w0.w;
        acc[4]+=v*w1.x; acc[5]+=v*w1.y; acc[6]+=v*w1.z; acc[7]+=v*w1.w;
        acc[8]+=v*w2.x; acc[9]+=v*w2.y; acc[10]+=v*w2.z; acc[11]+=v*w2.w;
      }
    }
  }
  float* ob = out + n*12288 + pix;
  #pragma unroll
  for(int k=0;k<12;k++) ob[k*1024] = fmaxf(acc[k],0.f);
}

// ---------------- ssza + channel-0 std per patch ----------------
__global__ void k_red(const float* __restrict__ f12, const float* __restrict__ x,
                      float* __restrict__ scalp){
  int n = blockIdx.x, t = threadIdx.x;
  __shared__ float sh[256];
  float s=0.f;
  const float* fb = f12 + n*12288;
  for(int k=t;k<12288;k+=256) s += fabsf(fb[k]);
  sh[t]=s; __syncthreads();
  for(int o=128;o>0;o>>=1){ if(t<o) sh[t]+=sh[t+o]; __syncthreads(); }
  if(t==0) scalp[n]=sh[0]*(1.f/12288.f);
  __syncthreads();
  int pw=n%5, ph=(n/5)%5, bb=n/25;
  const float* xb = x + ((bb*3+0)*160 + ph*32)*160 + pw*32;
  float sm=0.f, sq=0.f;
  for(int k=t;k<1024;k+=256){ int i=k>>5,j=k&31; float v=xb[i*160+j]-MEAN0; sm+=v; sq+=v*v; }
  sh[t]=sm; __syncthreads();
  for(int o=128;o>0;o>>=1){ if(t<o) sh[t]+=sh[t+o]; __syncthreads(); }
  float smean = sh[0]*(1.f/1024.f);
  __syncthreads();
  sh[t]=sq; __syncthreads();
  for(int o=128;o>0;o>>=1){ if(t<o) sh[t]+=sh[t+o]; __syncthreads(); }
  if(t==0){ float var = sh[0]*(1.f/1024.f) - smean*smean; scalp[128+n]=sqrtf(fmaxf(var,0.f)); }
}

// ---------------- conv4: 12->64 conv3x3 per patch, NO relu -> NHWC bf16 ----------------
__global__ void k_conv4(const float* __restrict__ fin, const float* __restrict__ w,
                        const float* __restrict__ bias, bf16* __restrict__ outN){
  int bid=blockIdx.x;
  int tile=bid&3, chunk=(bid>>2)&7, n=bid>>5;
  __shared__ __align__(16) float ws_[864];   // [tap108][oc8]
  __shared__ float bs[8];
  int ocb=chunk*8;
  for(int k=threadIdx.x;k<864;k+=256){ int t0=k>>3, kk=k&7; ws_[k]=w[(ocb+kk)*108+t0]; }
  if(threadIdx.x<8) bs[threadIdx.x]=bias[ocb+threadIdx.x];
  __syncthreads();
  int pix=tile*256+threadIdx.x, i=pix>>5, j=pix&31;
  float acc[8];
  #pragma unroll
  for(int k=0;k<8;k++) acc[k]=bs[k];
  const float* fb = fin + n*12288;
  for(int c=0;c<12;c++){
    const float* fc = fb + c*1024;
    #pragma unroll
    for(int dy=-1;dy<=1;dy++){
      int ii=i+dy; if((unsigned)ii>=32u) continue;
      #pragma unroll
      for(int dx=-1;dx<=1;dx++){
        int jj=j+dx; if((unsigned)jj>=32u) continue;
        float v=fc[(ii<<5)+jj];
        int t0=c*9+(dy+1)*3+(dx+1);
        const float4* wv=(const float4*)&ws_[t0*8];
        float4 wa=wv[0], wb=wv[1];
        acc[0]+=v*wa.x; acc[1]+=v*wa.y; acc[2]+=v*wa.z; acc[3]+=v*wa.w;
        acc[4]+=v*wb.x; acc[5]+=v*wb.y; acc[6]+=v*wb.z; acc[7]+=v*wb.w;
      }}}
  union { float4 v; bf16 h[8]; } pk;
  #pragma unroll
  for(int k=0;k<8;k++) pk.h[k]=__float2bfloat16(acc[k]);
  *(float4*)(outN + ((size_t)(n*1024+pix))*64 + ocb) = pk.v;
}

// ---------------- weight pack for dense-ified grouped convs: [conv6][tap][icchunk][oc64][ic8] ----------------
__global__ void k_wgprep(const float* __restrict__ w0, const float* __restrict__ w1,
                         const float* __restrict__ w2, const float* __restrict__ w3,
                         const float* __restrict__ w4, const float* __restrict__ w5,
                         bf16* __restrict__ wpg){
  int idx = blockIdx.x*256+threadIdx.x;   // < 221184
  if(idx>=221184) return;
  int conv = idx/36864; int r = idx - conv*36864;
  int tap = r>>12; int r2 = r&4095;
  int s = r2>>9; int oc = (r2>>3)&63; int j = r2&7;
  int ic = s*8+j, g = oc>>4, il = ic - g*16;
  const float* w = (conv==0)?w0:(conv==1)?w1:(conv==2)?w2:(conv==3)?w3:(conv==4)?w4:w5;
  float v = ((unsigned)il<16u) ? w[oc*144 + il*9 + tap] : 0.f;
  wpg[idx] = __float2bfloat16(v);
}

// ---------------- dense MFMA grouped conv: barrier-free tap loop, A from L2 ----------------
// block 128 (2 waves), tile 64oc x (4 rows x 32 cols); grid NP*8
__global__ __launch_bounds__(128,4) void k_gconvM(const bf16* __restrict__ in,
                        const bf16* __restrict__ wg, const float* __restrict__ bias,
                        const bf16* __restrict__ resid, bf16* __restrict__ out, int do_relu){
  __shared__ __align__(16) __bf16 sB[8*210*8];   // 26880 B (stride 210: tc-groups on disjoint bank quartets)
  int tid = threadIdx.x;
  int bid = blockIdx.x;
  int n = bid>>3, tile = bid&7;
  int y0 = tile*4;
  const bf16* ib = in + (size_t)n*65536;
  for(int cid=tid; cid<1632; cid+=128){
    int s = cid/204, p = cid - s*204;
    int r = p/34, c = p - r*34;
    int gy = y0-1+r, gx = c-1;
    float4 v = {0.f,0.f,0.f,0.f};
    if((unsigned)gy<32u && (unsigned)gx<32u)
      v = *(const float4*)(ib + (size_t)((gy<<5)+gx)*64 + s*8);
    *(float4*)(&sB[(size_t)(s*210+p)*8]) = v;
  }
  __syncthreads();
  int w_ = tid>>6, l = tid&63;
  int ks = l>>4, l15 = l&15;
  f32x4 acc[4][4];
  #pragma unroll
  for(int i=0;i<4;i++)
    #pragma unroll
    for(int j=0;j<4;j++) acc[i][j]=(f32x4){0.f,0.f,0.f,0.f};
  int pr[4], pc[4];
  #pragma unroll
  for(int fn=0;fn<4;fn++){ int npx = w_*64+fn*16+l15; pr[fn]=npx>>5; pc[fn]=npx&31; }
  for(int tap=0;tap<9;tap++){
    int ty=tap/3, tx=tap-ty*3;
    #pragma unroll
    for(int kk=0;kk<2;kk++){
      int tc = kk*4+ks;
      bf16x8 a[4], b[4];
      #pragma unroll
      for(int fm=0;fm<4;fm++)
        a[fm] = *(const bf16x8*)(wg + ((size_t)((tap*8+tc)*64) + fm*16+l15)*8);
      #pragma unroll
      for(int fn=0;fn<4;fn++)
        b[fn] = *(const bf16x8*)(&sB[(size_t)(tc*210 + (pr[fn]+ty)*34 + pc[fn]+tx)*8]);
      #pragma unroll
      for(int fm=0;fm<4;fm++)
        #pragma unroll
        for(int fn=0;fn<4;fn++)
          acc[fm][fn] = __builtin_amdgcn_mfma_f32_16x16x32_bf16(a[fm], b[fn], acc[fm][fn], 0,0,0);
    }
  }
  bf16* ob = out + (size_t)n*65536;
  const bf16* rb = resid ? resid + (size_t)n*65536 : (const bf16*)0;
  #pragma unroll
  for(int fm=0;fm<4;fm++){
    int oc0 = fm*16 + ks*4;
    #pragma unroll
    for(int fn=0;fn<4;fn++){
      int pxl = (y0+pr[fn])*32 + pc[fn];
      float v[4];
      #pragma unroll
      for(int j=0;j<4;j++){
        float t = acc[fm][fn][j] + bias[oc0+j];
        if(do_relu) t = fmaxf(t,0.f);
        v[j]=t;
      }
      if(rb){
        union{ uint2 u; bf16 h[4]; } ru;
        ru.u = *(const uint2*)(rb + (size_t)pxl*64 + oc0);
        #pragma unroll
        for(int j=0;j<4;j++) v[j] += __bfloat162float(ru.h[j]);
      }
      union{ uint2 u; bf16 h[4]; } pk;
      #pragma unroll
      for(int j=0;j<4;j++) pk.h[j]=__float2bfloat16(v[j]);
      *(uint2*)(ob + (size_t)pxl*64 + oc0) = pk.u;
    }
  }
}

// ---------------- weight pack for 1x1 GEMMs ----------------
__global__ void k_wcprep(const float* __restrict__ w1, const float* __restrict__ w2,
                         const float* __restrict__ w3, bf16* __restrict__ wpc){
  int idx = blockIdx.x*256+threadIdx.x;   // < 36864
  const float* w; int Cin, base;
  if(idx<8192){ w=w1; Cin=128; base=0; }
  else if(idx<20480){ w=w2; Cin=192; base=8192; }
  else { w=w3; Cin=256; base=20480; }
  int r = idx-base;
  int g = r>>9, oc = (r>>3)&63, j = r&7;
  wpc[idx] = __float2bfloat16(w[oc*Cin + g*8 + j]);
}

// ---------------- MFMA 1x1 conv (pure GEMM): NHWC bf16 sources -> NHWC bf16 out, relu ----------------
__global__ __launch_bounds__(256,2) void k_1x1M(const bf16* __restrict__ s0,
                        const bf16* __restrict__ s1, const bf16* __restrict__ s2,
                        const bf16* __restrict__ s3, int ns,
                        const bf16* __restrict__ wpk, const float* __restrict__ bias,
                        bf16* __restrict__ outN){
  __shared__ __align__(16) __bf16 sA[32*64*8];   // 32768 B
  __shared__ __align__(16) __bf16 sB[8*256*8];   // 32768 B
  int tid = threadIdx.x;
  int px0 = blockIdx.x*256;
  for(int cid=tid; cid<ns*512; cid+=256)
    *(float4*)(&sA[(size_t)cid*8]) = ((const float4*)wpk)[cid];
  int w_ = tid>>6, l = tid&63;
  int ks = l>>4, l15 = l&15;
  f32x4 acc[4][4];
  #pragma unroll
  for(int i=0;i<4;i++)
    #pragma unroll
    for(int j=0;j<4;j++) acc[i][j]=(f32x4){0.f,0.f,0.f,0.f};
  const bf16* srcs[4]={s0,s1,s2,s3};
  for(int s=0;s<ns;s++){
    __syncthreads();
    const bf16* sp = srcs[s];
    #pragma unroll
    for(int it=0;it<8;it++){
      *(float4*)(&sB[(size_t)(it*256+tid)*8]) = *(const float4*)(sp + (size_t)(px0+tid)*64 + it*8);
    }
    __syncthreads();
    #pragma unroll
    for(int kk=0;kk<2;kk++){
      int tc = kk*4+ks;
      bf16x8 a[4], b[4];
      #pragma unroll
      for(int fm=0;fm<4;fm++) a[fm] = *(const bf16x8*)(&sA[(size_t)((s*8+tc)*64 + fm*16+l15)*8]);
      #pragma unroll
      for(int fn=0;fn<4;fn++) b[fn] = *(const bf16x8*)(&sB[(size_t)(tc*256 + w_*64+fn*16+l15)*8]);
      #pragma unroll
      for(int fm=0;fm<4;fm++)
        #pragma unroll
        for(int fn=0;fn<4;fn++)
          acc[fm][fn] = __builtin_amdgcn_mfma_f32_16x16x32_bf16(a[fm], b[fn], acc[fm][fn], 0,0,0);
    }
  }
  #pragma unroll
  for(int fm=0;fm<4;fm++){
    int oc0 = fm*16 + ks*4;
    #pragma unroll
    for(int fn=0;fn<4;fn++){
      int pxt = px0 + w_*64 + fn*16 + l15;
      union{ uint2 u; bf16 h[4]; } pk;
      #pragma unroll
      for(int j=0;j<4;j++) pk.h[j]=__float2bfloat16(fmaxf(acc[fm][fn][j]+bias[oc0+j],0.f));
      *(uint2*)(outN + (size_t)pxt*64 + oc0) = pk.u;
    }
  }
}

// ---------------- routing select (NHWC bf16 srcs) -> NHWC bf16 featN (96ch) ----------------
__global__ void k_routeN(const bf16* __restrict__ xs, const bf16* __restrict__ xm,
                         const bf16* __restrict__ xh, const float* __restrict__ xseg,
                         const float* __restrict__ scalp, const float* __restrict__ tl,
                         const float* __restrict__ tr, bf16* __restrict__ featN, int npix){
  int idx = blockIdx.x*256+threadIdx.x;
  int c = idx%12; int px = idx/12;
  if(px >= npix) return;
  int b = px/25600; int rem = px - b*25600;
  int y = rem/160, xx = rem - y*160;
  int n = b*25 + (y>>5)*5 + (xx>>5);
  float sz = scalp[n];
  float tl0 = tl[0], tr0 = tr[0], thr = tl0+tr0;
  const bf16* src = (sz>thr) ? xs : ((sz>=tl0 && sz<=thr) ? xm : xh);
  uint4 v = make_uint4(0,0,0,0);
  if(c < 8){
    v = *(const uint4*)(src + ((size_t)n*1024 + ((y&31)<<5) + (xx&31))*64 + c*8);
  } else if(c == 8){
    union{ uint4 q; bf16 h[8]; } pk;
    pk.q = make_uint4(0,0,0,0);
    pk.h[0]=__float2bfloat16(xseg[(b*3+0)*25600 + rem]-MEAN0);
    pk.h[1]=__float2bfloat16(xseg[(b*3+1)*25600 + rem]-MEAN1);
    pk.h[2]=__float2bfloat16(xseg[(b*3+2)*25600 + rem]-MEAN2);
    v = pk.q;
  }
  *(uint4*)(featN + (size_t)px*96 + c*8) = v;
}

// ---------------- timep ----------------
__global__ void k_timep(const float* __restrict__ scalp, const float* __restrict__ tl,
                        const float* __restrict__ tr, float* __restrict__ dtp){
  __shared__ float sh[64];
  int b=blockIdx.x, t=threadIdx.x;
  float tl0=tl[0], tr0=tr[0], thr=tl0+tr0;
  float v=0.f;
  if(t<25){
    float sz=scalp[b*25+t];
    v = (sz>thr) ? 1e-4f*(sz-thr) : ((sz>=tl0 && sz<=thr) ? 2e-4f*tr0 : 3e-4f*(tl0-sz));
  }
  sh[t]=v; __syncthreads();
  for(int o=32;o>0;o>>=1){ if(t<o) sh[t]+=sh[t+o]; __syncthreads(); }
  if(t==0) dtp[b]=sh[0]*(1.f/25.f);
}

// ---------------- weight pack for MFMA up-convs: [conv][tap][s8][oc256][ic8] bf16 ----------------
__global__ void k_wprep(const float* __restrict__ w1, const float* __restrict__ w2,
                        bf16* __restrict__ wp){
  int idx = blockIdx.x*256+threadIdx.x;   // < 294912
  int conv = idx/147456; int r = idx - conv*147456;
  int tap = r>>14; int r2 = r&16383;
  int s   = (r2>>11)&7;
  int oc  = (r2>>3)&255;
  int j   = r2&7;
  int ic = s*8+j;
  const float* w = conv? w2 : w1;
  wp[idx] = __float2bfloat16(w[oc*576 + ic*9 + tap]);
}

// ---------------- weight pack for MARM MFMA ----------------
__global__ void k_wmprep(const float* __restrict__ w, bf16* __restrict__ wpm){
  int idx = blockIdx.x*256+threadIdx.x;   // < 55296
  if(idx>=55296) return;
  int tap = idx/6144; int r = idx - tap*6144;
  int icg = r>>9; int oc = (r>>3)&63; int j = r&7;
  int ic = icg*8+j;
  float v = 0.f;
  if(ic<64)      v = w[oc*603 + (3+ic)*9 + tap];
  else if(ic<67) v = w[oc*603 + (ic-64)*9 + tap];
  wpm[idx] = __float2bfloat16(v);
}

// ---------------- weight pack for final conv MFMA ----------------
__global__ void k_wuprep(const float* __restrict__ w, bf16* __restrict__ wpu){
  int idx = blockIdx.x*256+threadIdx.x;   // < 9216
  if(idx>=9216) return;
  int tap = idx>>10; int r = idx&1023;
  int tc = r>>7; int oc = (r>>3)&15; int j = r&7;
  int ic = tc*8+j;
  float v = (oc<3) ? w[oc*576 + ic*9 + tap] : 0.f;
  wpu[idx] = __float2bfloat16(v);
}

// ---------------- MARM MFMA: 96ch NHWC bf16 conv3x3 -> 64ch NHWC bf16, relu ----------------
__global__ __launch_bounds__(256,2) void k_marmM(const bf16* __restrict__ featN,
                        const bf16* __restrict__ wpm, const float* __restrict__ bias,
                        bf16* __restrict__ outN){
  __shared__ __align__(16) __bf16 sB[12*340*8];  // 65280 B
  __shared__ __align__(16) __bf16 sA[12*64*8];   // 12288 B
  int bid = blockIdx.x;
  int img = bid/100; int t_ = bid - img*100;
  int y0 = (t_/5)*8, x0 = (t_%5)*32;
  int tid = threadIdx.x;
  const bf16* ib = featN + (size_t)img*25600*96;
  for(int cid=tid; cid<4080; cid+=256){
    int icg = cid/340, p = cid - icg*340;
    int r = p/34, cc = p - r*34;
    int gy = y0-1+r, gx = x0-1+cc;
    float4 v = {0.f,0.f,0.f,0.f};
    if((unsigned)gy<160u && (unsigned)gx<160u)
      v = *(const float4*)(ib + (size_t)(gy*160+gx)*96 + icg*8);
    *(float4*)(&sB[(size_t)(icg*340+p)*8]) = v;
  }
  for(int cid=tid; cid<768; cid+=256)
    *(float4*)(&sA[(size_t)cid*8]) = ((const float4*)wpm)[cid];
  __syncthreads();
  int w_ = tid>>6, l = tid&63;
  int ks = l>>4, l15 = l&15;
  f32x4 acc[4][4];
  #pragma unroll
  for(int i=0;i<4;i++)
    #pragma unroll
    for(int j=0;j<4;j++) acc[i][j]=(f32x4){0.f,0.f,0.f,0.f};
  int pr[4], pc[4];
  #pragma unroll
  for(int fn=0;fn<4;fn++){ int npx = w_*64+fn*16+l15; pr[fn]=npx>>5; pc[fn]=npx&31; }
  float4 pre[3];
  for(int tap=0;tap<9;tap++){
    if(tap<8){
      #pragma unroll
      for(int k=0;k<3;k++) pre[k] = ((const float4*)wpm)[(tap+1)*768 + k*256 + tid];
    }
    int ty=tap/3, tx=tap-ty*3;
    #pragma unroll
    for(int kk=0;kk<3;kk++){
      int tc = kk*4+ks;
      bf16x8 a[4], b[4];
      #pragma unroll
      for(int fm=0;fm<4;fm++) a[fm] = *(const bf16x8*)(&sA[(size_t)(tc*64 + fm*16+l15)*8]);
      #pragma unroll
      for(int fn=0;fn<4;fn++)
        b[fn] = *(const bf16x8*)(&sB[(size_t)(tc*340 + (pr[fn]+ty)*34 + pc[fn]+tx)*8]);
      #pragma unroll
      for(int fm=0;fm<4;fm++)
        #pragma unroll
        for(int fn=0;fn<4;fn++)
          acc[fm][fn] = __builtin_amdgcn_mfma_f32_16x16x32_bf16(a[fm], b[fn], acc[fm][fn], 0,0,0);
    }
    if(tap<8){
      __syncthreads();
      #pragma unroll
      for(int k=0;k<3;k++) ((float4*)sA)[k*256+tid] = pre[k];
      __syncthreads();
    }
  }
  bf16* ob = outN + (size_t)img*25600*64;
  #pragma unroll
  for(int fm=0;fm<4;fm++){
    int oc0 = fm*16 + ks*4;
    #pragma unroll
    for(int fn=0;fn<4;fn++){
      int px = (y0+pr[fn])*160 + x0+pc[fn];
      union{ uint2 u; bf16 h[4]; } pk;
      #pragma unroll
      for(int j=0;j<4;j++) pk.h[j]=__float2bfloat16(fmaxf(acc[fm][fn][j]+bias[oc0+j],0.f));
      *(uint2*)(ob + (size_t)px*64 + oc0) = pk.u;
    }
  }
}

// ---------------- MFMA up-conv v3: 64->256 conv3x3 + ps(2) + relu -> NHWC bf16 ----------------
// tile 4x16 input px, ALL 256 oc per block (4 waves); A from L2, barrier-free tap loop;
// epilogue stages full 8x32x64ch output tile in LDS, then full-128B-line stores.
template<int H, int W>
__global__ __launch_bounds__(256,3) void k_convup(const bf16* __restrict__ in,
                        const bf16* __restrict__ wp, const float* __restrict__ bias,
                        bf16* __restrict__ out){
  constexpr int TXC = W/16, TPB = (H/4)*TXC;
  __shared__ __align__(16) char smem[32768];   // sB 14592 | epilogue 32768 (reused)
  __bf16* sB = (__bf16*)smem;                  // [8][114][8]
  int bid = blockIdx.x;
  int img = bid/TPB; int t_ = bid - img*TPB;
  int y0 = (t_/TXC)*4, x0 = (t_%TXC)*16;
  int tid = threadIdx.x;
  const bf16* ib = in + (size_t)img*H*W*64;
  for(int cid=tid; cid<864; cid+=256){
    int tt = cid/108, p = cid - tt*108;
    int r = p/18, cc = p - r*18;
    int gy = y0-1+r, gx = x0-1+cc;
    float4 v = {0.f,0.f,0.f,0.f};
    if((unsigned)gy<(unsigned)H && (unsigned)gx<(unsigned)W)
      v = *(const float4*)(ib + ((size_t)(gy*W+gx)*64 + tt*8));
    *(float4*)(&sB[(size_t)(tt*114+p)*8]) = v;
  }
  __syncthreads();
  int w_ = tid>>6, l = tid&63;
  int ks = l>>4, l15 = l&15;
  f32x4 acc[4][4];
  #pragma unroll
  for(int i=0;i<4;i++)
    #pragma unroll
    for(int j=0;j<4;j++) acc[i][j]=(f32x4){0.f,0.f,0.f,0.f};
  for(int tap=0;tap<9;tap++){
    int ty=tap/3, tx=tap-ty*3;
    #pragma unroll
    for(int kk=0;kk<2;kk++){
      int tc = kk*4+ks;
      bf16x8 a[4], b[4];
      #pragma unroll
      for(int fm=0;fm<4;fm++)
        a[fm] = *(const bf16x8*)(wp + ((size_t)((tap*8+tc)*256) + w_*64 + fm*16 + l15)*8);
      #pragma unroll
      for(int fn=0;fn<4;fn++)
        b[fn] = *(const bf16x8*)(&sB[(size_t)(tc*114 + (fn+ty)*18 + l15+tx)*8]);
      #pragma unroll
      for(int fm=0;fm<4;fm++)
        #pragma unroll
        for(int fn=0;fn<4;fn++)
          acc[fm][fn] = __builtin_amdgcn_mfma_f32_16x16x32_bf16(a[fm], b[fn], acc[fm][fn], 0,0,0);
    }
  }
  // epilogue: bias+relu+pixel-shuffle into LDS [opx 256][64ch 128B] with chunk-XOR swizzle
  __syncthreads();
  char* oT = smem;
  #pragma unroll
  for(int fm=0;fm<4;fm++){
    int co = w_*16 + fm*4 + ks;              // output channel 0..63
    #pragma unroll
    for(int j=0;j<4;j++){
      float bsv = bias[w_*64 + fm*16 + ks*4 + j];
      int r1=(j>>1)&1, r2=j&1;
      #pragma unroll
      for(int fn=0;fn<4;fn++){
        int opx = (2*fn+r1)*32 + 2*l15+r2;   // 8x32 output tile
        float v = fmaxf(acc[fm][fn][j]+bsv, 0.f);
        int sl = (co>>3) ^ ((opx>>1)&7);
        *(bf16*)(oT + opx*128 + sl*16 + (co&7)*2) = __float2bfloat16(v);
      }
    }
  }
  __syncthreads();
  bf16* ob = out + (size_t)img*4*H*W*64;
  const int W2 = 2*W;
  #pragma unroll
  for(int k=0;k<8;k++){
    int cid = k*256 + tid;
    int p = cid>>3, lq = cid&7;
    int sl = lq ^ ((p>>1)&7);
    uint4 v = *(const uint4*)(oT + p*128 + sl*16);
    int Y = 2*y0 + (p>>5), X = 2*x0 + (p&31);
    *(uint4*)(ob + ((size_t)Y*W2 + X)*64 + lq*8) = v;
  }
}

// ---------------- final conv MFMA: 64->3(pad16) @640x640 NHWC bf16; writes y, xcropia, xoutputa ----------------
__global__ __launch_bounds__(256,2) void k_upcM(const bf16* __restrict__ in,
                        const bf16* __restrict__ wpu, const float* __restrict__ bias,
                        const float* __restrict__ scal, float* __restrict__ dout, int b){
  __shared__ __align__(16) __bf16 sB[396*64];   // 50688 B
  int tid = threadIdx.x;
  int t_ = blockIdx.x;
  int by0 = (t_/10)*4, bx0 = (t_%10)*64;
  for(int cid=tid; cid<3168; cid+=256){
    int px = cid>>3, c = cid&7;
    int hr = px/66, hc = px - hr*66;
    int gy = by0-1+hr, gx = bx0-1+hc;
    float4 v = {0.f,0.f,0.f,0.f};
    if((unsigned)gy<640u && (unsigned)gx<640u)
      v = *(const float4*)(in + ((size_t)(gy*640+gx))*64 + c*8);
    int slot = c ^ (px&7);
    *(float4*)(&sB[(size_t)px*64 + slot*8]) = v;
  }
  int w_ = tid>>6, l = tid&63;
  int ks = l>>4, l15 = l&15;
  bf16x8 afr[9][2];
  #pragma unroll
  for(int tap=0;tap<9;tap++)
    #pragma unroll
    for(int kk=0;kk<2;kk++)
      afr[tap][kk] = *(const bf16x8*)(wpu + (size_t)((tap*8 + kk*4+ks)*16 + l15)*8);
  __syncthreads();
  f32x4 acc[4];
  #pragma unroll
  for(int fn=0;fn<4;fn++) acc[fn]=(f32x4){0.f,0.f,0.f,0.f};
  int r = w_;
  int cxc[4];
  #pragma unroll
  for(int fn=0;fn<4;fn++) cxc[fn]=fn*16+l15;
  for(int tap=0;tap<9;tap++){
    int ty=tap/3, tx=tap-ty*3;
    #pragma unroll
    for(int kk=0;kk<2;kk++){
      int tc = kk*4+ks;
      #pragma unroll
      for(int fn=0;fn<4;fn++){
        int ph = (r+ty)*66 + cxc[fn]+tx;
        int slot = tc ^ (ph&7);
        bf16x8 bb = *(const bf16x8*)(&sB[(size_t)ph*64 + slot*8]);
        acc[fn] = __builtin_amdgcn_mfma_f32_16x16x32_bf16(afr[tap][kk], bb, acc[fn], 0,0,0);
      }
    }
  }
  if(ks==0){
    float c0=bias[0]+MEAN0, c1=bias[1]+MEAN1, c2=bias[2]+MEAN2;
    int gy = by0 + r;
    size_t yb=(size_t)b*3*409600;
    #pragma unroll
    for(int fn=0;fn<4;fn++){
      int gx = bx0 + cxc[fn];
      float a0=acc[fn][0]+c0, a1=acc[fn][1]+c1, a2=acc[fn][2]+c2;
      int n=b*25+(gy>>7)*5+(gx>>7);
      float sv=scal[128+n];
      size_t pidx=(size_t)gy*640+gx;
      dout[yb+pidx]=a0; dout[yb+409600+pidx]=a1; dout[yb+819200+pidx]=a2;
      dout[4915204 + (size_t)b*409600 + pidx]=sv;
      size_t xa=6553604+yb;
      dout[xa+pidx]=a0*sv; dout[xa+409600+pidx]=a1*sv; dout[xa+819200+pidx]=a2*sv;
    }
  }
}

extern "C" void kernel_launch(void* const* d_in, const int* in_sizes, int n_in,
                              void* d_out, int out_size, void* d_ws, size_t ws_size,
                              hipStream_t stream){
  const float* x     =(const float*)d_in[0];
  const float* tl    =(const float*)d_in[1];
  const float* tr    =(const float*)d_in[2];
  const float* iicm_w=(const float*)d_in[3];
  const float* iicm_b=(const float*)d_in[4];
  const float* conv4_w=(const float*)d_in[5];
  const float* conv4_b=(const float*)d_in[6];
  const float* b1_w1 =(const float*)d_in[7];  const float* b1_b1=(const float*)d_in[8];
  const float* b1_w2 =(const float*)d_in[9];  const float* b1_b2=(const float*)d_in[10];
  const float* c1_w  =(const float*)d_in[11]; const float* c1_b =(const float*)d_in[12];
  const float* b2_w1 =(const float*)d_in[13]; const float* b2_b1=(const float*)d_in[14];
  const float* b2_w2 =(const float*)d_in[15]; const float* b2_b2=(const float*)d_in[16];
  const float* c2_w  =(const float*)d_in[17]; const float* c2_b =(const float*)d_in[18];
  const float* b3_w1 =(const float*)d_in[19]; const float* b3_b1=(const float*)d_in[20];
  const float* b3_w2 =(const float*)d_in[21]; const float* b3_b2=(const float*)d_in[22];
  const float* c3_w  =(const float*)d_in[23]; const float* c3_b =(const float*)d_in[24];
  const float* marm_w=(const float*)d_in[25]; const float* marm_b=(const float*)d_in[26];
  const float* up1_w =(const float*)d_in[27]; const float* up1_b=(const float*)d_in[28];
  const float* up2_w =(const float*)d_in[29]; const float* up2_b=(const float*)d_in[30];
  const float* upc_w =(const float*)d_in[31]; const float* upc_b=(const float*)d_in[32];

  char* base = (char*)d_ws;
  float* out =(float*)d_out;
  float* scal=(float*)base;                         // 1024 B

  const int SEG = (ws_size >= 188417024ull) ? 4 : 1;
  const int NP  = SEG*25;
  const int NPix= NP*1024;

  const size_t F12 = (size_t)NP*49152;              // f12 bytes
  const size_t SZB = (size_t)NP*131072;             // one NHWC-64 bf16 buffer
  float* f12 = (float*)(base + 1024);
  char* bufs = base + 1024 + F12;
  bf16* fN   = (bf16*)(bufs + 0*SZB);
  bf16* tmpN = (bf16*)(bufs + 1*SZB);
  bf16* xsN  = (bf16*)(bufs + 2*SZB);
  bf16* b1oN = (bf16*)(bufs + 3*SZB);
  bf16* b2oN = (bf16*)(bufs + 4*SZB);
  bf16* xmN  = (bf16*)(bufs + 5*SZB);
  bf16* b3oN = (bf16*)(bufs + 6*SZB);
  bf16* xhN  = (bf16*)(bufs + 7*SZB);
  bf16* featN= (bf16*)(bufs + 0*SZB);               // 1.5*SZB, over fN+tmpN (dead)
  bf16* marmN= (bf16*)(bufs + 2*SZB);               // over xsN (dead after route)
  bf16* ps1  = (bf16*)(bufs + 4*SZB);               // 4*SZB, over b2oN..xhN (dead)
  bf16* ps2  = (bf16*)(bufs + 8*SZB);               // 52,428,800 B (one image)
  char* packs = bufs + 8*SZB + 52428800;
  bf16* wpc = (bf16*)packs;                         // 36864
  bf16* wp1 = wpc + 36864;                          // 147456
  bf16* wp2 = wp1 + 147456;                         // 147456
  bf16* wpm = wp2 + 147456;                         // 55296
  bf16* wpu = wpm + 55296;                          // 9216
  bf16* wpg = wpu + 9216;                           // 221184

  // weight packs once
  k_wcprep<<<144, 256,0,stream>>>(c1_w, c2_w, c3_w, wpc);
  k_wprep <<<1152,256,0,stream>>>(up1_w, up2_w, wp1);
  k_wmprep<<<216, 256,0,stream>>>(marm_w, wpm);
  k_wuprep<<<36,  256,0,stream>>>(upc_w, wpu);
  k_wgprep<<<864, 256,0,stream>>>(b1_w1,b1_w2,b2_w1,b2_w2,b3_w1,b3_w2, wpg);

  for(int b0=0;b0<4;b0+=SEG){
    int p0 = b0*25;
    const float* xseg = x + (size_t)b0*3*25600;
    float* scalp = scal + p0;

    k_iicm <<<NP*4,  256,0,stream>>>(xseg, iicm_w, iicm_b, f12);
    k_red  <<<NP,    256,0,stream>>>(f12, xseg, scalp);
    k_conv4<<<NP*32, 256,0,stream>>>(f12, conv4_w, conv4_b, fN);
    // block 1
    k_gconvM<<<NP*8, 128,0,stream>>>(fN,   wpg,          b1_b1, (const bf16*)0, tmpN, 1);
    k_gconvM<<<NP*8, 128,0,stream>>>(tmpN, wpg+36864,    b1_b2, fN,             b1oN, 0);
    k_1x1M <<<NP*4,  256,0,stream>>>(fN, b1oN, (const bf16*)0, (const bf16*)0, 2, wpc, c1_b, xsN);
    // block 2
    k_gconvM<<<NP*8, 128,0,stream>>>(xsN,  wpg+2*36864,  b2_b1, (const bf16*)0, tmpN, 1);
    k_gconvM<<<NP*8, 128,0,stream>>>(tmpN, wpg+3*36864,  b2_b2, xsN,            b2oN, 0);
    k_1x1M <<<NP*4,  256,0,stream>>>(fN, b1oN, b2oN, (const bf16*)0, 3, wpc+8192, c2_b, xmN);
    // block 3
    k_gconvM<<<NP*8, 128,0,stream>>>(xmN,  wpg+4*36864,  b3_b1, (const bf16*)0, tmpN, 1);
    k_gconvM<<<NP*8, 128,0,stream>>>(tmpN, wpg+5*36864,  b3_b2, xmN,            b3oN, 0);
    k_1x1M <<<NP*4,  256,0,stream>>>(fN, b1oN, b2oN, b3oN, 4, wpc+20480, c3_b, xhN);
    // routing -> featN (96ch NHWC) + timep
    k_routeN<<<(NPix*12+255)/256,256,0,stream>>>(xsN, xmN, xhN, xseg, scalp, tl, tr, featN, NPix);
    k_timep<<<SEG,   64, 0,stream>>>(scalp, tl, tr, out + 4915200 + b0);
    // MARM + upsample chain
    k_marmM<<<SEG*100, 256,0,stream>>>(featN, wpm, marm_b, marmN);
    k_convup<160,160><<<SEG*400, 256,0,stream>>>(marmN, wp1, up1_b, ps1);
    for(int i=0;i<SEG;i++){
      k_convup<320,320><<<1600, 256,0,stream>>>(ps1 + (size_t)i*6553600, wp2, up2_b, ps2);
      k_upcM<<<1600,256,0,stream>>>(ps2, wpu, upc_b, scal, out, b0+i);
    }
  }
}